// Round 1
// baseline (2385.412 us; speedup 1.0000x reference)
//
#include <hip/hip_runtime.h>
#include <math.h>

constexpr int CC = 64, KK = 256, LL = 128;
constexpr int NN = KK * LL;          // 32768
constexpr int PR = 64;               // Linformer projection
constexpr int CPG = 16;              // channels per group (C / 4)
constexpr float EPSV = 1e-5f;
constexpr float SCL = 0.35355339059327373f;  // 1/sqrt(8)

// ---------------- adaptive adjacency: softmax(relu(nv1@nv2), axis=1) ----------------
__global__ __launch_bounds__(256) void k_adp(const float* __restrict__ nv1,
                                             const float* __restrict__ nv2,
                                             float* __restrict__ adp) {
  int w = blockIdx.x, v = threadIdx.x;
  float s = 0.f;
  for (int d = 0; d < 10; ++d) s += nv1[w * 10 + d] * nv2[d * KK + v];
  s = fmaxf(s, 0.f);
  __shared__ float red[256];
  red[v] = s; __syncthreads();
  for (int off = 128; off; off >>= 1) { if (v < off) red[v] = fmaxf(red[v], red[v + off]); __syncthreads(); }
  float m = red[0]; __syncthreads();
  float e = expf(s - m);
  red[v] = e; __syncthreads();
  for (int off = 128; off; off >>= 1) { if (v < off) red[v] += red[v + off]; __syncthreads(); }
  adp[w * KK + v] = e / red[0];
}

// ---------------- out[b,c,w,l] = sum_v A[w,v] * in[b,c,v,l] ----------------
// grid: (B*C*4) blocks, 128 threads; each block does a 64-row chunk of w.
__global__ __launch_bounds__(128) void k_adj(const float* __restrict__ A,
                                             const float* __restrict__ in,
                                             float* __restrict__ out) {
  int blk = blockIdx.x;
  int wch = blk & 3, bc = blk >> 2;
  const float* src = in + (size_t)bc * NN;
  float* dst = out + (size_t)bc * NN + (size_t)wch * 64 * LL;
  int l = threadIdx.x;
  __shared__ float sIn[64][LL];    // 32 KB
  __shared__ float sA[64][65];     // 16.25 KB
  float acc[64];
#pragma unroll
  for (int w = 0; w < 64; ++w) acc[w] = 0.f;
  for (int v0 = 0; v0 < KK; v0 += 64) {
    for (int r = 0; r < 64; ++r) sIn[r][l] = src[(size_t)(v0 + r) * LL + l];
    for (int i = 0; i < 32; ++i) {
      int idx = i * 128 + l; int w = idx >> 6, v = idx & 63;
      sA[w][v] = A[(size_t)(wch * 64 + w) * KK + v0 + v];
    }
    __syncthreads();
    for (int v = 0; v < 64; ++v) {
      float xv = sIn[v][l];
#pragma unroll
      for (int w = 0; w < 64; ++w) acc[w] += sA[w][v] * xv;
    }
    __syncthreads();
  }
  for (int w = 0; w < 64; ++w) dst[(size_t)w * LL + l] = acc[w];
}

// ---------------- out[b,o,n] (+)= sum_c W[o*wstride+woff+c] * in[b,c,n] (+bias) ----------------
// grid: B*NN/256 blocks, 256 threads (one spatial position each).
__global__ __launch_bounds__(256) void k_chan(const float* __restrict__ W, int wstride, int woff,
                                              const float* __restrict__ bias,
                                              const float* __restrict__ in,
                                              float* __restrict__ out, int accumulate) {
  int t = threadIdx.x;
  size_t nbase = (size_t)blockIdx.x * 256;
  int b = (int)(nbase >> 15);
  size_t n = nbase & (size_t)(NN - 1);
  __shared__ float sW[64][65];
  for (int i = t; i < 4096; i += 256) { int o = i >> 6, c = i & 63; sW[o][c] = W[(size_t)o * wstride + woff + c]; }
  __syncthreads();
  const float* src = in + (size_t)b * CC * NN + n + t;
  float* dst = out + (size_t)b * CC * NN + n + t;
  float acc[64];
#pragma unroll
  for (int o = 0; o < 64; ++o) acc[o] = 0.f;
  for (int c = 0; c < 64; ++c) {
    float x = src[(size_t)c * NN];
#pragma unroll
    for (int o = 0; o < 64; ++o) acc[o] += sW[o][c] * x;
  }
  for (int o = 0; o < 64; ++o) {
    float r = acc[o] + (bias ? bias[o] : 0.f);
    if (accumulate) r += dst[(size_t)o * NN];
    dst[(size_t)o * NN] = r;
  }
}

// ---------------- generic (c,l)-plane transpose per (b,k), optional add (indexed like dst) ----------------
// grid: (512, (nC/32)*(nL/32)), 256 threads. Caller arranges sl==1 and dc==1 for coalescing.
__global__ __launch_bounds__(256) void k_tr(const float* __restrict__ src, float* __restrict__ dst,
                                            const float* __restrict__ add,
                                            long sb, long sk, long sc, long sl,
                                            long db, long dk, long dc, long dl, int nC, int nL) {
  int outer = blockIdx.x;
  int b = outer >> 8, k = outer & 255;
  int tilesL = nL >> 5;
  int tC = blockIdx.y / tilesL, tL = blockIdx.y % tilesL;
  int c0 = tC << 5, l0 = tL << 5;
  __shared__ float s[32][33];
  int tx = threadIdx.x & 31, ty = threadIdx.x >> 5;
  const float* sp = src + (long)b * sb + (long)k * sk;
#pragma unroll
  for (int j = 0; j < 4; ++j) {
    int cc = c0 + ty + j * 8;
    s[ty + j * 8][tx] = sp[(long)cc * sc + (long)(l0 + tx) * sl];
  }
  __syncthreads();
  long dbase = (long)b * db + (long)k * dk;
#pragma unroll
  for (int j = 0; j < 4; ++j) {
    int ll = l0 + ty + j * 8;
    long off = dbase + (long)(c0 + tx) * dc + (long)ll * dl;
    float val = s[tx][ty + j * 8];
    if (add) val += add[off];
    dst[off] = val;
  }
}

// ---------------- row-major (R,CIN) @ (CIN,COUT) + bias, optional activation ----------------
// ACT: 0 none, 1 relu, 2 exact gelu. grid: R/ROWS blocks, 256 threads.
template <int CIN, int COUT, int ACT, int ROWS>
__global__ __launch_bounds__(256) void k_rowmm(const float* __restrict__ in,
                                               const float* __restrict__ W,
                                               const float* __restrict__ bias,
                                               float* __restrict__ out) {
  int r0 = blockIdx.x * ROWS;
  __shared__ float sIn[ROWS][CIN];
  __shared__ float sW[CIN][COUT];
  int t = threadIdx.x;
  for (int i = t; i < ROWS * CIN; i += 256) ((float*)sIn)[i] = in[(size_t)r0 * CIN + i];
  for (int i = t; i < CIN * COUT; i += 256) ((float*)sW)[i] = W[i];
  __syncthreads();
  constexpr int NRG = 256 / COUT;
  int col = t % COUT, rg = t / COUT;
  float bv = bias ? bias[col] : 0.f;
  for (int rr = 0; rr < ROWS / NRG; ++rr) {
    int r = rr * NRG + rg;
    float acc = bv;
#pragma unroll 8
    for (int c = 0; c < CIN; ++c) acc += sIn[r][c] * sW[c][col];
    if (ACT == 1) acc = fmaxf(acc, 0.f);
    if (ACT == 2) acc = 0.5f * acc * (1.f + erff(acc * 0.70710678118654752440f));
    out[(size_t)(r0 + r) * COUT + col] = acc;
  }
}

// ---------------- kp2[bl,p,c] = sum_n X[bl,n,c] * P[n,p] ----------------
__global__ __launch_bounds__(256) void k_sproj(const float* __restrict__ X,
                                               const float* __restrict__ P,
                                               float* __restrict__ out) {
  int bl = blockIdx.x;
  const float* src = X + (size_t)bl * KK * CC;
  float* dst = out + (size_t)bl * PR * CC;
  int t = threadIdx.x, c = t & 63, pg = t >> 6;
  __shared__ float sX[64][CC];
  __shared__ float sP[64][PR];
  float acc[16];
#pragma unroll
  for (int i = 0; i < 16; ++i) acc[i] = 0.f;
  for (int n0 = 0; n0 < KK; n0 += 64) {
    for (int i = t; i < 64 * CC; i += 256) ((float*)sX)[i] = src[(size_t)n0 * CC + i];
    for (int i = t; i < 64 * PR; i += 256) ((float*)sP)[i] = P[(size_t)n0 * PR + i];
    __syncthreads();
    for (int n = 0; n < 64; ++n) {
      float xv = sX[n][c];
#pragma unroll
      for (int i = 0; i < 16; ++i) acc[i] += sP[n][pg * 16 + i] * xv;
    }
    __syncthreads();
  }
#pragma unroll
  for (int i = 0; i < 16; ++i) dst[(size_t)(pg * 16 + i) * CC + c] = acc[i];
}

// ---------------- spatial attention: per (b,l), 256 threads (one per k row) ----------------
__global__ __launch_bounds__(256) void k_sattn(const float* __restrict__ Q, const float* __restrict__ KP,
                                               const float* __restrict__ VP, float* __restrict__ O) {
  int bl = blockIdx.x, k = threadIdx.x;
  __shared__ float sK[PR][CC];
  __shared__ float sV[PR][CC];
  for (int i = k; i < PR * CC; i += 256) {
    ((float*)sK)[i] = KP[(size_t)bl * PR * CC + i];
    ((float*)sV)[i] = VP[(size_t)bl * PR * CC + i];
  }
  __syncthreads();
  const float* qrow = Q + ((size_t)bl * KK + k) * CC;
  float* orow = O + ((size_t)bl * KK + k) * CC;
  for (int h = 0; h < 8; ++h) {
    float q[8];
#pragma unroll
    for (int d = 0; d < 8; ++d) q[d] = qrow[h * 8 + d] * SCL;
    float m = -1e30f;
    for (int p = 0; p < PR; ++p) {
      float s = 0.f;
#pragma unroll
      for (int d = 0; d < 8; ++d) s += q[d] * sK[p][h * 8 + d];
      m = fmaxf(m, s);
    }
    float sum = 0.f, o[8];
#pragma unroll
    for (int d = 0; d < 8; ++d) o[d] = 0.f;
    for (int p = 0; p < PR; ++p) {
      float s = 0.f;
#pragma unroll
      for (int d = 0; d < 8; ++d) s += q[d] * sK[p][h * 8 + d];
      float e = expf(s - m);
      sum += e;
#pragma unroll
      for (int d = 0; d < 8; ++d) o[d] += e * sV[p][h * 8 + d];
    }
    float inv = 1.f / sum;
#pragma unroll
    for (int d = 0; d < 8; ++d) orow[h * 8 + d] = o[d] * inv;
  }
}

// ---------------- temporal attention: per (b,k), 128 threads (one per l row) ----------------
__global__ __launch_bounds__(128) void k_tattn(const float* __restrict__ Q, const float* __restrict__ Kt,
                                               const float* __restrict__ Vt, float* __restrict__ O) {
  int bk = blockIdx.x, l = threadIdx.x;
  __shared__ float sK[LL][CC];   // 32 KB
  __shared__ float sV[LL][CC];   // 32 KB
  for (int i = l; i < LL * CC; i += 128) {
    ((float*)sK)[i] = Kt[(size_t)bk * LL * CC + i];
    ((float*)sV)[i] = Vt[(size_t)bk * LL * CC + i];
  }
  __syncthreads();
  const float* qrow = Q + ((size_t)bk * LL + l) * CC;
  float* orow = O + ((size_t)bk * LL + l) * CC;
  for (int h = 0; h < 8; ++h) {
    float q[8];
#pragma unroll
    for (int d = 0; d < 8; ++d) q[d] = qrow[h * 8 + d] * SCL;
    float m = -1e30f;
    for (int p = 0; p < LL; ++p) {
      float s = 0.f;
#pragma unroll
      for (int d = 0; d < 8; ++d) s += q[d] * sK[p][h * 8 + d];
      m = fmaxf(m, s);
    }
    float sum = 0.f, o[8];
#pragma unroll
    for (int d = 0; d < 8; ++d) o[d] = 0.f;
    for (int p = 0; p < LL; ++p) {
      float s = 0.f;
#pragma unroll
      for (int d = 0; d < 8; ++d) s += q[d] * sK[p][h * 8 + d];
      float e = expf(s - m);
      sum += e;
#pragma unroll
      for (int d = 0; d < 8; ++d) o[d] += e * sV[p][h * 8 + d];
    }
    float inv = 1.f / sum;
#pragma unroll
    for (int d = 0; d < 8; ++d) orow[h * 8 + d] = o[d] * inv;
  }
}

// ---------------- LayerNorm over C=64 per row, input = A (+ optional Bp) ----------------
__global__ __launch_bounds__(256) void k_ln(const float* __restrict__ A, const float* __restrict__ Bp,
                                            const float* __restrict__ g, const float* __restrict__ be,
                                            float* __restrict__ out) {
  int row = blockIdx.x * 4 + (threadIdx.x >> 6);
  int c = threadIdx.x & 63;
  size_t idx = (size_t)row * CC + c;
  float x = A[idx] + (Bp ? Bp[idx] : 0.f);
  float s = x, ss = x * x;
#pragma unroll
  for (int off = 32; off; off >>= 1) { s += __shfl_xor(s, off); ss += __shfl_xor(ss, off); }
  float mu = s * (1.f / 64.f);
  float var = ss * (1.f / 64.f) - mu * mu;
  out[idx] = (x - mu) * rsqrtf(var + EPSV) * g[c] + be[c];
}

// ---------------- GroupNorm: deterministic two-phase stats over contiguous (b,g) regions ----------------
__global__ __launch_bounds__(256) void k_gn_part(const float* __restrict__ p0, const float* __restrict__ p1,
                                                 float* __restrict__ part) {
  int bg = blockIdx.y, blk = blockIdx.x, t = threadIdx.x;
  size_t start = (size_t)bg * ((size_t)CPG * NN) + (size_t)blk * 8192;
  float s = 0.f, ss = 0.f;
  for (int i = t; i < 8192; i += 256) {
    float x = p0[start + i];
    if (p1) x += p1[start + i];
    s += x; ss += x * x;
  }
  __shared__ float rs[256], rq[256];
  rs[t] = s; rq[t] = ss; __syncthreads();
  for (int off = 128; off; off >>= 1) { if (t < off) { rs[t] += rs[t + off]; rq[t] += rq[t + off]; } __syncthreads(); }
  if (t == 0) { part[(bg * 64 + blk) * 2] = rs[0]; part[(bg * 64 + blk) * 2 + 1] = rq[0]; }
}

__global__ __launch_bounds__(64) void k_gn_final(const float* __restrict__ part, float* __restrict__ stats) {
  int bg = blockIdx.x, t = threadIdx.x;
  float s = part[(bg * 64 + t) * 2], ss = part[(bg * 64 + t) * 2 + 1];
#pragma unroll
  for (int off = 32; off; off >>= 1) { s += __shfl_xor(s, off); ss += __shfl_xor(ss, off); }
  if (t == 0) {
    float inv = 1.f / (float)((size_t)CPG * NN);
    float mu = s * inv;
    float var = ss * inv - mu * mu;
    stats[bg * 2] = mu;
    stats[bg * 2 + 1] = rsqrtf(var + EPSV);
  }
}

__global__ __launch_bounds__(256) void k_gn_apply(const float* __restrict__ p0, const float* __restrict__ p1,
                                                  const float* __restrict__ stats, const float* __restrict__ g,
                                                  const float* __restrict__ be, float* __restrict__ out) {
  size_t i = (size_t)blockIdx.x * 256 + threadIdx.x;
  int chan = (int)(i >> 15) & 63;
  int bg = (int)(i >> 19);
  float x = p0[i];
  if (p1) x += p1[i];
  out[i] = (x - stats[bg * 2]) * stats[bg * 2 + 1] * g[chan] + be[chan];
}

__global__ __launch_bounds__(256) void k_add3(const float* __restrict__ a, const float* __restrict__ b,
                                              const float* __restrict__ c, float* __restrict__ o) {
  size_t i = (size_t)blockIdx.x * 256 + threadIdx.x;
  o[i] = a[i] + b[i] + c[i];
}

extern "C" void kernel_launch(void* const* d_in, const int* in_sizes, int n_in,
                              void* d_out, int out_size, void* d_ws, size_t ws_size,
                              hipStream_t stream) {
  (void)in_sizes; (void)n_in; (void)out_size; (void)ws_size;
  const float* y     = (const float*)d_in[0];
  const float* a1    = (const float*)d_in[1];
  const float* a2    = (const float*)d_in[2];
  const float* nv1   = (const float*)d_in[3];
  const float* nv2   = (const float*)d_in[4];
  const float* gcn_w = (const float*)d_in[5];
  const float* gcn_b = (const float*)d_in[6];
  const float* s_wq  = (const float*)d_in[7];
  const float* s_wk  = (const float*)d_in[8];
  const float* s_wv  = (const float*)d_in[9];
  const float* s_pk  = (const float*)d_in[10];
  const float* s_pv  = (const float*)d_in[11];
  const float* s_wo  = (const float*)d_in[12];
  const float* s_bo  = (const float*)d_in[13];
  const float* t_wq  = (const float*)d_in[14];
  const float* t_wk  = (const float*)d_in[15];
  const float* t_wv  = (const float*)d_in[16];
  const float* t_bq  = (const float*)d_in[17];
  const float* t_bk  = (const float*)d_in[18];
  const float* t_bv  = (const float*)d_in[19];
  const float* t_wo  = (const float*)d_in[20];
  const float* t_bo  = (const float*)d_in[21];
  const float* t_l1w = (const float*)d_in[22];
  const float* t_l1b = (const float*)d_in[23];
  const float* t_l2w = (const float*)d_in[24];
  const float* t_l2b = (const float*)d_in[25];
  const float* ln1g  = (const float*)d_in[26];
  const float* ln1b  = (const float*)d_in[27];
  const float* ln2g  = (const float*)d_in[28];
  const float* ln2b  = (const float*)d_in[29];
  const float* gnlg  = (const float*)d_in[30];
  const float* gnlb  = (const float*)d_in[31];
  const float* gnsg  = (const float*)d_in[32];
  const float* gnsb  = (const float*)d_in[33];
  const float* gntg  = (const float*)d_in[34];
  const float* gntb  = (const float*)d_in[35];
  const float* ff1w  = (const float*)d_in[36];
  const float* ff1b  = (const float*)d_in[37];
  const float* ff2w  = (const float*)d_in[38];
  const float* ff2b  = (const float*)d_in[39];
  const float* gn2g  = (const float*)d_in[40];
  const float* gn2b  = (const float*)d_in[41];

  float* ws = (float*)d_ws;
  float* adp   = ws;                 // 65536
  float* part  = ws + 65536;         // 1024
  float* stats = ws + 66560;         // 16
  float* kp2   = ws + 131072;        // 1 M floats
  float* vp2   = ws + 131072 + 1048576;
  float* ffh   = ws + 2228224;       // 512 K floats
  const size_t SLOT = 4194304;
  float* G0 = ws + SLOT * 1;  // y_local acc -> y_local_gn (persists)
  float* G1 = ws + SLOT * 2;  // y_s_gn (persists)
  float* G2 = ws + SLOT * 3;  // xs / xt / y_t_gn
  float* G3 = ws + SLOT * 4;
  float* G4 = ws + SLOT * 5;
  float* G5 = ws + SLOT * 6;  // + G6: contiguous 2-slot region for FFN hidden
  float* G6 = ws + SLOT * 7;
  float* out = (float*)d_out;

  const long BS = 2097152;  // per-batch stride of a 16MB tensor in floats

  // ---- adaptive adjacency ----
  k_adp<<<256, 256, 0, stream>>>(nv1, nv2, adp);

  // ---- AdaptiveGCN ----
  k_chan<<<256, 256, 0, stream>>>(gcn_w, 7 * CC, 0, gcn_b, y, G0, 0);  // chunk 0 = identity
  const float* adjs[3] = {a1, a2, adp};
  for (int j = 0; j < 3; ++j) {
    k_adj<<<512, 128, 0, stream>>>(adjs[j], y, G3);
    k_chan<<<256, 256, 0, stream>>>(gcn_w, 7 * CC, (1 + 2 * j) * CC, nullptr, G3, G0, 1);
    k_adj<<<512, 128, 0, stream>>>(adjs[j], G3, G4);
    k_chan<<<256, 256, 0, stream>>>(gcn_w, 7 * CC, (2 + 2 * j) * CC, nullptr, G4, G0, 1);
  }
  k_gn_part<<<dim3(64, 8), 256, 0, stream>>>(y, G0, part);
  k_gn_final<<<8, 64, 0, stream>>>(part, stats);
  k_gn_apply<<<16384, 256, 0, stream>>>(y, G0, stats, gnlg, gnlb, G0);

  // ---- Linformer spatial attention ----
  // xs (B,L,K,C)
  k_tr<<<dim3(512, 8), 256, 0, stream>>>(y, G2, nullptr, BS, 128, 32768, 1, BS, 64, 1, 16384, 64, 128);
  k_rowmm<64, 64, 0, 64><<<1024, 256, 0, stream>>>(G2, s_wq, nullptr, G3);
  k_rowmm<64, 64, 0, 64><<<1024, 256, 0, stream>>>(G2, s_wk, nullptr, G4);
  k_rowmm<64, 64, 0, 64><<<1024, 256, 0, stream>>>(G2, s_wv, nullptr, G5);
  k_sproj<<<256, 256, 0, stream>>>(G4, s_pk, kp2);
  k_sproj<<<256, 256, 0, stream>>>(G5, s_pv, vp2);
  k_sattn<<<256, 256, 0, stream>>>(G3, kp2, vp2, G6);
  k_rowmm<64, 64, 0, 64><<<1024, 256, 0, stream>>>(G6, s_wo, s_bo, G4);
  // back to (B,C,K,L)
  k_tr<<<dim3(512, 8), 256, 0, stream>>>(G4, G1, nullptr, BS, 64, 16384, 1, BS, 128, 1, 32768, 128, 64);
  k_gn_part<<<dim3(64, 8), 256, 0, stream>>>(y, G1, part);
  k_gn_final<<<8, 64, 0, stream>>>(part, stats);
  k_gn_apply<<<16384, 256, 0, stream>>>(y, G1, stats, gnsg, gnsb, G1);

  // ---- temporal transformer layer ----
  // xt (B,K,L,C)
  k_tr<<<dim3(512, 8), 256, 0, stream>>>(y, G2, nullptr, BS, 128, 32768, 1, BS, 8192, 1, 64, 64, 128);
  k_rowmm<64, 64, 0, 64><<<1024, 256, 0, stream>>>(G2, t_wq, t_bq, G3);
  k_rowmm<64, 64, 0, 64><<<1024, 256, 0, stream>>>(G2, t_wk, t_bk, G4);
  k_rowmm<64, 64, 0, 64><<<1024, 256, 0, stream>>>(G2, t_wv, t_bv, G5);
  k_tattn<<<512, 128, 0, stream>>>(G3, G4, G5, G6);
  k_rowmm<64, 64, 0, 64><<<1024, 256, 0, stream>>>(G6, t_wo, t_bo, G3);
  k_ln<<<16384, 256, 0, stream>>>(G2, G3, ln1g, ln1b, G4);                  // src
  k_rowmm<64, 8, 2, 64><<<1024, 256, 0, stream>>>(G4, t_l1w, t_l1b, ffh);   // gelu
  k_rowmm<8, 64, 0, 64><<<1024, 256, 0, stream>>>(ffh, t_l2w, t_l2b, G5);
  k_ln<<<16384, 256, 0, stream>>>(G4, G5, ln2g, ln2b, G6);                  // src2
  k_tr<<<dim3(512, 8), 256, 0, stream>>>(G6, G2, nullptr, BS, 8192, 64, 1, BS, 128, 1, 32768, 128, 64);
  k_gn_part<<<dim3(64, 8), 256, 0, stream>>>(y, G2, part);
  k_gn_final<<<8, 64, 0, stream>>>(part, stats);
  k_gn_apply<<<16384, 256, 0, stream>>>(y, G2, stats, gntg, gntb, G2);

  // ---- fuse + channel FFN + final GroupNorm ----
  k_add3<<<16384, 256, 0, stream>>>(G0, G1, G2, G3);                        // y_in2 (B,C,N)
  k_tr<<<dim3(512, 8), 256, 0, stream>>>(G3, G4, nullptr, BS, 128, 32768, 1, BS, 8192, 1, 64, 64, 128); // (B,N,C)
  k_rowmm<64, 128, 1, 64><<<1024, 256, 0, stream>>>(G4, ff1w, ff1b, G5);    // relu, hidden in G5..G6
  k_rowmm<128, 64, 0, 32><<<2048, 256, 0, stream>>>(G5, ff2w, ff2b, G4);
  k_tr<<<dim3(512, 8), 256, 0, stream>>>(G4, out, G3, BS, 8192, 64, 1, BS, 128, 1, 32768, 128, 64); // h^T + y_in2
  k_gn_part<<<dim3(64, 8), 256, 0, stream>>>(out, nullptr, part);
  k_gn_final<<<8, 64, 0, stream>>>(part, stats);
  k_gn_apply<<<16384, 256, 0, stream>>>(out, nullptr, stats, gn2g, gn2b, out);
}

// Round 3
// 877.621 us; speedup vs baseline: 2.7180x; 2.7180x over previous
//
#include <hip/hip_runtime.h>
#include <math.h>

constexpr int CC = 64, KK = 256, LL = 128;
constexpr int NN = KK * LL;          // 32768
constexpr int PR = 64;               // Linformer projection
constexpr int CPG = 16;              // channels per group (C / 4)
constexpr float EPSV = 1e-5f;
constexpr float SCL = 0.35355339059327373f;  // 1/sqrt(8)

// ---------------- adaptive adjacency: softmax(relu(nv1@nv2), axis=1) ----------------
__global__ __launch_bounds__(256) void k_adp(const float* __restrict__ nv1,
                                             const float* __restrict__ nv2,
                                             float* __restrict__ adp) {
  int w = blockIdx.x, v = threadIdx.x;
  float s = 0.f;
  for (int d = 0; d < 10; ++d) s += nv1[w * 10 + d] * nv2[d * KK + v];
  s = fmaxf(s, 0.f);
  __shared__ float red[256];
  red[v] = s; __syncthreads();
  for (int off = 128; off; off >>= 1) { if (v < off) red[v] = fmaxf(red[v], red[v + off]); __syncthreads(); }
  float m = red[0]; __syncthreads();
  float e = expf(s - m);
  red[v] = e; __syncthreads();
  for (int off = 128; off; off >>= 1) { if (v < off) red[v] += red[v + off]; __syncthreads(); }
  adp[w * KK + v] = e / red[0];
}

// ---------------- out[b,c,w,l] = sum_v A[w,v] * in[b,c,v,l] ----------------
// grid: B*C*4 = 512 blocks, 256 threads; block computes 64w x 128l tile for one bc.
// micro-tile: 4 w x 8 l per thread.
__global__ __launch_bounds__(256) void k_adj(const float* __restrict__ A,
                                             const float* __restrict__ in,
                                             float* __restrict__ out) {
  int blk = blockIdx.x;
  int wch = blk & 3, bc = blk >> 2;
  const float* src = in + (size_t)bc * NN;
  float* dst = out + (size_t)bc * NN + (size_t)(wch * 64) * LL;
  int t = threadIdx.x;
  int tw = t >> 4, tl = t & 15;
  int w0 = tw * 4, l0 = tl * 8;
  __shared__ float sIn[64][128];   // 32 KB
  __shared__ float sA[64][65];     // 16.25 KB
  float acc[4][8];
#pragma unroll
  for (int i = 0; i < 4; ++i)
#pragma unroll
    for (int j = 0; j < 8; ++j) acc[i][j] = 0.f;
  for (int v0 = 0; v0 < KK; v0 += 64) {
    const float4* gsrc = (const float4*)(src + (size_t)v0 * 128);
    float4* ls = (float4*)sIn;
    for (int i = t; i < 2048; i += 256) ls[i] = gsrc[i];
    for (int i = t; i < 4096; i += 256) {
      int w = i >> 6, v = i & 63;
      sA[w][v] = A[(size_t)(wch * 64 + w) * KK + v0 + v];
    }
    __syncthreads();
    for (int v = 0; v < 64; ++v) {
      float a[4];
#pragma unroll
      for (int i = 0; i < 4; ++i) a[i] = sA[w0 + i][v];
      float4 xa = *(const float4*)&sIn[v][l0];
      float4 xb = *(const float4*)&sIn[v][l0 + 4];
      float x[8] = {xa.x, xa.y, xa.z, xa.w, xb.x, xb.y, xb.z, xb.w};
#pragma unroll
      for (int i = 0; i < 4; ++i)
#pragma unroll
        for (int j = 0; j < 8; ++j) acc[i][j] += a[i] * x[j];
    }
    __syncthreads();
  }
#pragma unroll
  for (int i = 0; i < 4; ++i) {
    float4 ra = {acc[i][0], acc[i][1], acc[i][2], acc[i][3]};
    float4 rb = {acc[i][4], acc[i][5], acc[i][6], acc[i][7]};
    *(float4*)&dst[(size_t)(w0 + i) * 128 + l0] = ra;
    *(float4*)&dst[(size_t)(w0 + i) * 128 + l0 + 4] = rb;
  }
}

// ---------------- fused GCN output: out[b,o,n] = bias[o] + sum_s sum_c W[o,448][s*64+c]*src_s[b,c,n] ----------------
// grid: (256, 2) — 2 halves of o. 256 threads = 256 consecutive n positions.
__global__ __launch_bounds__(256) void k_gcn(const float* __restrict__ W, const float* __restrict__ bias,
                                             const float* __restrict__ s0, const float* __restrict__ s1,
                                             const float* __restrict__ s2, const float* __restrict__ s3,
                                             const float* __restrict__ s4, const float* __restrict__ s5,
                                             const float* __restrict__ s6, float* __restrict__ out) {
  const float* srcs[7] = {s0, s1, s2, s3, s4, s5, s6};
  int t = threadIdx.x;
  int oy = blockIdx.y;              // o half
  size_t nbase = (size_t)blockIdx.x * 256;
  int b = (int)(nbase >> 15);
  size_t n = (nbase & (size_t)(NN - 1)) + t;
  __shared__ float sWT[64][36];     // [c][o'] for 32 o
  float acc[32];
#pragma unroll
  for (int o = 0; o < 32; ++o) acc[o] = bias[oy * 32 + o];
  for (int s = 0; s < 7; ++s) {
    __syncthreads();
    for (int i = t; i < 2048; i += 256) {
      int o = i >> 6, c = i & 63;
      sWT[c][o] = W[(size_t)(oy * 32 + o) * 448 + s * 64 + c];
    }
    __syncthreads();
    const float* sp = srcs[s] + (size_t)b * CC * NN + n;
    for (int c = 0; c < 64; ++c) {
      float x = sp[(size_t)c * NN];
#pragma unroll
      for (int og = 0; og < 8; ++og) {
        float4 wv = *(const float4*)&sWT[c][og * 4];
        acc[og * 4 + 0] += wv.x * x;
        acc[og * 4 + 1] += wv.y * x;
        acc[og * 4 + 2] += wv.z * x;
        acc[og * 4 + 3] += wv.w * x;
      }
    }
  }
  float* dst = out + (size_t)b * CC * NN + (size_t)(oy * 32) * NN + n;
#pragma unroll
  for (int o = 0; o < 32; ++o) dst[(size_t)o * NN] = acc[o];
}

// ---------------- generic (c,l)-plane transpose per (b,k), optional add (indexed like dst) ----------------
__global__ __launch_bounds__(256) void k_tr(const float* __restrict__ src, float* __restrict__ dst,
                                            const float* __restrict__ add,
                                            long sb, long sk, long sc, long sl,
                                            long db, long dk, long dc, long dl, int nC, int nL) {
  int outer = blockIdx.x;
  int b = outer >> 8, k = outer & 255;
  int tilesL = nL >> 5;
  int tC = blockIdx.y / tilesL, tL = blockIdx.y % tilesL;
  int c0 = tC << 5, l0 = tL << 5;
  __shared__ float s[32][33];
  int tx = threadIdx.x & 31, ty = threadIdx.x >> 5;
  const float* sp = src + (long)b * sb + (long)k * sk;
#pragma unroll
  for (int j = 0; j < 4; ++j) {
    int cc = c0 + ty + j * 8;
    s[ty + j * 8][tx] = sp[(long)cc * sc + (long)(l0 + tx) * sl];
  }
  __syncthreads();
  long dbase = (long)b * db + (long)k * dk;
#pragma unroll
  for (int j = 0; j < 4; ++j) {
    int ll = l0 + ty + j * 8;
    long off = dbase + (long)(c0 + tx) * dc + (long)ll * dl;
    float val = s[tx][ty + j * 8];
    if (add) val += add[off];
    dst[off] = val;
  }
}

// ---------------- row-major (R,CIN) @ (CIN,COUT) + bias, optional activation ----------------
// ACT: 0 none, 1 relu, 2 exact gelu. grid: R/ROWS blocks, 256 threads.
template <int CIN, int COUT, int ACT, int ROWS>
__global__ __launch_bounds__(256) void k_rowmm(const float* __restrict__ in,
                                               const float* __restrict__ W,
                                               const float* __restrict__ bias,
                                               float* __restrict__ out) {
  int r0 = blockIdx.x * ROWS;
  __shared__ float sInT[CIN][ROWS + 4];   // transposed input tile
  __shared__ float sW[CIN][COUT];
  int t = threadIdx.x;
  for (int i = t; i < CIN * COUT; i += 256) ((float*)sW)[i] = W[i];
  for (int i = t; i < ROWS * CIN; i += 256) {
    int r = i / CIN, c = i % CIN;
    sInT[c][r] = in[(size_t)r0 * CIN + i];
  }
  __syncthreads();
  constexpr int NRG = 256 / COUT;
  constexpr int RPT = ROWS / NRG;
  int col = t % COUT, rg = t / COUT;
  int rbase = rg * RPT;
  float acc[RPT];
  float bv = bias ? bias[col] : 0.f;
#pragma unroll
  for (int r = 0; r < RPT; ++r) acc[r] = bv;
  for (int c = 0; c < CIN; ++c) {
    float wv = sW[c][col];
    if constexpr (RPT % 4 == 0) {
#pragma unroll
      for (int rr = 0; rr < RPT; rr += 4) {
        float4 xv = *(const float4*)&sInT[c][rbase + rr];
        acc[rr] += xv.x * wv; acc[rr + 1] += xv.y * wv;
        acc[rr + 2] += xv.z * wv; acc[rr + 3] += xv.w * wv;
      }
    } else {
#pragma unroll
      for (int rr = 0; rr < RPT; ++rr) acc[rr] += sInT[c][rbase + rr] * wv;
    }
  }
#pragma unroll
  for (int rr = 0; rr < RPT; ++rr) {
    float v = acc[rr];
    if (ACT == 1) v = fmaxf(v, 0.f);
    if (ACT == 2) v = 0.5f * v * (1.f + erff(v * 0.70710678118654752440f));
    out[(size_t)(r0 + rbase + rr) * COUT + col] = v;
  }
}

// ---------------- kp2[bl,p,c] = sum_n X[bl,n,c] * P[n,p] ----------------
__global__ __launch_bounds__(256) void k_sproj(const float* __restrict__ X,
                                               const float* __restrict__ P,
                                               float* __restrict__ out) {
  int bl = blockIdx.x;
  const float* src = X + (size_t)bl * KK * CC;
  float* dst = out + (size_t)bl * PR * CC;
  int t = threadIdx.x, c = t & 63, pg = t >> 6;
  __shared__ float sX[64][CC];
  __shared__ float sP[64][PR];
  float acc[16];
#pragma unroll
  for (int i = 0; i < 16; ++i) acc[i] = 0.f;
  for (int n0 = 0; n0 < KK; n0 += 64) {
    for (int i = t; i < 64 * CC; i += 256) ((float*)sX)[i] = src[(size_t)n0 * CC + i];
    for (int i = t; i < 64 * PR; i += 256) ((float*)sP)[i] = P[(size_t)n0 * PR + i];
    __syncthreads();
    for (int n = 0; n < 64; ++n) {
      float xv = sX[n][c];
#pragma unroll
      for (int q = 0; q < 4; ++q) {
        float4 pv = *(const float4*)&sP[n][pg * 16 + q * 4];
        acc[q * 4 + 0] += pv.x * xv; acc[q * 4 + 1] += pv.y * xv;
        acc[q * 4 + 2] += pv.z * xv; acc[q * 4 + 3] += pv.w * xv;
      }
    }
    __syncthreads();
  }
#pragma unroll
  for (int i = 0; i < 16; ++i) dst[(size_t)(pg * 16 + i) * CC + c] = acc[i];
}

// ---------------- spatial attention: one wave per (b,l,h); 4 k-rows per thread ----------------
__global__ __launch_bounds__(64) void k_sattn(const float* __restrict__ Q, const float* __restrict__ KP,
                                              const float* __restrict__ VP, float* __restrict__ O) {
  int blk = blockIdx.x;
  int h = blk & 7, bl = blk >> 3;
  int t = threadIdx.x;
  __shared__ float sK[PR][8], sV[PR][8];
  {
    const float* kr = KP + ((size_t)bl * PR + t) * CC + h * 8;
    const float* vr = VP + ((size_t)bl * PR + t) * CC + h * 8;
    *(float4*)&sK[t][0] = *(const float4*)kr;
    *(float4*)&sK[t][4] = *(const float4*)(kr + 4);
    *(float4*)&sV[t][0] = *(const float4*)vr;
    *(float4*)&sV[t][4] = *(const float4*)(vr + 4);
  }
  __syncthreads();
  float q[4][8], o[4][8], sum[4];
#pragma unroll
  for (int j = 0; j < 4; ++j) {
    const float* qr = Q + ((size_t)bl * KK + j * 64 + t) * CC + h * 8;
    float4 qa = *(const float4*)qr, qb = *(const float4*)(qr + 4);
    q[j][0] = qa.x * SCL; q[j][1] = qa.y * SCL; q[j][2] = qa.z * SCL; q[j][3] = qa.w * SCL;
    q[j][4] = qb.x * SCL; q[j][5] = qb.y * SCL; q[j][6] = qb.z * SCL; q[j][7] = qb.w * SCL;
    sum[j] = 0.f;
#pragma unroll
    for (int d = 0; d < 8; ++d) o[j][d] = 0.f;
  }
  for (int p = 0; p < PR; ++p) {
    float4 ka = *(const float4*)&sK[p][0], kb = *(const float4*)&sK[p][4];
    float4 va = *(const float4*)&sV[p][0], vb = *(const float4*)&sV[p][4];
    float k[8] = {ka.x, ka.y, ka.z, ka.w, kb.x, kb.y, kb.z, kb.w};
    float v[8] = {va.x, va.y, va.z, va.w, vb.x, vb.y, vb.z, vb.w};
#pragma unroll
    for (int j = 0; j < 4; ++j) {
      float s = 0.f;
#pragma unroll
      for (int d = 0; d < 8; ++d) s += q[j][d] * k[d];
      float e = __expf(s);
      sum[j] += e;
#pragma unroll
      for (int d = 0; d < 8; ++d) o[j][d] += e * v[d];
    }
  }
#pragma unroll
  for (int j = 0; j < 4; ++j) {
    float inv = 1.f / sum[j];
    float* orow = O + ((size_t)bl * KK + j * 64 + t) * CC + h * 8;
    float4 ra = {o[j][0] * inv, o[j][1] * inv, o[j][2] * inv, o[j][3] * inv};
    float4 rb = {o[j][4] * inv, o[j][5] * inv, o[j][6] * inv, o[j][7] * inv};
    *(float4*)orow = ra; *(float4*)(orow + 4) = rb;
  }
}

// ---------------- temporal attention: one wave per (b,k,h); 2 l-rows per thread ----------------
__global__ __launch_bounds__(64) void k_tattn(const float* __restrict__ Q, const float* __restrict__ Kt,
                                              const float* __restrict__ Vt, float* __restrict__ O) {
  int blk = blockIdx.x;
  int h = blk & 7, bk = blk >> 3;
  int t = threadIdx.x;
  __shared__ float sK[LL][8], sV[LL][8];
#pragma unroll
  for (int j = 0; j < 2; ++j) {
    int r = j * 64 + t;
    const float* kr = Kt + ((size_t)bk * LL + r) * CC + h * 8;
    const float* vr = Vt + ((size_t)bk * LL + r) * CC + h * 8;
    *(float4*)&sK[r][0] = *(const float4*)kr;
    *(float4*)&sK[r][4] = *(const float4*)(kr + 4);
    *(float4*)&sV[r][0] = *(const float4*)vr;
    *(float4*)&sV[r][4] = *(const float4*)(vr + 4);
  }
  __syncthreads();
  float q[2][8], o[2][8], sum[2];
#pragma unroll
  for (int j = 0; j < 2; ++j) {
    const float* qr = Q + ((size_t)bk * LL + j * 64 + t) * CC + h * 8;
    float4 qa = *(const float4*)qr, qb = *(const float4*)(qr + 4);
    q[j][0] = qa.x * SCL; q[j][1] = qa.y * SCL; q[j][2] = qa.z * SCL; q[j][3] = qa.w * SCL;
    q[j][4] = qb.x * SCL; q[j][5] = qb.y * SCL; q[j][6] = qb.z * SCL; q[j][7] = qb.w * SCL;
    sum[j] = 0.f;
#pragma unroll
    for (int d = 0; d < 8; ++d) o[j][d] = 0.f;
  }
  for (int p = 0; p < LL; ++p) {
    float4 ka = *(const float4*)&sK[p][0], kb = *(const float4*)&sK[p][4];
    float4 va = *(const float4*)&sV[p][0], vb = *(const float4*)&sV[p][4];
    float k[8] = {ka.x, ka.y, ka.z, ka.w, kb.x, kb.y, kb.z, kb.w};
    float v[8] = {va.x, va.y, va.z, va.w, vb.x, vb.y, vb.z, vb.w};
#pragma unroll
    for (int j = 0; j < 2; ++j) {
      float s = 0.f;
#pragma unroll
      for (int d = 0; d < 8; ++d) s += q[j][d] * k[d];
      float e = __expf(s);
      sum[j] += e;
#pragma unroll
      for (int d = 0; d < 8; ++d) o[j][d] += e * v[d];
    }
  }
#pragma unroll
  for (int j = 0; j < 2; ++j) {
    float inv = 1.f / sum[j];
    float* orow = O + ((size_t)bk * LL + j * 64 + t) * CC + h * 8;
    float4 ra = {o[j][0] * inv, o[j][1] * inv, o[j][2] * inv, o[j][3] * inv};
    float4 rb = {o[j][4] * inv, o[j][5] * inv, o[j][6] * inv, o[j][7] * inv};
    *(float4*)orow = ra; *(float4*)(orow + 4) = rb;
  }
}

// ---------------- LayerNorm over C=64 per row, input = A (+ optional Bp) ----------------
__global__ __launch_bounds__(256) void k_ln(const float* __restrict__ A, const float* __restrict__ Bp,
                                            const float* __restrict__ g, const float* __restrict__ be,
                                            float* __restrict__ out) {
  int row = blockIdx.x * 4 + (threadIdx.x >> 6);
  int c = threadIdx.x & 63;
  size_t idx = (size_t)row * CC + c;
  float x = A[idx] + (Bp ? Bp[idx] : 0.f);
  float s = x, ss = x * x;
#pragma unroll
  for (int off = 32; off; off >>= 1) { s += __shfl_xor(s, off); ss += __shfl_xor(ss, off); }
  float mu = s * (1.f / 64.f);
  float var = ss * (1.f / 64.f) - mu * mu;
  out[idx] = (x - mu) * rsqrtf(var + EPSV) * g[c] + be[c];
}

// ---------------- GroupNorm: deterministic two-phase stats over contiguous (b,g) regions ----------------
__global__ __launch_bounds__(256) void k_gn_part(const float* __restrict__ p0, const float* __restrict__ p1,
                                                 float* __restrict__ part) {
  int bg = blockIdx.y, blk = blockIdx.x, t = threadIdx.x;
  size_t start = (size_t)bg * ((size_t)CPG * NN) + (size_t)blk * 8192;
  float s = 0.f, ss = 0.f;
  for (int i = t; i < 8192; i += 256) {
    float x = p0[start + i];
    if (p1) x += p1[start + i];
    s += x; ss += x * x;
  }
  __shared__ float rs[256], rq[256];
  rs[t] = s; rq[t] = ss; __syncthreads();
  for (int off = 128; off; off >>= 1) { if (t < off) { rs[t] += rs[t + off]; rq[t] += rq[t + off]; } __syncthreads(); }
  if (t == 0) { part[(bg * 64 + blk) * 2] = rs[0]; part[(bg * 64 + blk) * 2 + 1] = rq[0]; }
}

__global__ __launch_bounds__(64) void k_gn_final(const float* __restrict__ part, float* __restrict__ stats) {
  int bg = blockIdx.x, t = threadIdx.x;
  float s = part[(bg * 64 + t) * 2], ss = part[(bg * 64 + t) * 2 + 1];
#pragma unroll
  for (int off = 32; off; off >>= 1) { s += __shfl_xor(s, off); ss += __shfl_xor(ss, off); }
  if (t == 0) {
    float inv = 1.f / (float)((size_t)CPG * NN);
    float mu = s * inv;
    float var = ss * inv - mu * mu;
    stats[bg * 2] = mu;
    stats[bg * 2 + 1] = rsqrtf(var + EPSV);
  }
}

__global__ __launch_bounds__(256) void k_gn_apply(const float* __restrict__ p0, const float* __restrict__ p1,
                                                  const float* __restrict__ stats, const float* __restrict__ g,
                                                  const float* __restrict__ be, float* __restrict__ out) {
  size_t i = (size_t)blockIdx.x * 256 + threadIdx.x;
  int chan = (int)(i >> 15) & 63;
  int bg = (int)(i >> 19);
  float x = p0[i];
  if (p1) x += p1[i];
  out[i] = (x - stats[bg * 2]) * stats[bg * 2 + 1] * g[chan] + be[chan];
}

__global__ __launch_bounds__(256) void k_add3(const float* __restrict__ a, const float* __restrict__ b,
                                              const float* __restrict__ c, float* __restrict__ o) {
  size_t i = (size_t)blockIdx.x * 256 + threadIdx.x;
  o[i] = a[i] + b[i] + c[i];
}

extern "C" void kernel_launch(void* const* d_in, const int* in_sizes, int n_in,
                              void* d_out, int out_size, void* d_ws, size_t ws_size,
                              hipStream_t stream) {
  (void)in_sizes; (void)n_in; (void)out_size; (void)ws_size;
  const float* y     = (const float*)d_in[0];
  const float* a1    = (const float*)d_in[1];
  const float* a2    = (const float*)d_in[2];
  const float* nv1   = (const float*)d_in[3];
  const float* nv2   = (const float*)d_in[4];
  const float* gcn_w = (const float*)d_in[5];
  const float* gcn_b = (const float*)d_in[6];
  const float* s_wq  = (const float*)d_in[7];
  const float* s_wk  = (const float*)d_in[8];
  const float* s_wv  = (const float*)d_in[9];
  const float* s_pk  = (const float*)d_in[10];
  const float* s_pv  = (const float*)d_in[11];
  const float* s_wo  = (const float*)d_in[12];
  const float* s_bo  = (const float*)d_in[13];
  const float* t_wq  = (const float*)d_in[14];
  const float* t_wk  = (const float*)d_in[15];
  const float* t_wv  = (const float*)d_in[16];
  const float* t_bq  = (const float*)d_in[17];
  const float* t_bk  = (const float*)d_in[18];
  const float* t_bv  = (const float*)d_in[19];
  const float* t_wo  = (const float*)d_in[20];
  const float* t_bo  = (const float*)d_in[21];
  const float* t_l1w = (const float*)d_in[22];
  const float* t_l1b = (const float*)d_in[23];
  const float* t_l2w = (const float*)d_in[24];
  const float* t_l2b = (const float*)d_in[25];
  const float* ln1g  = (const float*)d_in[26];
  const float* ln1b  = (const float*)d_in[27];
  const float* ln2g  = (const float*)d_in[28];
  const float* ln2b  = (const float*)d_in[29];
  const float* gnlg  = (const float*)d_in[30];
  const float* gnlb  = (const float*)d_in[31];
  const float* gnsg  = (const float*)d_in[32];
  const float* gnsb  = (const float*)d_in[33];
  const float* gntg  = (const float*)d_in[34];
  const float* gntb  = (const float*)d_in[35];
  const float* ff1w  = (const float*)d_in[36];
  const float* ff1b  = (const float*)d_in[37];
  const float* ff2w  = (const float*)d_in[38];
  const float* ff2b  = (const float*)d_in[39];
  const float* gn2g  = (const float*)d_in[40];
  const float* gn2b  = (const float*)d_in[41];

  float* ws = (float*)d_ws;
  float* adp   = ws;                 // 65536
  float* part  = ws + 65536;         // 1024
  float* stats = ws + 66560;         // 16
  float* kp2   = ws + 131072;        // 1 M floats
  float* vp2   = ws + 131072 + 1048576;
  float* ffh   = ws + 2228224;       // 512 K floats
  const size_t SLOT = 4194304;
  float* G0 = ws + SLOT * 1;
  float* G1 = ws + SLOT * 2;
  float* G2 = ws + SLOT * 3;
  float* G3 = ws + SLOT * 4;
  float* G4 = ws + SLOT * 5;
  float* G5 = ws + SLOT * 6;
  float* G6 = ws + SLOT * 7;
  float* out = (float*)d_out;

  const long BS = 2097152;  // per-batch stride of a 16MB tensor in floats

  // ---- adaptive adjacency ----
  k_adp<<<256, 256, 0, stream>>>(nv1, nv2, adp);

  // ---- AdaptiveGCN: 6 hops then fused output conv ----
  k_adj<<<512, 256, 0, stream>>>(a1, y, G1);
  k_adj<<<512, 256, 0, stream>>>(a1, G1, G2);
  k_adj<<<512, 256, 0, stream>>>(a2, y, G3);
  k_adj<<<512, 256, 0, stream>>>(a2, G3, G4);
  k_adj<<<512, 256, 0, stream>>>(adp, y, G5);
  k_adj<<<512, 256, 0, stream>>>(adp, G5, G6);
  k_gcn<<<dim3(256, 2), 256, 0, stream>>>(gcn_w, gcn_b, y, G1, G2, G3, G4, G5, G6, G0);
  k_gn_part<<<dim3(64, 8), 256, 0, stream>>>(y, G0, part);
  k_gn_final<<<8, 64, 0, stream>>>(part, stats);
  k_gn_apply<<<16384, 256, 0, stream>>>(y, G0, stats, gnlg, gnlb, G0);

  // ---- Linformer spatial attention ----
  k_tr<<<dim3(512, 8), 256, 0, stream>>>(y, G2, nullptr, BS, 128, 32768, 1, BS, 64, 1, 16384, 64, 128);
  k_rowmm<64, 64, 0, 64><<<1024, 256, 0, stream>>>(G2, s_wq, nullptr, G3);
  k_rowmm<64, 64, 0, 64><<<1024, 256, 0, stream>>>(G2, s_wk, nullptr, G4);
  k_rowmm<64, 64, 0, 64><<<1024, 256, 0, stream>>>(G2, s_wv, nullptr, G5);
  k_sproj<<<256, 256, 0, stream>>>(G4, s_pk, kp2);
  k_sproj<<<256, 256, 0, stream>>>(G5, s_pv, vp2);
  k_sattn<<<2048, 64, 0, stream>>>(G3, kp2, vp2, G6);
  k_rowmm<64, 64, 0, 64><<<1024, 256, 0, stream>>>(G6, s_wo, s_bo, G4);
  k_tr<<<dim3(512, 8), 256, 0, stream>>>(G4, G1, nullptr, BS, 64, 16384, 1, BS, 128, 1, 32768, 128, 64);
  k_gn_part<<<dim3(64, 8), 256, 0, stream>>>(y, G1, part);
  k_gn_final<<<8, 64, 0, stream>>>(part, stats);
  k_gn_apply<<<16384, 256, 0, stream>>>(y, G1, stats, gnsg, gnsb, G1);

  // ---- temporal transformer layer ----
  k_tr<<<dim3(512, 8), 256, 0, stream>>>(y, G2, nullptr, BS, 128, 32768, 1, BS, 8192, 1, 64, 64, 128);
  k_rowmm<64, 64, 0, 64><<<1024, 256, 0, stream>>>(G2, t_wq, t_bq, G3);
  k_rowmm<64, 64, 0, 64><<<1024, 256, 0, stream>>>(G2, t_wk, t_bk, G4);
  k_rowmm<64, 64, 0, 64><<<1024, 256, 0, stream>>>(G2, t_wv, t_bv, G5);
  k_tattn<<<4096, 64, 0, stream>>>(G3, G4, G5, G6);
  k_rowmm<64, 64, 0, 64><<<1024, 256, 0, stream>>>(G6, t_wo, t_bo, G3);
  k_ln<<<16384, 256, 0, stream>>>(G2, G3, ln1g, ln1b, G4);
  k_rowmm<64, 8, 2, 64><<<1024, 256, 0, stream>>>(G4, t_l1w, t_l1b, ffh);
  k_rowmm<8, 64, 0, 64><<<1024, 256, 0, stream>>>(ffh, t_l2w, t_l2b, G5);
  k_ln<<<16384, 256, 0, stream>>>(G4, G5, ln2g, ln2b, G6);
  k_tr<<<dim3(512, 8), 256, 0, stream>>>(G6, G2, nullptr, BS, 8192, 64, 1, BS, 128, 1, 32768, 128, 64);
  k_gn_part<<<dim3(64, 8), 256, 0, stream>>>(y, G2, part);
  k_gn_final<<<8, 64, 0, stream>>>(part, stats);
  k_gn_apply<<<16384, 256, 0, stream>>>(y, G2, stats, gntg, gntb, G2);

  // ---- fuse + channel FFN + final GroupNorm ----
  k_add3<<<16384, 256, 0, stream>>>(G0, G1, G2, G3);
  k_tr<<<dim3(512, 8), 256, 0, stream>>>(G3, G4, nullptr, BS, 128, 32768, 1, BS, 8192, 1, 64, 64, 128);
  k_rowmm<64, 128, 1, 64><<<1024, 256, 0, stream>>>(G4, ff1w, ff1b, G5);
  k_rowmm<128, 64, 0, 32><<<2048, 256, 0, stream>>>(G5, ff2w, ff2b, G4);
  k_tr<<<dim3(512, 8), 256, 0, stream>>>(G4, out, G3, BS, 8192, 64, 1, BS, 128, 1, 32768, 128, 64);
  k_gn_part<<<dim3(64, 8), 256, 0, stream>>>(out, nullptr, part);
  k_gn_final<<<8, 64, 0, stream>>>(part, stats);
  k_gn_apply<<<16384, 256, 0, stream>>>(out, nullptr, stats, gn2g, gn2b, out);
}

// Round 5
// 787.548 us; speedup vs baseline: 3.0289x; 1.1144x over previous
//
#include <hip/hip_runtime.h>
#include <math.h>

constexpr int CC = 64, KK = 256, LL = 128;
constexpr int NN = KK * LL;          // 32768
constexpr int PR = 64;               // Linformer projection
constexpr int CPG = 16;              // channels per group (C / 4)
constexpr float EPSV = 1e-5f;
constexpr float SCL = 0.35355339059327373f;  // 1/sqrt(8)

typedef __attribute__((ext_vector_type(8))) short short8;      // 8 bf16 (4 VGPR)
typedef __attribute__((ext_vector_type(4))) float f32x4;       // MFMA 16x16 acc

__device__ __forceinline__ unsigned short f2bf(float x) {
  union { float f; unsigned int u; } v; v.f = x;
  unsigned int r = (v.u + 0x7FFFu + ((v.u >> 16) & 1u)) >> 16;
  return (unsigned short)r;
}

// ---------------- adaptive adjacency: softmax(relu(nv1@nv2), axis=1) ----------------
__global__ __launch_bounds__(256) void k_adp(const float* __restrict__ nv1,
                                             const float* __restrict__ nv2,
                                             float* __restrict__ adp) {
  int w = blockIdx.x, v = threadIdx.x;
  float s = 0.f;
  for (int d = 0; d < 10; ++d) s += nv1[w * 10 + d] * nv2[d * KK + v];
  s = fmaxf(s, 0.f);
  __shared__ float red[256];
  red[v] = s; __syncthreads();
  for (int off = 128; off; off >>= 1) { if (v < off) red[v] = fmaxf(red[v], red[v + off]); __syncthreads(); }
  float m = red[0]; __syncthreads();
  float e = expf(s - m);
  red[v] = e; __syncthreads();
  for (int off = 128; off; off >>= 1) { if (v < off) red[v] += red[v + off]; __syncthreads(); }
  adp[w * KK + v] = e / red[0];
}

// ---------------- fp32 -> bf16 cast (adjacency matrices) ----------------
__global__ __launch_bounds__(256) void k_cast(const float* __restrict__ src,
                                              unsigned short* __restrict__ dst) {
  int i = blockIdx.x * 256 + threadIdx.x;
  dst[i] = f2bf(src[i]);
}

// ---------------- X (bc, v=256, l=128) fp32 -> XT (bc, l=128, v=256) bf16 ----------------
__global__ __launch_bounds__(256) void k_castT(const float* __restrict__ src,
                                               unsigned short* __restrict__ dst) {
  int bc = blockIdx.x;
  int tv = blockIdx.y >> 2, tl = blockIdx.y & 3;
  int v0 = tv * 32, l0 = tl * 32;
  __shared__ float s[32][33];
  int tx = threadIdx.x & 31, ty = threadIdx.x >> 5;
  const float* sp = src + (size_t)bc * NN;
#pragma unroll
  for (int j = 0; j < 4; ++j)
    s[ty + j * 8][tx] = sp[(size_t)(v0 + ty + j * 8) * 128 + l0 + tx];
  __syncthreads();
  unsigned short* dp = dst + (size_t)bc * NN;
#pragma unroll
  for (int j = 0; j < 4; ++j)
    dp[(size_t)(l0 + ty + j * 8) * 256 + v0 + tx] = f2bf(s[tx][ty + j * 8]);
}

// ---------------- out[bc, w, l] = sum_v A[w,v] * XT[bc, l, v]  (bf16 MFMA 16x16x32) ----------------
// grid: 256 = (bc=128) x (l-half=2); 256 threads = 4 waves; wave: 64 w-rows x 64 l-cols (4x4 16-tiles).
// Layouts (all ladder-verified for 16x16x32): A row = lane&15, k = (lane>>4)*8+i (contig);
// B col = lane&15, k = (lane>>4)*8+i (contig along v of XT); D col = lane&15, row = (lane>>4)*4+reg.
__global__ __launch_bounds__(256) void k_adjM(const unsigned short* __restrict__ Abf,
                                              const unsigned short* __restrict__ XT,
                                              float* __restrict__ out) {
  int lh = blockIdx.x & 1, bc = blockIdx.x >> 1;
  int tid = threadIdx.x, wid = tid >> 6, lane = tid & 63;
  int lr = lane & 15, g = lane >> 4;
  int wbase = wid * 64;
  const unsigned short* aP = Abf + (size_t)(wbase + lr) * 256 + g * 8;
  const unsigned short* bP = XT + ((size_t)bc * 128 + lh * 64 + lr) * 256 + g * 8;
  f32x4 acc[4][4];
#pragma unroll
  for (int i = 0; i < 4; ++i)
#pragma unroll
    for (int j = 0; j < 4; ++j) acc[i][j] = f32x4{0.f, 0.f, 0.f, 0.f};
  for (int k0 = 0; k0 < 256; k0 += 32) {
    short8 af[4], bf[4];
#pragma unroll
    for (int i = 0; i < 4; ++i) af[i] = *(const short8*)(aP + (size_t)i * 16 * 256 + k0);
#pragma unroll
    for (int i = 0; i < 4; ++i) bf[i] = *(const short8*)(bP + (size_t)i * 16 * 256 + k0);
#pragma unroll
    for (int rm = 0; rm < 4; ++rm)
#pragma unroll
      for (int cn = 0; cn < 4; ++cn)
        acc[rm][cn] = __builtin_amdgcn_mfma_f32_16x16x32_bf16(af[rm], bf[cn], acc[rm][cn], 0, 0, 0);
  }
  float* dst = out + (size_t)bc * NN + lh * 64;
#pragma unroll
  for (int rm = 0; rm < 4; ++rm)
#pragma unroll
    for (int cn = 0; cn < 4; ++cn) {
      int col = cn * 16 + lr;
      int row = wbase + rm * 16 + g * 4;
#pragma unroll
      for (int j = 0; j < 4; ++j)
        dst[(size_t)(row + j) * 128 + col] = acc[rm][cn][j];
    }
}

// ---------------- fused GCN output: out[b,o,n] = bias[o] + sum_{s,c} W[o][s*64+c]*src_s[b,c,n] ----------------
__global__ __launch_bounds__(256) void k_gcn(const float* __restrict__ W, const float* __restrict__ bias,
                                             const float* __restrict__ s0, const float* __restrict__ s1,
                                             const float* __restrict__ s2, const float* __restrict__ s3,
                                             const float* __restrict__ s4, const float* __restrict__ s5,
                                             const float* __restrict__ s6, float* __restrict__ out) {
  const float* srcs[7] = {s0, s1, s2, s3, s4, s5, s6};
  int t = threadIdx.x;
  size_t nbase = (size_t)blockIdx.x * 256;
  int b = (int)(nbase >> 15);
  size_t n = (nbase & (size_t)(NN - 1)) + t;
  __shared__ float sW[64][68];     // [c][o], padded
  float acc[64];
#pragma unroll
  for (int o = 0; o < 64; ++o) acc[o] = bias[o];
  for (int s = 0; s < 7; ++s) {
    __syncthreads();
    for (int i = t; i < 4096; i += 256) {
      int c = i >> 6, o = i & 63;
      sW[c][o] = W[(size_t)o * 448 + s * 64 + c];
    }
    __syncthreads();
    const float* sp = srcs[s] + (size_t)b * CC * NN + n;
    for (int c = 0; c < 64; c += 4) {
      float x0 = sp[(size_t)(c + 0) * NN];
      float x1 = sp[(size_t)(c + 1) * NN];
      float x2 = sp[(size_t)(c + 2) * NN];
      float x3 = sp[(size_t)(c + 3) * NN];
#pragma unroll
      for (int og = 0; og < 16; ++og) {
        float4 w0 = *(const float4*)&sW[c + 0][og * 4];
        float4 w1 = *(const float4*)&sW[c + 1][og * 4];
        float4 w2 = *(const float4*)&sW[c + 2][og * 4];
        float4 w3 = *(const float4*)&sW[c + 3][og * 4];
        acc[og * 4 + 0] += w0.x * x0 + w1.x * x1 + w2.x * x2 + w3.x * x3;
        acc[og * 4 + 1] += w0.y * x0 + w1.y * x1 + w2.y * x2 + w3.y * x3;
        acc[og * 4 + 2] += w0.z * x0 + w1.z * x1 + w2.z * x2 + w3.z * x3;
        acc[og * 4 + 3] += w0.w * x0 + w1.w * x1 + w2.w * x2 + w3.w * x3;
      }
    }
  }
  float* dst = out + (size_t)b * CC * NN + n;
#pragma unroll
  for (int o = 0; o < 64; ++o) dst[(size_t)o * NN] = acc[o];
}

// ---------------- generic (c,l)-plane transpose per (b,k), optional add (indexed like dst) ----------------
__global__ __launch_bounds__(256) void k_tr(const float* __restrict__ src, float* __restrict__ dst,
                                            const float* __restrict__ add,
                                            long sb, long sk, long sc, long sl,
                                            long db, long dk, long dc, long dl, int nC, int nL) {
  int outer = blockIdx.x;
  int b = outer >> 8, k = outer & 255;
  int tilesL = nL >> 5;
  int tC = blockIdx.y / tilesL, tL = blockIdx.y % tilesL;
  int c0 = tC << 5, l0 = tL << 5;
  __shared__ float s[32][33];
  int tx = threadIdx.x & 31, ty = threadIdx.x >> 5;
  const float* sp = src + (long)b * sb + (long)k * sk;
#pragma unroll
  for (int j = 0; j < 4; ++j) {
    int cc = c0 + ty + j * 8;
    s[ty + j * 8][tx] = sp[(long)cc * sc + (long)(l0 + tx) * sl];
  }
  __syncthreads();
  long dbase = (long)b * db + (long)k * dk;
#pragma unroll
  for (int j = 0; j < 4; ++j) {
    int ll = l0 + ty + j * 8;
    long off = dbase + (long)(c0 + tx) * dc + (long)ll * dl;
    float val = s[tx][ty + j * 8];
    if (add) val += add[off];
    dst[off] = val;
  }
}

// ---------------- row-major (R,CIN) @ (CIN,COUT) + bias, optional activation ----------------
template <int CIN, int COUT, int ACT, int ROWS>
__global__ __launch_bounds__(256) void k_rowmm(const float* __restrict__ in,
                                               const float* __restrict__ W,
                                               const float* __restrict__ bias,
                                               float* __restrict__ out) {
  int r0 = blockIdx.x * ROWS;
  __shared__ float sInT[CIN][ROWS + 4];
  __shared__ float sW[CIN][COUT];
  int t = threadIdx.x;
  for (int i = t; i < CIN * COUT; i += 256) ((float*)sW)[i] = W[i];
  for (int i = t; i < ROWS * CIN; i += 256) {
    int r = i / CIN, c = i % CIN;
    sInT[c][r] = in[(size_t)r0 * CIN + i];
  }
  __syncthreads();
  constexpr int NRG = 256 / COUT;
  constexpr int RPT = ROWS / NRG;
  int col = t % COUT, rg = t / COUT;
  int rbase = rg * RPT;
  float acc[RPT];
  float bv = bias ? bias[col] : 0.f;
#pragma unroll
  for (int r = 0; r < RPT; ++r) acc[r] = bv;
  for (int c = 0; c < CIN; ++c) {
    float wv = sW[c][col];
    if constexpr (RPT % 4 == 0) {
#pragma unroll
      for (int rr = 0; rr < RPT; rr += 4) {
        float4 xv = *(const float4*)&sInT[c][rbase + rr];
        acc[rr] += xv.x * wv; acc[rr + 1] += xv.y * wv;
        acc[rr + 2] += xv.z * wv; acc[rr + 3] += xv.w * wv;
      }
    } else {
#pragma unroll
      for (int rr = 0; rr < RPT; ++rr) acc[rr] += sInT[c][rbase + rr] * wv;
    }
  }
#pragma unroll
  for (int rr = 0; rr < RPT; ++rr) {
    float v = acc[rr];
    if (ACT == 1) v = fmaxf(v, 0.f);
    if (ACT == 2) v = 0.5f * v * (1.f + erff(v * 0.70710678118654752440f));
    out[(size_t)(r0 + rbase + rr) * COUT + col] = v;
  }
}

// ---------------- kp2[bl,p,c] = sum_n X[bl,n,c] * P[n,p] ----------------
__global__ __launch_bounds__(256) void k_sproj(const float* __restrict__ X,
                                               const float* __restrict__ P,
                                               float* __restrict__ out) {
  int bl = blockIdx.x;
  const float* src = X + (size_t)bl * KK * CC;
  float* dst = out + (size_t)bl * PR * CC;
  int t = threadIdx.x, c = t & 63, pg = t >> 6;
  __shared__ float sX[64][CC];
  __shared__ float sP[64][PR];
  float acc[16];
#pragma unroll
  for (int i = 0; i < 16; ++i) acc[i] = 0.f;
  for (int n0 = 0; n0 < KK; n0 += 64) {
    for (int i = t; i < 64 * CC; i += 256) ((float*)sX)[i] = src[(size_t)n0 * CC + i];
    for (int i = t; i < 64 * PR; i += 256) ((float*)sP)[i] = P[(size_t)n0 * PR + i];
    __syncthreads();
    for (int n = 0; n < 64; ++n) {
      float xv = sX[n][c];
#pragma unroll
      for (int q = 0; q < 4; ++q) {
        float4 pv = *(const float4*)&sP[n][pg * 16 + q * 4];
        acc[q * 4 + 0] += pv.x * xv; acc[q * 4 + 1] += pv.y * xv;
        acc[q * 4 + 2] += pv.z * xv; acc[q * 4 + 3] += pv.w * xv;
      }
    }
    __syncthreads();
  }
#pragma unroll
  for (int i = 0; i < 16; ++i) dst[(size_t)(pg * 16 + i) * CC + c] = acc[i];
}

// ---------------- spatial attention: one wave per (b,l,h); 4 k-rows per thread ----------------
__global__ __launch_bounds__(64) void k_sattn(const float* __restrict__ Q, const float* __restrict__ KP,
                                              const float* __restrict__ VP, float* __restrict__ O) {
  int blk = blockIdx.x;
  int h = blk & 7, bl = blk >> 3;
  int t = threadIdx.x;
  __shared__ float sK[PR][8], sV[PR][8];
  {
    const float* kr = KP + ((size_t)bl * PR + t) * CC + h * 8;
    const float* vr = VP + ((size_t)bl * PR + t) * CC + h * 8;
    *(float4*)&sK[t][0] = *(const float4*)kr;
    *(float4*)&sK[t][4] = *(const float4*)(kr + 4);
    *(float4*)&sV[t][0] = *(const float4*)vr;
    *(float4*)&sV[t][4] = *(const float4*)(vr + 4);
  }
  __syncthreads();
  float q[4][8], o[4][8], sum[4];
#pragma unroll
  for (int j = 0; j < 4; ++j) {
    const float* qr = Q + ((size_t)bl * KK + j * 64 + t) * CC + h * 8;
    float4 qa = *(const float4*)qr, qb = *(const float4*)(qr + 4);
    q[j][0] = qa.x * SCL; q[j][1] = qa.y * SCL; q[j][2] = qa.z * SCL; q[j][3] = qa.w * SCL;
    q[j][4] = qb.x * SCL; q[j][5] = qb.y * SCL; q[j][6] = qb.z * SCL; q[j][7] = qb.w * SCL;
    sum[j] = 0.f;
#pragma unroll
    for (int d = 0; d < 8; ++d) o[j][d] = 0.f;
  }
  for (int p = 0; p < PR; ++p) {
    float4 ka = *(const float4*)&sK[p][0], kb = *(const float4*)&sK[p][4];
    float4 va = *(const float4*)&sV[p][0], vb = *(const float4*)&sV[p][4];
    float k[8] = {ka.x, ka.y, ka.z, ka.w, kb.x, kb.y, kb.z, kb.w};
    float v[8] = {va.x, va.y, va.z, va.w, vb.x, vb.y, vb.z, vb.w};
#pragma unroll
    for (int j = 0; j < 4; ++j) {
      float s = 0.f;
#pragma unroll
      for (int d = 0; d < 8; ++d) s += q[j][d] * k[d];
      float e = __expf(s);
      sum[j] += e;
#pragma unroll
      for (int d = 0; d < 8; ++d) o[j][d] += e * v[d];
    }
  }
#pragma unroll
  for (int j = 0; j < 4; ++j) {
    float inv = 1.f / sum[j];
    float* orow = O + ((size_t)bl * KK + j * 64 + t) * CC + h * 8;
    float4 ra = {o[j][0] * inv, o[j][1] * inv, o[j][2] * inv, o[j][3] * inv};
    float4 rb = {o[j][4] * inv, o[j][5] * inv, o[j][6] * inv, o[j][7] * inv};
    *(float4*)orow = ra; *(float4*)(orow + 4) = rb;
  }
}

// ---------------- temporal attention: one wave per (b,k,h); 2 l-rows per thread ----------------
__global__ __launch_bounds__(64) void k_tattn(const float* __restrict__ Q, const float* __restrict__ Kt,
                                              const float* __restrict__ Vt, float* __restrict__ O) {
  int blk = blockIdx.x;
  int h = blk & 7, bk = blk >> 3;
  int t = threadIdx.x;
  __shared__ float sK[LL][8], sV[LL][8];
#pragma unroll
  for (int j = 0; j < 2; ++j) {
    int r = j * 64 + t;
    const float* kr = Kt + ((size_t)bk * LL + r) * CC + h * 8;
    const float* vr = Vt + ((size_t)bk * LL + r) * CC + h * 8;
    *(float4*)&sK[r][0] = *(const float4*)kr;
    *(float4*)&sK[r][4] = *(const float4*)(kr + 4);
    *(float4*)&sV[r][0] = *(const float4*)vr;
    *(float4*)&sV[r][4] = *(const float4*)(vr + 4);
  }
  __syncthreads();
  float q[2][8], o[2][8], sum[2];
#pragma unroll
  for (int j = 0; j < 2; ++j) {
    const float* qr = Q + ((size_t)bk * LL + j * 64 + t) * CC + h * 8;
    float4 qa = *(const float4*)qr, qb = *(const float4*)(qr + 4);
    q[j][0] = qa.x * SCL; q[j][1] = qa.y * SCL; q[j][2] = qa.z * SCL; q[j][3] = qa.w * SCL;
    q[j][4] = qb.x * SCL; q[j][5] = qb.y * SCL; q[j][6] = qb.z * SCL; q[j][7] = qb.w * SCL;
    sum[j] = 0.f;
#pragma unroll
    for (int d = 0; d < 8; ++d) o[j][d] = 0.f;
  }
  for (int p = 0; p < LL; ++p) {
    float4 ka = *(const float4*)&sK[p][0], kb = *(const float4*)&sK[p][4];
    float4 va = *(const float4*)&sV[p][0], vb = *(const float4*)&sV[p][4];
    float k[8] = {ka.x, ka.y, ka.z, ka.w, kb.x, kb.y, kb.z, kb.w};
    float v[8] = {va.x, va.y, va.z, va.w, vb.x, vb.y, vb.z, vb.w};
#pragma unroll
    for (int j = 0; j < 2; ++j) {
      float s = 0.f;
#pragma unroll
      for (int d = 0; d < 8; ++d) s += q[j][d] * k[d];
      float e = __expf(s);
      sum[j] += e;
#pragma unroll
      for (int d = 0; d < 8; ++d) o[j][d] += e * v[d];
    }
  }
#pragma unroll
  for (int j = 0; j < 2; ++j) {
    float inv = 1.f / sum[j];
    float* orow = O + ((size_t)bk * LL + j * 64 + t) * CC + h * 8;
    float4 ra = {o[j][0] * inv, o[j][1] * inv, o[j][2] * inv, o[j][3] * inv};
    float4 rb = {o[j][4] * inv, o[j][5] * inv, o[j][6] * inv, o[j][7] * inv};
    *(float4*)orow = ra; *(float4*)(orow + 4) = rb;
  }
}

// ---------------- LayerNorm over C=64 per row, input = A (+ optional Bp) ----------------
__global__ __launch_bounds__(256) void k_ln(const float* __restrict__ A, const float* __restrict__ Bp,
                                            const float* __restrict__ g, const float* __restrict__ be,
                                            float* __restrict__ out) {
  int row = blockIdx.x * 4 + (threadIdx.x >> 6);
  int c = threadIdx.x & 63;
  size_t idx = (size_t)row * CC + c;
  float x = A[idx] + (Bp ? Bp[idx] : 0.f);
  float s = x, ss = x * x;
#pragma unroll
  for (int off = 32; off; off >>= 1) { s += __shfl_xor(s, off); ss += __shfl_xor(ss, off); }
  float mu = s * (1.f / 64.f);
  float var = ss * (1.f / 64.f) - mu * mu;
  out[idx] = (x - mu) * rsqrtf(var + EPSV) * g[c] + be[c];
}

// ---------------- GroupNorm: deterministic two-phase stats ----------------
__global__ __launch_bounds__(256) void k_gn_part(const float* __restrict__ p0, const float* __restrict__ p1,
                                                 float* __restrict__ part) {
  int bg = blockIdx.y, blk = blockIdx.x, t = threadIdx.x;
  size_t start = (size_t)bg * ((size_t)CPG * NN) + (size_t)blk * 8192;
  float s = 0.f, ss = 0.f;
  for (int i = t; i < 8192; i += 256) {
    float x = p0[start + i];
    if (p1) x += p1[start + i];
    s += x; ss += x * x;
  }
  __shared__ float rs[256], rq[256];
  rs[t] = s; rq[t] = ss; __syncthreads();
  for (int off = 128; off; off >>= 1) { if (t < off) { rs[t] += rs[t + off]; rq[t] += rq[t + off]; } __syncthreads(); }
  if (t == 0) { part[(bg * 64 + blk) * 2] = rs[0]; part[(bg * 64 + blk) * 2 + 1] = rq[0]; }
}

__global__ __launch_bounds__(64) void k_gn_final(const float* __restrict__ part, float* __restrict__ stats) {
  int bg = blockIdx.x, t = threadIdx.x;
  float s = part[(bg * 64 + t) * 2], ss = part[(bg * 64 + t) * 2 + 1];
#pragma unroll
  for (int off = 32; off; off >>= 1) { s += __shfl_xor(s, off); ss += __shfl_xor(ss, off); }
  if (t == 0) {
    float inv = 1.f / (float)((size_t)CPG * NN);
    float mu = s * inv;
    float var = ss * inv - mu * mu;
    stats[bg * 2] = mu;
    stats[bg * 2 + 1] = rsqrtf(var + EPSV);
  }
}

// out = GN(p0 (+p1)) (+ q0) (+ q1)
__global__ __launch_bounds__(256) void k_gn_apply(const float* __restrict__ p0, const float* __restrict__ p1,
                                                  const float* __restrict__ stats, const float* __restrict__ g,
                                                  const float* __restrict__ be,
                                                  const float* __restrict__ q0, const float* __restrict__ q1,
                                                  float* __restrict__ out) {
  size_t i = (size_t)blockIdx.x * 256 + threadIdx.x;
  int chan = (int)(i >> 15) & 63;
  int bg = (int)(i >> 19);
  float x = p0[i];
  if (p1) x += p1[i];
  float v = (x - stats[bg * 2]) * stats[bg * 2 + 1] * g[chan] + be[chan];
  if (q0) v += q0[i];
  if (q1) v += q1[i];
  out[i] = v;
}

extern "C" void kernel_launch(void* const* d_in, const int* in_sizes, int n_in,
                              void* d_out, int out_size, void* d_ws, size_t ws_size,
                              hipStream_t stream) {
  (void)in_sizes; (void)n_in; (void)out_size; (void)ws_size;
  const float* y     = (const float*)d_in[0];
  const float* a1    = (const float*)d_in[1];
  const float* a2    = (const float*)d_in[2];
  const float* nv1   = (const float*)d_in[3];
  const float* nv2   = (const float*)d_in[4];
  const float* gcn_w = (const float*)d_in[5];
  const float* gcn_b = (const float*)d_in[6];
  const float* s_wq  = (const float*)d_in[7];
  const float* s_wk  = (const float*)d_in[8];
  const float* s_wv  = (const float*)d_in[9];
  const float* s_pk  = (const float*)d_in[10];
  const float* s_pv  = (const float*)d_in[11];
  const float* s_wo  = (const float*)d_in[12];
  const float* s_bo  = (const float*)d_in[13];
  const float* t_wq  = (const float*)d_in[14];
  const float* t_wk  = (const float*)d_in[15];
  const float* t_wv  = (const float*)d_in[16];
  const float* t_bq  = (const float*)d_in[17];
  const float* t_bk  = (const float*)d_in[18];
  const float* t_bv  = (const float*)d_in[19];
  const float* t_wo  = (const float*)d_in[20];
  const float* t_bo  = (const float*)d_in[21];
  const float* t_l1w = (const float*)d_in[22];
  const float* t_l1b = (const float*)d_in[23];
  const float* t_l2w = (const float*)d_in[24];
  const float* t_l2b = (const float*)d_in[25];
  const float* ln1g  = (const float*)d_in[26];
  const float* ln1b  = (const float*)d_in[27];
  const float* ln2g  = (const float*)d_in[28];
  const float* ln2b  = (const float*)d_in[29];
  const float* gnlg  = (const float*)d_in[30];
  const float* gnlb  = (const float*)d_in[31];
  const float* gnsg  = (const float*)d_in[32];
  const float* gnsb  = (const float*)d_in[33];
  const float* gntg  = (const float*)d_in[34];
  const float* gntb  = (const float*)d_in[35];
  const float* ff1w  = (const float*)d_in[36];
  const float* ff1b  = (const float*)d_in[37];
  const float* ff2w  = (const float*)d_in[38];
  const float* ff2b  = (const float*)d_in[39];
  const float* gn2g  = (const float*)d_in[40];
  const float* gn2b  = (const float*)d_in[41];

  float* ws = (float*)d_ws;
  float* adp   = ws;                                    // [0, 65536)
  float* part  = ws + 65536;                            // [65536, 66560)
  float* stats = ws + 66560;                            // 16
  unsigned short* a1_bf  = (unsigned short*)(ws + 131072);   // 32768 floats
  unsigned short* a2_bf  = (unsigned short*)(ws + 163840);
  unsigned short* adp_bf = (unsigned short*)(ws + 196608);
  unsigned short* yT_bf  = (unsigned short*)(ws + 262144);   // 2M floats [262144, 2359296)
  // later-phase scratch (GCN-section buffers above are dead by then):
  float* kp2 = ws + 131072;                             // 1M floats
  float* vp2 = ws + 131072 + 1048576;
  float* ffh = ws + 2228224;                            // 512K floats
  const size_t SLOT = 4194304;
  float* G0 = ws + SLOT * 1;
  unsigned short* h1T_g = (unsigned short*)G0;          // borrows G0's slot; dead before k_gcn writes G0
  float* G1 = ws + SLOT * 2;
  float* G2 = ws + SLOT * 3;
  float* G3 = ws + SLOT * 4;
  float* G4 = ws + SLOT * 5;
  float* G5 = ws + SLOT * 6;
  float* G6 = ws + SLOT * 7;
  float* out = (float*)d_out;

  const long BS = 2097152;  // per-batch stride of a 16MB tensor in floats

  // ---- adaptive adjacency + bf16 casts ----
  k_adp<<<256, 256, 0, stream>>>(nv1, nv2, adp);
  k_cast<<<256, 256, 0, stream>>>(a1, a1_bf);
  k_cast<<<256, 256, 0, stream>>>(a2, a2_bf);
  k_cast<<<256, 256, 0, stream>>>(adp, adp_bf);
  k_castT<<<dim3(128, 32), 256, 0, stream>>>(y, yT_bf);

  // ---- AdaptiveGCN: per adjacency, hop1 GEMM -> transpose-cast -> hop2 GEMM ----
  k_adjM<<<256, 256, 0, stream>>>(a1_bf, yT_bf, G1);
  k_castT<<<dim3(128, 32), 256, 0, stream>>>(G1, h1T_g);
  k_adjM<<<256, 256, 0, stream>>>(a1_bf, h1T_g, G2);
  k_adjM<<<256, 256, 0, stream>>>(a2_bf, yT_bf, G3);
  k_castT<<<dim3(128, 32), 256, 0, stream>>>(G3, h1T_g);
  k_adjM<<<256, 256, 0, stream>>>(a2_bf, h1T_g, G4);
  k_adjM<<<256, 256, 0, stream>>>(adp_bf, yT_bf, G5);
  k_castT<<<dim3(128, 32), 256, 0, stream>>>(G5, h1T_g);
  k_adjM<<<256, 256, 0, stream>>>(adp_bf, h1T_g, G6);
  k_gcn<<<256, 256, 0, stream>>>(gcn_w, gcn_b, y, G1, G2, G3, G4, G5, G6, G0);
  k_gn_part<<<dim3(64, 8), 256, 0, stream>>>(y, G0, part);
  k_gn_final<<<8, 64, 0, stream>>>(part, stats);
  k_gn_apply<<<16384, 256, 0, stream>>>(y, G0, stats, gnlg, gnlb, nullptr, nullptr, G0);

  // ---- Linformer spatial attention ----
  k_tr<<<dim3(512, 8), 256, 0, stream>>>(y, G2, nullptr, BS, 128, 32768, 1, BS, 64, 1, 16384, 64, 128);
  k_rowmm<64, 64, 0, 64><<<1024, 256, 0, stream>>>(G2, s_wq, nullptr, G3);
  k_rowmm<64, 64, 0, 64><<<1024, 256, 0, stream>>>(G2, s_wk, nullptr, G4);
  k_rowmm<64, 64, 0, 64><<<1024, 256, 0, stream>>>(G2, s_wv, nullptr, G5);
  k_sproj<<<256, 256, 0, stream>>>(G4, s_pk, kp2);
  k_sproj<<<256, 256, 0, stream>>>(G5, s_pv, vp2);
  k_sattn<<<2048, 64, 0, stream>>>(G3, kp2, vp2, G6);
  k_rowmm<64, 64, 0, 64><<<1024, 256, 0, stream>>>(G6, s_wo, s_bo, G4);
  k_tr<<<dim3(512, 8), 256, 0, stream>>>(G4, G1, nullptr, BS, 64, 16384, 1, BS, 128, 1, 32768, 128, 64);
  k_gn_part<<<dim3(64, 8), 256, 0, stream>>>(y, G1, part);
  k_gn_final<<<8, 64, 0, stream>>>(part, stats);
  k_gn_apply<<<16384, 256, 0, stream>>>(y, G1, stats, gnsg, gnsb, nullptr, nullptr, G1);

  // ---- temporal transformer layer ----
  k_tr<<<dim3(512, 8), 256, 0, stream>>>(y, G2, nullptr, BS, 128, 32768, 1, BS, 8192, 1, 64, 64, 128);
  k_rowmm<64, 64, 0, 64><<<1024, 256, 0, stream>>>(G2, t_wq, t_bq, G3);
  k_rowmm<64, 64, 0, 64><<<1024, 256, 0, stream>>>(G2, t_wk, t_bk, G4);
  k_rowmm<64, 64, 0, 64><<<1024, 256, 0, stream>>>(G2, t_wv, t_bv, G5);
  k_tattn<<<4096, 64, 0, stream>>>(G3, G4, G5, G6);
  k_rowmm<64, 64, 0, 64><<<1024, 256, 0, stream>>>(G6, t_wo, t_bo, G3);
  k_ln<<<16384, 256, 0, stream>>>(G2, G3, ln1g, ln1b, G4);
  k_rowmm<64, 8, 2, 64><<<1024, 256, 0, stream>>>(G4, t_l1w, t_l1b, ffh);
  k_rowmm<8, 64, 0, 64><<<1024, 256, 0, stream>>>(ffh, t_l2w, t_l2b, G5);
  k_ln<<<16384, 256, 0, stream>>>(G4, G5, ln2g, ln2b, G6);
  k_tr<<<dim3(512, 8), 256, 0, stream>>>(G6, G2, nullptr, BS, 8192, 64, 1, BS, 128, 1, 32768, 128, 64);
  k_gn_part<<<dim3(64, 8), 256, 0, stream>>>(y, G2, part);
  k_gn_final<<<8, 64, 0, stream>>>(part, stats);
  // y_in2 = GN(y + y_t_pre) + G0 + G1  -> G3
  k_gn_apply<<<16384, 256, 0, stream>>>(y, G2, stats, gntg, gntb, G0, G1, G3);

  // ---- fuse + channel FFN + final GroupNorm ----
  k_tr<<<dim3(512, 8), 256, 0, stream>>>(G3, G4, nullptr, BS, 128, 32768, 1, BS, 8192, 1, 64, 64, 128);
  k_rowmm<64, 128, 1, 64><<<1024, 256, 0, stream>>>(G4, ff1w, ff1b, G5);
  k_rowmm<128, 64, 0, 32><<<2048, 256, 0, stream>>>(G5, ff2w, ff2b, G4);
  k_tr<<<dim3(512, 8), 256, 0, stream>>>(G4, out, G3, BS, 8192, 64, 1, BS, 128, 1, 32768, 128, 64);
  k_gn_part<<<dim3(64, 8), 256, 0, stream>>>(out, nullptr, part);
  k_gn_final<<<8, 64, 0, stream>>>(part, stats);
  k_gn_apply<<<16384, 256, 0, stream>>>(out, nullptr, stats, gn2g, gn2b, nullptr, nullptr, out);
}

// Round 6
// 729.995 us; speedup vs baseline: 3.2677x; 1.0788x over previous
//
#include <hip/hip_runtime.h>
#include <math.h>

constexpr int CC = 64, KK = 256, LL = 128;
constexpr int NN = KK * LL;          // 32768
constexpr int PR = 64;               // Linformer projection
constexpr int CPG = 16;              // channels per group (C / 4)
constexpr float EPSV = 1e-5f;
constexpr float SCL = 0.35355339059327373f;  // 1/sqrt(8)

typedef __attribute__((ext_vector_type(8))) short short8;      // 8 bf16 (4 VGPR)
typedef __attribute__((ext_vector_type(4))) float f32x4;       // MFMA 16x16 acc

__device__ __forceinline__ unsigned short f2bf(float x) {
  union { float f; unsigned int u; } v; v.f = x;
  unsigned int r = (v.u + 0x7FFFu + ((v.u >> 16) & 1u)) >> 16;
  return (unsigned short)r;
}

// ---------------- adaptive adjacency: softmax(relu(nv1@nv2), axis=1) ----------------
__global__ __launch_bounds__(256) void k_adp(const float* __restrict__ nv1,
                                             const float* __restrict__ nv2,
                                             float* __restrict__ adp) {
  int w = blockIdx.x, v = threadIdx.x;
  float s = 0.f;
  for (int d = 0; d < 10; ++d) s += nv1[w * 10 + d] * nv2[d * KK + v];
  s = fmaxf(s, 0.f);
  __shared__ float red[256];
  red[v] = s; __syncthreads();
  for (int off = 128; off; off >>= 1) { if (v < off) red[v] = fmaxf(red[v], red[v + off]); __syncthreads(); }
  float m = red[0]; __syncthreads();
  float e = expf(s - m);
  red[v] = e; __syncthreads();
  for (int off = 128; off; off >>= 1) { if (v < off) red[v] += red[v + off]; __syncthreads(); }
  adp[w * KK + v] = e / red[0];
}

// ---------------- fp32 -> bf16 cast ----------------
__global__ __launch_bounds__(256) void k_cast(const float* __restrict__ src,
                                              unsigned short* __restrict__ dst) {
  int i = blockIdx.x * 256 + threadIdx.x;
  dst[i] = f2bf(src[i]);
}

// ---------------- X (bc, v=256, l=128) fp32 -> XT (bc, l=128, v=256) bf16 ----------------
__global__ __launch_bounds__(256) void k_castT(const float* __restrict__ src,
                                               unsigned short* __restrict__ dst) {
  int bc = blockIdx.x;
  int tv = blockIdx.y >> 2, tl = blockIdx.y & 3;
  int v0 = tv * 32, l0 = tl * 32;
  __shared__ float s[32][33];
  int tx = threadIdx.x & 31, ty = threadIdx.x >> 5;
  const float* sp = src + (size_t)bc * NN;
#pragma unroll
  for (int j = 0; j < 4; ++j)
    s[ty + j * 8][tx] = sp[(size_t)(v0 + ty + j * 8) * 128 + l0 + tx];
  __syncthreads();
  unsigned short* dp = dst + (size_t)bc * NN;
#pragma unroll
  for (int j = 0; j < 4; ++j)
    dp[(size_t)(l0 + ty + j * 8) * 256 + v0 + tx] = f2bf(s[tx][ty + j * 8]);
}

// ---------------- out[bc, w, l] = sum_v A[w,v] * XT[bc, l, v]  (bf16 MFMA 16x16x32) ----------------
// grid: 512 = (bc=128) x (l-quarter=4); 256 threads = 4 waves; wave: 64 w-rows x 32 l-cols.
// Optional outT: bf16 transposed [l][v] plane for the next hop's B operand (fuses castT).
__global__ __launch_bounds__(256) void k_adjM(const unsigned short* __restrict__ Abf,
                                              const unsigned short* __restrict__ XT,
                                              float* __restrict__ out,
                                              unsigned short* __restrict__ outT) {
  int lq = blockIdx.x & 3, bc = blockIdx.x >> 2;
  int tid = threadIdx.x, wid = tid >> 6, lane = tid & 63;
  int lr = lane & 15, g = lane >> 4;
  int wbase = wid * 64;
  const unsigned short* aP = Abf + (size_t)(wbase + lr) * 256 + g * 8;
  const unsigned short* bP = XT + ((size_t)bc * 128 + lq * 32 + lr) * 256 + g * 8;
  f32x4 acc[4][2];
#pragma unroll
  for (int i = 0; i < 4; ++i)
#pragma unroll
    for (int j = 0; j < 2; ++j) acc[i][j] = f32x4{0.f, 0.f, 0.f, 0.f};
  for (int k0 = 0; k0 < 256; k0 += 32) {
    short8 af[4], bf[2];
#pragma unroll
    for (int i = 0; i < 4; ++i) af[i] = *(const short8*)(aP + (size_t)i * 16 * 256 + k0);
#pragma unroll
    for (int i = 0; i < 2; ++i) bf[i] = *(const short8*)(bP + (size_t)i * 16 * 256 + k0);
#pragma unroll
    for (int rm = 0; rm < 4; ++rm)
#pragma unroll
      for (int cn = 0; cn < 2; ++cn)
        acc[rm][cn] = __builtin_amdgcn_mfma_f32_16x16x32_bf16(af[rm], bf[cn], acc[rm][cn], 0, 0, 0);
  }
  float* dst = out + (size_t)bc * NN + lq * 32;
#pragma unroll
  for (int rm = 0; rm < 4; ++rm)
#pragma unroll
    for (int cn = 0; cn < 2; ++cn) {
      int col = cn * 16 + lr;
      int row = wbase + rm * 16 + g * 4;
#pragma unroll
      for (int j = 0; j < 4; ++j)
        dst[(size_t)(row + j) * 128 + col] = acc[rm][cn][j];
    }
  if (outT) {
    unsigned short* dT = outT + (size_t)bc * NN + (size_t)(lq * 32) * 256;
#pragma unroll
    for (int rm = 0; rm < 4; ++rm)
#pragma unroll
      for (int cn = 0; cn < 2; ++cn) {
        int l = cn * 16 + lr;
        int v = wbase + rm * 16 + g * 4;
        ushort4 pk;
        pk.x = f2bf(acc[rm][cn][0]); pk.y = f2bf(acc[rm][cn][1]);
        pk.z = f2bf(acc[rm][cn][2]); pk.w = f2bf(acc[rm][cn][3]);
        *(ushort4*)&dT[(size_t)l * 256 + v] = pk;
      }
  }
}

// ---------------- fused GCN output: out[b,o,n] = bias[o] + sum_{s,c} W[o][s*64+c]*src_s[b,c,n] ----------------
// grid: 1024 blocks = 64-n tiles; 256 threads = 64 n x 4 o-groups; acc[16]/thread.
__global__ __launch_bounds__(256) void k_gcn(const float* __restrict__ W, const float* __restrict__ bias,
                                             const float* __restrict__ s0, const float* __restrict__ s1,
                                             const float* __restrict__ s2, const float* __restrict__ s3,
                                             const float* __restrict__ s4, const float* __restrict__ s5,
                                             const float* __restrict__ s6, float* __restrict__ out) {
  const float* srcs[7] = {s0, s1, s2, s3, s4, s5, s6};
  int t = threadIdx.x;
  int nl = t & 63, og = t >> 6;
  size_t nbase = (size_t)blockIdx.x * 64;
  int b = (int)(nbase >> 15);
  size_t n0 = nbase & (size_t)(NN - 1);
  __shared__ float sX[64][64];     // [c][n]
  __shared__ float sW[64][68];     // [c][o], padded
  float acc[16];
#pragma unroll
  for (int i = 0; i < 16; ++i) acc[i] = bias[og * 16 + i];
  for (int s = 0; s < 7; ++s) {
    __syncthreads();
    for (int i = t; i < 4096; i += 256) {
      int c = i >> 6, o = i & 63;
      sW[c][o] = W[(size_t)o * 448 + s * 64 + c];
    }
    const float* sp = srcs[s] + (size_t)b * CC * NN + n0;
    for (int i = t; i < 4096; i += 256) {
      int c = i >> 6, nn = i & 63;
      sX[c][nn] = sp[(size_t)c * NN + nn];
    }
    __syncthreads();
    for (int c = 0; c < 64; ++c) {
      float x = sX[c][nl];
#pragma unroll
      for (int q = 0; q < 4; ++q) {
        float4 wv = *(const float4*)&sW[c][og * 16 + q * 4];
        acc[q * 4 + 0] += wv.x * x;
        acc[q * 4 + 1] += wv.y * x;
        acc[q * 4 + 2] += wv.z * x;
        acc[q * 4 + 3] += wv.w * x;
      }
    }
  }
  float* dst = out + (size_t)b * CC * NN + n0 + nl;
#pragma unroll
  for (int i = 0; i < 16; ++i) dst[(size_t)(og * 16 + i) * NN] = acc[i];
}

// ---------------- generic (c,l)-plane transpose per (b,k), optional add (indexed like dst) ----------------
__global__ __launch_bounds__(256) void k_tr(const float* __restrict__ src, float* __restrict__ dst,
                                            const float* __restrict__ add,
                                            long sb, long sk, long sc, long sl,
                                            long db, long dk, long dc, long dl, int nC, int nL) {
  int outer = blockIdx.x;
  int b = outer >> 8, k = outer & 255;
  int tilesL = nL >> 5;
  int tC = blockIdx.y / tilesL, tL = blockIdx.y % tilesL;
  int c0 = tC << 5, l0 = tL << 5;
  __shared__ float s[32][33];
  int tx = threadIdx.x & 31, ty = threadIdx.x >> 5;
  const float* sp = src + (long)b * sb + (long)k * sk;
#pragma unroll
  for (int j = 0; j < 4; ++j) {
    int cc = c0 + ty + j * 8;
    s[ty + j * 8][tx] = sp[(long)cc * sc + (long)(l0 + tx) * sl];
  }
  __syncthreads();
  long dbase = (long)b * db + (long)k * dk;
#pragma unroll
  for (int j = 0; j < 4; ++j) {
    int ll = l0 + ty + j * 8;
    long off = dbase + (long)(c0 + tx) * dc + (long)ll * dl;
    float val = s[tx][ty + j * 8];
    if (add) val += add[off];
    dst[off] = val;
  }
}

// ---------------- fused QKV row-matmul: (R,64) @ 3x(64,64) (+biases) ----------------
// grid: R/64 blocks, 256 threads.
__global__ __launch_bounds__(256) void k_qkv(const float* __restrict__ in,
                                             const float* __restrict__ W0, const float* __restrict__ W1,
                                             const float* __restrict__ W2,
                                             const float* __restrict__ b0, const float* __restrict__ b1,
                                             const float* __restrict__ b2,
                                             float* __restrict__ o0, float* __restrict__ o1,
                                             float* __restrict__ o2) {
  int r0 = blockIdx.x * 64;
  __shared__ float sInT[64][68];     // [c][r]
  __shared__ float sW[3][64][64];    // [which][c][col]
  int t = threadIdx.x;
  for (int i = t; i < 4096; i += 256) {
    int c = i >> 6, o = i & 63;
    sW[0][c][o] = W0[i];
    sW[1][c][o] = W1[i];
    sW[2][c][o] = W2[i];
  }
  for (int i = t; i < 4096; i += 256) {
    int r = i >> 6, c = i & 63;
    sInT[c][r] = in[(size_t)(r0 + r) * 64 + c];
  }
  __syncthreads();
  int col = t & 63, rg = t >> 6;
  int rbase = rg * 16;
  float a0[16], a1[16], a2[16];
  float bv0 = b0 ? b0[col] : 0.f;
  float bv1 = b1 ? b1[col] : 0.f;
  float bv2 = b2 ? b2[col] : 0.f;
#pragma unroll
  for (int i = 0; i < 16; ++i) { a0[i] = bv0; a1[i] = bv1; a2[i] = bv2; }
  for (int c = 0; c < 64; ++c) {
    float w0 = sW[0][c][col], w1 = sW[1][c][col], w2 = sW[2][c][col];
#pragma unroll
    for (int rr = 0; rr < 16; rr += 4) {
      float4 xv = *(const float4*)&sInT[c][rbase + rr];
      a0[rr + 0] += xv.x * w0; a0[rr + 1] += xv.y * w0; a0[rr + 2] += xv.z * w0; a0[rr + 3] += xv.w * w0;
      a1[rr + 0] += xv.x * w1; a1[rr + 1] += xv.y * w1; a1[rr + 2] += xv.z * w1; a1[rr + 3] += xv.w * w1;
      a2[rr + 0] += xv.x * w2; a2[rr + 1] += xv.y * w2; a2[rr + 2] += xv.z * w2; a2[rr + 3] += xv.w * w2;
    }
  }
#pragma unroll
  for (int rr = 0; rr < 16; ++rr) {
    size_t idx = (size_t)(r0 + rbase + rr) * 64 + col;
    o0[idx] = a0[rr]; o1[idx] = a1[rr]; o2[idx] = a2[rr];
  }
}

// ---------------- row-major (R,CIN) @ (CIN,COUT) + bias, optional activation ----------------
template <int CIN, int COUT, int ACT, int ROWS>
__global__ __launch_bounds__(256) void k_rowmm(const float* __restrict__ in,
                                               const float* __restrict__ W,
                                               const float* __restrict__ bias,
                                               float* __restrict__ out) {
  int r0 = blockIdx.x * ROWS;
  __shared__ float sInT[CIN][ROWS + 4];
  __shared__ float sW[CIN][COUT];
  int t = threadIdx.x;
  for (int i = t; i < CIN * COUT; i += 256) ((float*)sW)[i] = W[i];
  for (int i = t; i < ROWS * CIN; i += 256) {
    int r = i / CIN, c = i % CIN;
    sInT[c][r] = in[(size_t)r0 * CIN + i];
  }
  __syncthreads();
  constexpr int NRG = 256 / COUT;
  constexpr int RPT = ROWS / NRG;
  int col = t % COUT, rg = t / COUT;
  int rbase = rg * RPT;
  float acc[RPT];
  float bv = bias ? bias[col] : 0.f;
#pragma unroll
  for (int r = 0; r < RPT; ++r) acc[r] = bv;
  for (int c = 0; c < CIN; ++c) {
    float wv = sW[c][col];
    if constexpr (RPT % 4 == 0) {
#pragma unroll
      for (int rr = 0; rr < RPT; rr += 4) {
        float4 xv = *(const float4*)&sInT[c][rbase + rr];
        acc[rr] += xv.x * wv; acc[rr + 1] += xv.y * wv;
        acc[rr + 2] += xv.z * wv; acc[rr + 3] += xv.w * wv;
      }
    } else {
#pragma unroll
      for (int rr = 0; rr < RPT; ++rr) acc[rr] += sInT[c][rbase + rr] * wv;
    }
  }
#pragma unroll
  for (int rr = 0; rr < RPT; ++rr) {
    float v = acc[rr];
    if (ACT == 1) v = fmaxf(v, 0.f);
    if (ACT == 2) v = 0.5f * v * (1.f + erff(v * 0.70710678118654752440f));
    out[(size_t)(r0 + rbase + rr) * COUT + col] = v;
  }
}

// ---------------- kp2[bl,p,c] = sum_n X[bl,n,c] * P[n,p] ----------------
__global__ __launch_bounds__(256) void k_sproj(const float* __restrict__ X,
                                               const float* __restrict__ P,
                                               float* __restrict__ out) {
  int bl = blockIdx.x;
  const float* src = X + (size_t)bl * KK * CC;
  float* dst = out + (size_t)bl * PR * CC;
  int t = threadIdx.x, c = t & 63, pg = t >> 6;
  __shared__ float sX[64][CC];
  __shared__ float sP[64][PR];
  float acc[16];
#pragma unroll
  for (int i = 0; i < 16; ++i) acc[i] = 0.f;
  for (int n0 = 0; n0 < KK; n0 += 64) {
    for (int i = t; i < 64 * CC; i += 256) ((float*)sX)[i] = src[(size_t)n0 * CC + i];
    for (int i = t; i < 64 * PR; i += 256) ((float*)sP)[i] = P[(size_t)n0 * PR + i];
    __syncthreads();
    for (int n = 0; n < 64; ++n) {
      float xv = sX[n][c];
#pragma unroll
      for (int q = 0; q < 4; ++q) {
        float4 pv = *(const float4*)&sP[n][pg * 16 + q * 4];
        acc[q * 4 + 0] += pv.x * xv; acc[q * 4 + 1] += pv.y * xv;
        acc[q * 4 + 2] += pv.z * xv; acc[q * 4 + 3] += pv.w * xv;
      }
    }
    __syncthreads();
  }
#pragma unroll
  for (int i = 0; i < 16; ++i) dst[(size_t)(pg * 16 + i) * CC + c] = acc[i];
}

// ---------------- spatial attention: one wave per (b,l,h); 4 k-rows per thread ----------------
__global__ __launch_bounds__(64) void k_sattn(const float* __restrict__ Q, const float* __restrict__ KP,
                                              const float* __restrict__ VP, float* __restrict__ O) {
  int blk = blockIdx.x;
  int h = blk & 7, bl = blk >> 3;
  int t = threadIdx.x;
  __shared__ float sK[PR][8], sV[PR][8];
  {
    const float* kr = KP + ((size_t)bl * PR + t) * CC + h * 8;
    const float* vr = VP + ((size_t)bl * PR + t) * CC + h * 8;
    *(float4*)&sK[t][0] = *(const float4*)kr;
    *(float4*)&sK[t][4] = *(const float4*)(kr + 4);
    *(float4*)&sV[t][0] = *(const float4*)vr;
    *(float4*)&sV[t][4] = *(const float4*)(vr + 4);
  }
  __syncthreads();
  float q[4][8], o[4][8], sum[4];
#pragma unroll
  for (int j = 0; j < 4; ++j) {
    const float* qr = Q + ((size_t)bl * KK + j * 64 + t) * CC + h * 8;
    float4 qa = *(const float4*)qr, qb = *(const float4*)(qr + 4);
    q[j][0] = qa.x * SCL; q[j][1] = qa.y * SCL; q[j][2] = qa.z * SCL; q[j][3] = qa.w * SCL;
    q[j][4] = qb.x * SCL; q[j][5] = qb.y * SCL; q[j][6] = qb.z * SCL; q[j][7] = qb.w * SCL;
    sum[j] = 0.f;
#pragma unroll
    for (int d = 0; d < 8; ++d) o[j][d] = 0.f;
  }
  for (int p = 0; p < PR; ++p) {
    float4 ka = *(const float4*)&sK[p][0], kb = *(const float4*)&sK[p][4];
    float4 va = *(const float4*)&sV[p][0], vb = *(const float4*)&sV[p][4];
    float k[8] = {ka.x, ka.y, ka.z, ka.w, kb.x, kb.y, kb.z, kb.w};
    float v[8] = {va.x, va.y, va.z, va.w, vb.x, vb.y, vb.z, vb.w};
#pragma unroll
    for (int j = 0; j < 4; ++j) {
      float s = 0.f;
#pragma unroll
      for (int d = 0; d < 8; ++d) s += q[j][d] * k[d];
      float e = __expf(s);
      sum[j] += e;
#pragma unroll
      for (int d = 0; d < 8; ++d) o[j][d] += e * v[d];
    }
  }
#pragma unroll
  for (int j = 0; j < 4; ++j) {
    float inv = 1.f / sum[j];
    float* orow = O + ((size_t)bl * KK + j * 64 + t) * CC + h * 8;
    float4 ra = {o[j][0] * inv, o[j][1] * inv, o[j][2] * inv, o[j][3] * inv};
    float4 rb = {o[j][4] * inv, o[j][5] * inv, o[j][6] * inv, o[j][7] * inv};
    *(float4*)orow = ra; *(float4*)(orow + 4) = rb;
  }
}

// ---------------- temporal attention: one wave per (b,k,h); 2 l-rows per thread ----------------
__global__ __launch_bounds__(64) void k_tattn(const float* __restrict__ Q, const float* __restrict__ Kt,
                                              const float* __restrict__ Vt, float* __restrict__ O) {
  int blk = blockIdx.x;
  int h = blk & 7, bk = blk >> 3;
  int t = threadIdx.x;
  __shared__ float sK[LL][8], sV[LL][8];
#pragma unroll
  for (int j = 0; j < 2; ++j) {
    int r = j * 64 + t;
    const float* kr = Kt + ((size_t)bk * LL + r) * CC + h * 8;
    const float* vr = Vt + ((size_t)bk * LL + r) * CC + h * 8;
    *(float4*)&sK[r][0] = *(const float4*)kr;
    *(float4*)&sK[r][4] = *(const float4*)(kr + 4);
    *(float4*)&sV[r][0] = *(const float4*)vr;
    *(float4*)&sV[r][4] = *(const float4*)(vr + 4);
  }
  __syncthreads();
  float q[2][8], o[2][8], sum[2];
#pragma unroll
  for (int j = 0; j < 2; ++j) {
    const float* qr = Q + ((size_t)bk * LL + j * 64 + t) * CC + h * 8;
    float4 qa = *(const float4*)qr, qb = *(const float4*)(qr + 4);
    q[j][0] = qa.x * SCL; q[j][1] = qa.y * SCL; q[j][2] = qa.z * SCL; q[j][3] = qa.w * SCL;
    q[j][4] = qb.x * SCL; q[j][5] = qb.y * SCL; q[j][6] = qb.z * SCL; q[j][7] = qb.w * SCL;
    sum[j] = 0.f;
#pragma unroll
    for (int d = 0; d < 8; ++d) o[j][d] = 0.f;
  }
  for (int p = 0; p < LL; ++p) {
    float4 ka = *(const float4*)&sK[p][0], kb = *(const float4*)&sK[p][4];
    float4 va = *(const float4*)&sV[p][0], vb = *(const float4*)&sV[p][4];
    float k[8] = {ka.x, ka.y, ka.z, ka.w, kb.x, kb.y, kb.z, kb.w};
    float v[8] = {va.x, va.y, va.z, va.w, vb.x, vb.y, vb.z, vb.w};
#pragma unroll
    for (int j = 0; j < 2; ++j) {
      float s = 0.f;
#pragma unroll
      for (int d = 0; d < 8; ++d) s += q[j][d] * k[d];
      float e = __expf(s);
      sum[j] += e;
#pragma unroll
      for (int d = 0; d < 8; ++d) o[j][d] += e * v[d];
    }
  }
#pragma unroll
  for (int j = 0; j < 2; ++j) {
    float inv = 1.f / sum[j];
    float* orow = O + ((size_t)bk * LL + j * 64 + t) * CC + h * 8;
    float4 ra = {o[j][0] * inv, o[j][1] * inv, o[j][2] * inv, o[j][3] * inv};
    float4 rb = {o[j][4] * inv, o[j][5] * inv, o[j][6] * inv, o[j][7] * inv};
    *(float4*)orow = ra; *(float4*)(orow + 4) = rb;
  }
}

// ---------------- LayerNorm over C=64 per row, input = A (+ optional Bp) ----------------
__global__ __launch_bounds__(256) void k_ln(const float* __restrict__ A, const float* __restrict__ Bp,
                                            const float* __restrict__ g, const float* __restrict__ be,
                                            float* __restrict__ out) {
  int row = blockIdx.x * 4 + (threadIdx.x >> 6);
  int c = threadIdx.x & 63;
  size_t idx = (size_t)row * CC + c;
  float x = A[idx] + (Bp ? Bp[idx] : 0.f);
  float s = x, ss = x * x;
#pragma unroll
  for (int off = 32; off; off >>= 1) { s += __shfl_xor(s, off); ss += __shfl_xor(ss, off); }
  float mu = s * (1.f / 64.f);
  float var = ss * (1.f / 64.f) - mu * mu;
  out[idx] = (x - mu) * rsqrtf(var + EPSV) * g[c] + be[c];
}

// ---------------- GroupNorm: deterministic two-phase stats (float4) ----------------
__global__ __launch_bounds__(256) void k_gn_part(const float* __restrict__ p0, const float* __restrict__ p1,
                                                 float* __restrict__ part) {
  int bg = blockIdx.y, blk = blockIdx.x, t = threadIdx.x;
  size_t start = (size_t)bg * ((size_t)CPG * NN) + (size_t)blk * 8192;
  const float4* q0 = (const float4*)(p0 + start);
  const float4* q1 = p1 ? (const float4*)(p1 + start) : nullptr;
  float s = 0.f, ss = 0.f;
  for (int i = t; i < 2048; i += 256) {
    float4 x = q0[i];
    if (q1) { float4 y4 = q1[i]; x.x += y4.x; x.y += y4.y; x.z += y4.z; x.w += y4.w; }
    s += x.x + x.y + x.z + x.w;
    ss += x.x * x.x + x.y * x.y + x.z * x.z + x.w * x.w;
  }
  __shared__ float rs[256], rq[256];
  rs[t] = s; rq[t] = ss; __syncthreads();
  for (int off = 128; off; off >>= 1) { if (t < off) { rs[t] += rs[t + off]; rq[t] += rq[t + off]; } __syncthreads(); }
  if (t == 0) { part[(bg * 64 + blk) * 2] = rs[0]; part[(bg * 64 + blk) * 2 + 1] = rq[0]; }
}

__global__ __launch_bounds__(64) void k_gn_final(const float* __restrict__ part, float* __restrict__ stats) {
  int bg = blockIdx.x, t = threadIdx.x;
  float s = part[(bg * 64 + t) * 2], ss = part[(bg * 64 + t) * 2 + 1];
#pragma unroll
  for (int off = 32; off; off >>= 1) { s += __shfl_xor(s, off); ss += __shfl_xor(ss, off); }
  if (t == 0) {
    float inv = 1.f / (float)((size_t)CPG * NN);
    float mu = s * inv;
    float var = ss * inv - mu * mu;
    stats[bg * 2] = mu;
    stats[bg * 2 + 1] = rsqrtf(var + EPSV);
  }
}

// out = GN(p0 (+p1)) (+ q0) (+ q1)   — float4, grid 4096
__global__ __launch_bounds__(256) void k_gn_apply(const float* __restrict__ p0, const float* __restrict__ p1,
                                                  const float* __restrict__ stats, const float* __restrict__ g,
                                                  const float* __restrict__ be,
                                                  const float* __restrict__ q0, const float* __restrict__ q1,
                                                  float* __restrict__ out) {
  size_t i4 = (size_t)blockIdx.x * 256 + threadIdx.x;
  size_t i = i4 * 4;
  int chan = (int)(i >> 15) & 63;
  int bg = (int)(i >> 19);
  float4 x = ((const float4*)p0)[i4];
  if (p1) { float4 y4 = ((const float4*)p1)[i4]; x.x += y4.x; x.y += y4.y; x.z += y4.z; x.w += y4.w; }
  float mu = stats[bg * 2], rr = stats[bg * 2 + 1];
  float gc = g[chan], bc = be[chan];
  float4 v;
  v.x = (x.x - mu) * rr * gc + bc;
  v.y = (x.y - mu) * rr * gc + bc;
  v.z = (x.z - mu) * rr * gc + bc;
  v.w = (x.w - mu) * rr * gc + bc;
  if (q0) { float4 y4 = ((const float4*)q0)[i4]; v.x += y4.x; v.y += y4.y; v.z += y4.z; v.w += y4.w; }
  if (q1) { float4 y4 = ((const float4*)q1)[i4]; v.x += y4.x; v.y += y4.y; v.z += y4.z; v.w += y4.w; }
  ((float4*)out)[i4] = v;
}

extern "C" void kernel_launch(void* const* d_in, const int* in_sizes, int n_in,
                              void* d_out, int out_size, void* d_ws, size_t ws_size,
                              hipStream_t stream) {
  (void)in_sizes; (void)n_in; (void)out_size; (void)ws_size;
  const float* y     = (const float*)d_in[0];
  const float* a1    = (const float*)d_in[1];
  const float* a2    = (const float*)d_in[2];
  const float* nv1   = (const float*)d_in[3];
  const float* nv2   = (const float*)d_in[4];
  const float* gcn_w = (const float*)d_in[5];
  const float* gcn_b = (const float*)d_in[6];
  const float* s_wq  = (const float*)d_in[7];
  const float* s_wk  = (const float*)d_in[8];
  const float* s_wv  = (const float*)d_in[9];
  const float* s_pk  = (const float*)d_in[10];
  const float* s_pv  = (const float*)d_in[11];
  const float* s_wo  = (const float*)d_in[12];
  const float* s_bo  = (const float*)d_in[13];
  const float* t_wq  = (const float*)d_in[14];
  const float* t_wk  = (const float*)d_in[15];
  const float* t_wv  = (const float*)d_in[16];
  const float* t_bq  = (const float*)d_in[17];
  const float* t_bk  = (const float*)d_in[18];
  const float* t_bv  = (const float*)d_in[19];
  const float* t_wo  = (const float*)d_in[20];
  const float* t_bo  = (const float*)d_in[21];
  const float* t_l1w = (const float*)d_in[22];
  const float* t_l1b = (const float*)d_in[23];
  const float* t_l2w = (const float*)d_in[24];
  const float* t_l2b = (const float*)d_in[25];
  const float* ln1g  = (const float*)d_in[26];
  const float* ln1b  = (const float*)d_in[27];
  const float* ln2g  = (const float*)d_in[28];
  const float* ln2b  = (const float*)d_in[29];
  const float* gnlg  = (const float*)d_in[30];
  const float* gnlb  = (const float*)d_in[31];
  const float* gnsg  = (const float*)d_in[32];
  const float* gnsb  = (const float*)d_in[33];
  const float* gntg  = (const float*)d_in[34];
  const float* gntb  = (const float*)d_in[35];
  const float* ff1w  = (const float*)d_in[36];
  const float* ff1b  = (const float*)d_in[37];
  const float* ff2w  = (const float*)d_in[38];
  const float* ff2b  = (const float*)d_in[39];
  const float* gn2g  = (const float*)d_in[40];
  const float* gn2b  = (const float*)d_in[41];

  float* ws = (float*)d_ws;
  float* adp   = ws;                                    // [0, 65536)
  float* part  = ws + 65536;
  float* stats = ws + 66560;
  unsigned short* a1_bf  = (unsigned short*)(ws + 131072);
  unsigned short* a2_bf  = (unsigned short*)(ws + 163840);
  unsigned short* adp_bf = (unsigned short*)(ws + 196608);
  unsigned short* yT_bf  = (unsigned short*)(ws + 262144);   // [262144, 2359296)
  // later-phase scratch (GCN buffers above dead by then):
  float* kp2 = ws + 131072;
  float* vp2 = ws + 131072 + 1048576;
  float* ffh = ws + 2228224;
  const size_t SLOT = 4194304;
  float* G0 = ws + SLOT * 1;
  unsigned short* h1T = (unsigned short*)G0;            // borrows G0; dead before k_gcn writes G0
  float* G1 = ws + SLOT * 2;
  float* G2 = ws + SLOT * 3;
  float* G3 = ws + SLOT * 4;
  float* G4 = ws + SLOT * 5;
  float* G5 = ws + SLOT * 6;
  float* G6 = ws + SLOT * 7;
  float* out = (float*)d_out;

  const long BS = 2097152;

  // ---- adaptive adjacency + bf16 casts ----
  k_adp<<<256, 256, 0, stream>>>(nv1, nv2, adp);
  k_cast<<<256, 256, 0, stream>>>(a1, a1_bf);
  k_cast<<<256, 256, 0, stream>>>(a2, a2_bf);
  k_cast<<<256, 256, 0, stream>>>(adp, adp_bf);
  k_castT<<<dim3(128, 32), 256, 0, stream>>>(y, yT_bf);

  // ---- AdaptiveGCN: per adjacency, hop1 (emits bf16-T) -> hop2 ----
  k_adjM<<<512, 256, 0, stream>>>(a1_bf, yT_bf, G1, h1T);
  k_adjM<<<512, 256, 0, stream>>>(a1_bf, h1T, G2, nullptr);
  k_adjM<<<512, 256, 0, stream>>>(a2_bf, yT_bf, G3, h1T);
  k_adjM<<<512, 256, 0, stream>>>(a2_bf, h1T, G4, nullptr);
  k_adjM<<<512, 256, 0, stream>>>(adp_bf, yT_bf, G5, h1T);
  k_adjM<<<512, 256, 0, stream>>>(adp_bf, h1T, G6, nullptr);
  k_gcn<<<1024, 256, 0, stream>>>(gcn_w, gcn_b, y, G1, G2, G3, G4, G5, G6, G0);
  k_gn_part<<<dim3(64, 8), 256, 0, stream>>>(y, G0, part);
  k_gn_final<<<8, 64, 0, stream>>>(part, stats);
  k_gn_apply<<<4096, 256, 0, stream>>>(y, G0, stats, gnlg, gnlb, nullptr, nullptr, G0);

  // ---- Linformer spatial attention ----
  k_tr<<<dim3(512, 8), 256, 0, stream>>>(y, G2, nullptr, BS, 128, 32768, 1, BS, 64, 1, 16384, 64, 128);
  k_qkv<<<1024, 256, 0, stream>>>(G2, s_wq, s_wk, s_wv, nullptr, nullptr, nullptr, G3, G4, G5);
  k_sproj<<<256, 256, 0, stream>>>(G4, s_pk, kp2);
  k_sproj<<<256, 256, 0, stream>>>(G5, s_pv, vp2);
  k_sattn<<<2048, 64, 0, stream>>>(G3, kp2, vp2, G6);
  k_rowmm<64, 64, 0, 64><<<1024, 256, 0, stream>>>(G6, s_wo, s_bo, G4);
  k_tr<<<dim3(512, 8), 256, 0, stream>>>(G4, G1, nullptr, BS, 64, 16384, 1, BS, 128, 1, 32768, 128, 64);
  k_gn_part<<<dim3(64, 8), 256, 0, stream>>>(y, G1, part);
  k_gn_final<<<8, 64, 0, stream>>>(part, stats);
  k_gn_apply<<<4096, 256, 0, stream>>>(y, G1, stats, gnsg, gnsb, nullptr, nullptr, G1);

  // ---- temporal transformer layer ----
  k_tr<<<dim3(512, 8), 256, 0, stream>>>(y, G2, nullptr, BS, 128, 32768, 1, BS, 8192, 1, 64, 64, 128);
  k_qkv<<<1024, 256, 0, stream>>>(G2, t_wq, t_wk, t_wv, t_bq, t_bk, t_bv, G3, G4, G5);
  k_tattn<<<4096, 64, 0, stream>>>(G3, G4, G5, G6);
  k_rowmm<64, 64, 0, 64><<<1024, 256, 0, stream>>>(G6, t_wo, t_bo, G3);
  k_ln<<<16384, 256, 0, stream>>>(G2, G3, ln1g, ln1b, G4);
  k_rowmm<64, 8, 2, 64><<<1024, 256, 0, stream>>>(G4, t_l1w, t_l1b, ffh);
  k_rowmm<8, 64, 0, 64><<<1024, 256, 0, stream>>>(ffh, t_l2w, t_l2b, G5);
  k_ln<<<16384, 256, 0, stream>>>(G4, G5, ln2g, ln2b, G6);
  k_tr<<<dim3(512, 8), 256, 0, stream>>>(G6, G2, nullptr, BS, 8192, 64, 1, BS, 128, 1, 32768, 128, 64);
  k_gn_part<<<dim3(64, 8), 256, 0, stream>>>(y, G2, part);
  k_gn_final<<<8, 64, 0, stream>>>(part, stats);
  // y_in2 = GN(y + y_t_pre) + G0 + G1 -> G3
  k_gn_apply<<<4096, 256, 0, stream>>>(y, G2, stats, gntg, gntb, G0, G1, G3);

  // ---- fuse + channel FFN + final GroupNorm ----
  k_tr<<<dim3(512, 8), 256, 0, stream>>>(G3, G4, nullptr, BS, 128, 32768, 1, BS, 8192, 1, 64, 64, 128);
  k_rowmm<64, 128, 1, 64><<<1024, 256, 0, stream>>>(G4, ff1w, ff1b, G5);
  k_rowmm<128, 64, 0, 32><<<2048, 256, 0, stream>>>(G5, ff2w, ff2b, G4);
  k_tr<<<dim3(512, 8), 256, 0, stream>>>(G4, out, G3, BS, 8192, 64, 1, BS, 128, 1, 32768, 128, 64);
  k_gn_part<<<dim3(64, 8), 256, 0, stream>>>(out, nullptr, part);
  k_gn_final<<<8, 64, 0, stream>>>(part, stats);
  k_gn_apply<<<4096, 256, 0, stream>>>(out, nullptr, stats, gn2g, gn2b, nullptr, nullptr, out);
}

// Round 7
// 662.569 us; speedup vs baseline: 3.6002x; 1.1018x over previous
//
#include <hip/hip_runtime.h>
#include <math.h>

constexpr int CC = 64, KK = 256, LL = 128;
constexpr int NN = KK * LL;          // 32768
constexpr int PR = 64;               // Linformer projection
constexpr int CPG = 16;              // channels per group (C / 4)
constexpr float EPSV = 1e-5f;
constexpr float SCL = 0.35355339059327373f;  // 1/sqrt(8)

typedef __attribute__((ext_vector_type(8))) short short8;      // 8 bf16 (4 VGPR)
typedef __attribute__((ext_vector_type(4))) float f32x4;       // MFMA 16x16 acc

__device__ __forceinline__ unsigned short f2bf(float x) {
  union { float f; unsigned int u; } v; v.f = x;
  unsigned int r = (v.u + 0x7FFFu + ((v.u >> 16) & 1u)) >> 16;
  return (unsigned short)r;
}
__device__ __forceinline__ float bf2f(unsigned short x) {
  union { unsigned int u; float f; } v; v.u = ((unsigned int)x) << 16;
  return v.f;
}

// ---------------- adaptive adjacency: softmax(relu(nv1@nv2), axis=1) ----------------
__global__ __launch_bounds__(256) void k_adp(const float* __restrict__ nv1,
                                             const float* __restrict__ nv2,
                                             float* __restrict__ adp) {
  int w = blockIdx.x, v = threadIdx.x;
  float s = 0.f;
  for (int d = 0; d < 10; ++d) s += nv1[w * 10 + d] * nv2[d * KK + v];
  s = fmaxf(s, 0.f);
  __shared__ float red[256];
  red[v] = s; __syncthreads();
  for (int off = 128; off; off >>= 1) { if (v < off) red[v] = fmaxf(red[v], red[v + off]); __syncthreads(); }
  float m = red[0]; __syncthreads();
  float e = expf(s - m);
  red[v] = e; __syncthreads();
  for (int off = 128; off; off >>= 1) { if (v < off) red[v] += red[v + off]; __syncthreads(); }
  adp[w * KK + v] = e / red[0];
}

// ---------------- fp32 -> bf16 cast ----------------
__global__ __launch_bounds__(256) void k_cast(const float* __restrict__ src,
                                              unsigned short* __restrict__ dst) {
  int i = blockIdx.x * 256 + threadIdx.x;
  dst[i] = f2bf(src[i]);
}

// ---------------- channel-mix: U_s[(b,l,k), o] = xs[(b,l,k), c] @ W_s[c][o]  (MFMA, K=64) ----------------
// grid 1024 x 64 threads (1 wave): block = 64 k-positions (one (b,l), quarter of k) x all 64 o.
// s=0 -> fp32 (b,o,n) + bias; s=1..6 -> bf16 T-layout [(b*64+o)][l][k] for k_adjM.
__global__ __launch_bounds__(64) void k_mix(const unsigned short* __restrict__ Xbf,
                                            const unsigned short* __restrict__ Wbf,
                                            const float* __restrict__ bias,
                                            float* __restrict__ s0,
                                            unsigned short* __restrict__ U1, unsigned short* __restrict__ U2,
                                            unsigned short* __restrict__ U3, unsigned short* __restrict__ U4,
                                            unsigned short* __restrict__ U5, unsigned short* __restrict__ U6) {
  unsigned short* Us[6] = {U1, U2, U3, U4, U5, U6};
  int pb = blockIdx.x;
  int b = pb >> 9;
  int rem = pb & 511;
  int l = rem >> 2;
  int kq = (rem & 3) * 64;
  size_t posbase = ((size_t)(b * 128 + l)) * 256 + kq;
  int lane = threadIdx.x;
  int lr = lane & 15, g = lane >> 4;

  short8 af[4][2];
#pragma unroll
  for (int rt = 0; rt < 4; ++rt)
#pragma unroll
    for (int kc = 0; kc < 2; ++kc)
      af[rt][kc] = *(const short8*)(Xbf + (posbase + rt * 16 + lr) * 64 + kc * 32 + g * 8);

  for (int s = 0; s < 7; ++s) {
    short8 bf[4][2];
#pragma unroll
    for (int ct = 0; ct < 4; ++ct)
#pragma unroll
      for (int kc = 0; kc < 2; ++kc)
        bf[ct][kc] = *(const short8*)(Wbf + (size_t)(ct * 16 + lr) * 448 + s * 64 + kc * 32 + g * 8);
    f32x4 acc[4][4];
#pragma unroll
    for (int rt = 0; rt < 4; ++rt)
#pragma unroll
      for (int ct = 0; ct < 4; ++ct) acc[rt][ct] = f32x4{0.f, 0.f, 0.f, 0.f};
#pragma unroll
    for (int kc = 0; kc < 2; ++kc)
#pragma unroll
      for (int rt = 0; rt < 4; ++rt)
#pragma unroll
        for (int ct = 0; ct < 4; ++ct)
          acc[rt][ct] = __builtin_amdgcn_mfma_f32_16x16x32_bf16(af[rt][kc], bf[ct][kc], acc[rt][ct], 0, 0, 0);

    if (s == 0) {
#pragma unroll
      for (int rt = 0; rt < 4; ++rt)
#pragma unroll
        for (int ct = 0; ct < 4; ++ct) {
          int o = ct * 16 + lr;
          float bv = bias[o];
          int k = kq + rt * 16 + g * 4;
#pragma unroll
          for (int j = 0; j < 4; ++j)
            s0[(size_t)(b * 64 + o) * NN + (size_t)(k + j) * 128 + l] = acc[rt][ct][j] + bv;
        }
    } else {
      unsigned short* dst = Us[s - 1];
#pragma unroll
      for (int rt = 0; rt < 4; ++rt)
#pragma unroll
        for (int ct = 0; ct < 4; ++ct) {
          int o = ct * 16 + lr;
          int k = kq + rt * 16 + g * 4;
          ushort4 pk;
          pk.x = f2bf(acc[rt][ct][0]); pk.y = f2bf(acc[rt][ct][1]);
          pk.z = f2bf(acc[rt][ct][2]); pk.w = f2bf(acc[rt][ct][3]);
          *(ushort4*)&dst[((size_t)(b * 64 + o) * 128 + l) * 256 + k] = pk;
        }
    }
  }
}

// ---------------- out[bc, w, l] = sum_v A[w,v] * XT[bc, l, v]  (bf16 MFMA 16x16x32) ----------------
// grid: 512 = (bc=128) x (l-quarter=4); 256 threads = 4 waves; wave: 64 w-rows x 32 l-cols.
// out (fp32 (bc,w,l)) optional; outT (bf16 [l][v], + optional addT in same layout) optional.
__global__ __launch_bounds__(256) void k_adjM(const unsigned short* __restrict__ Abf,
                                              const unsigned short* __restrict__ XT,
                                              float* __restrict__ out,
                                              unsigned short* __restrict__ outT,
                                              const unsigned short* __restrict__ addT) {
  int lq = blockIdx.x & 3, bc = blockIdx.x >> 2;
  int tid = threadIdx.x, wid = tid >> 6, lane = tid & 63;
  int lr = lane & 15, g = lane >> 4;
  int wbase = wid * 64;
  const unsigned short* aP = Abf + (size_t)(wbase + lr) * 256 + g * 8;
  const unsigned short* bP = XT + ((size_t)bc * 128 + lq * 32 + lr) * 256 + g * 8;
  f32x4 acc[4][2];
#pragma unroll
  for (int i = 0; i < 4; ++i)
#pragma unroll
    for (int j = 0; j < 2; ++j) acc[i][j] = f32x4{0.f, 0.f, 0.f, 0.f};
  for (int k0 = 0; k0 < 256; k0 += 32) {
    short8 af[4], bfv[2];
#pragma unroll
    for (int i = 0; i < 4; ++i) af[i] = *(const short8*)(aP + (size_t)i * 16 * 256 + k0);
#pragma unroll
    for (int i = 0; i < 2; ++i) bfv[i] = *(const short8*)(bP + (size_t)i * 16 * 256 + k0);
#pragma unroll
    for (int rm = 0; rm < 4; ++rm)
#pragma unroll
      for (int cn = 0; cn < 2; ++cn)
        acc[rm][cn] = __builtin_amdgcn_mfma_f32_16x16x32_bf16(af[rm], bfv[cn], acc[rm][cn], 0, 0, 0);
  }
  if (out) {
    float* dst = out + (size_t)bc * NN + lq * 32;
#pragma unroll
    for (int rm = 0; rm < 4; ++rm)
#pragma unroll
      for (int cn = 0; cn < 2; ++cn) {
        int col = cn * 16 + lr;
        int row = wbase + rm * 16 + g * 4;
#pragma unroll
        for (int j = 0; j < 4; ++j)
          dst[(size_t)(row + j) * 128 + col] = acc[rm][cn][j];
      }
  }
  if (outT) {
    unsigned short* dT = outT + (size_t)bc * NN + (size_t)(lq * 32) * 256;
    const unsigned short* aT = addT ? addT + (size_t)bc * NN + (size_t)(lq * 32) * 256 : nullptr;
#pragma unroll
    for (int rm = 0; rm < 4; ++rm)
#pragma unroll
      for (int cn = 0; cn < 2; ++cn) {
        int l = cn * 16 + lr;
        int v = wbase + rm * 16 + g * 4;
        float a0 = 0.f, a1 = 0.f, a2 = 0.f, a3 = 0.f;
        if (aT) {
          ushort4 av = *(const ushort4*)&aT[(size_t)l * 256 + v];
          a0 = bf2f(av.x); a1 = bf2f(av.y); a2 = bf2f(av.z); a3 = bf2f(av.w);
        }
        ushort4 pk;
        pk.x = f2bf(acc[rm][cn][0] + a0); pk.y = f2bf(acc[rm][cn][1] + a1);
        pk.z = f2bf(acc[rm][cn][2] + a2); pk.w = f2bf(acc[rm][cn][3] + a3);
        *(ushort4*)&dT[(size_t)l * 256 + v] = pk;
      }
  }
}

// ---------------- generic (c,l)-plane transpose per (b,k), optional add + bf16 side output ----------------
__global__ __launch_bounds__(256) void k_tr(const float* __restrict__ src, float* __restrict__ dst,
                                            const float* __restrict__ add,
                                            unsigned short* __restrict__ dstBf,
                                            long sb, long sk, long sc, long sl,
                                            long db, long dk, long dc, long dl, int nC, int nL) {
  int outer = blockIdx.x;
  int b = outer >> 8, k = outer & 255;
  int tilesL = nL >> 5;
  int tC = blockIdx.y / tilesL, tL = blockIdx.y % tilesL;
  int c0 = tC << 5, l0 = tL << 5;
  __shared__ float s[32][33];
  int tx = threadIdx.x & 31, ty = threadIdx.x >> 5;
  const float* sp = src + (long)b * sb + (long)k * sk;
#pragma unroll
  for (int j = 0; j < 4; ++j) {
    int cc = c0 + ty + j * 8;
    s[ty + j * 8][tx] = sp[(long)cc * sc + (long)(l0 + tx) * sl];
  }
  __syncthreads();
  long dbase = (long)b * db + (long)k * dk;
#pragma unroll
  for (int j = 0; j < 4; ++j) {
    int ll = l0 + ty + j * 8;
    long off = dbase + (long)(c0 + tx) * dc + (long)ll * dl;
    float val = s[tx][ty + j * 8];
    if (add) val += add[off];
    dst[off] = val;
    if (dstBf) dstBf[off] = f2bf(val);
  }
}

// ---------------- fused QKV row-matmul: (R,64) @ 3x(64,64) (+biases) ----------------
__global__ __launch_bounds__(256) void k_qkv(const float* __restrict__ in,
                                             const float* __restrict__ W0, const float* __restrict__ W1,
                                             const float* __restrict__ W2,
                                             const float* __restrict__ b0, const float* __restrict__ b1,
                                             const float* __restrict__ b2,
                                             float* __restrict__ o0, float* __restrict__ o1,
                                             float* __restrict__ o2) {
  int r0 = blockIdx.x * 64;
  __shared__ float sInT[64][68];
  __shared__ float sW[3][64][64];
  int t = threadIdx.x;
  for (int i = t; i < 4096; i += 256) {
    int c = i >> 6, o = i & 63;
    sW[0][c][o] = W0[i];
    sW[1][c][o] = W1[i];
    sW[2][c][o] = W2[i];
  }
  for (int i = t; i < 4096; i += 256) {
    int r = i >> 6, c = i & 63;
    sInT[c][r] = in[(size_t)(r0 + r) * 64 + c];
  }
  __syncthreads();
  int col = t & 63, rg = t >> 6;
  int rbase = rg * 16;
  float a0[16], a1[16], a2[16];
  float bv0 = b0 ? b0[col] : 0.f;
  float bv1 = b1 ? b1[col] : 0.f;
  float bv2 = b2 ? b2[col] : 0.f;
#pragma unroll
  for (int i = 0; i < 16; ++i) { a0[i] = bv0; a1[i] = bv1; a2[i] = bv2; }
  for (int c = 0; c < 64; ++c) {
    float w0 = sW[0][c][col], w1 = sW[1][c][col], w2 = sW[2][c][col];
#pragma unroll
    for (int rr = 0; rr < 16; rr += 4) {
      float4 xv = *(const float4*)&sInT[c][rbase + rr];
      a0[rr + 0] += xv.x * w0; a0[rr + 1] += xv.y * w0; a0[rr + 2] += xv.z * w0; a0[rr + 3] += xv.w * w0;
      a1[rr + 0] += xv.x * w1; a1[rr + 1] += xv.y * w1; a1[rr + 2] += xv.z * w1; a1[rr + 3] += xv.w * w1;
      a2[rr + 0] += xv.x * w2; a2[rr + 1] += xv.y * w2; a2[rr + 2] += xv.z * w2; a2[rr + 3] += xv.w * w2;
    }
  }
#pragma unroll
  for (int rr = 0; rr < 16; ++rr) {
    size_t idx = (size_t)(r0 + rbase + rr) * 64 + col;
    o0[idx] = a0[rr]; o1[idx] = a1[rr]; o2[idx] = a2[rr];
  }
}

// ---------------- row-major (R,CIN) @ (CIN,COUT) + bias, optional activation ----------------
template <int CIN, int COUT, int ACT, int ROWS>
__global__ __launch_bounds__(256) void k_rowmm(const float* __restrict__ in,
                                               const float* __restrict__ W,
                                               const float* __restrict__ bias,
                                               float* __restrict__ out) {
  int r0 = blockIdx.x * ROWS;
  __shared__ float sInT[CIN][ROWS + 4];
  __shared__ float sW[CIN][COUT];
  int t = threadIdx.x;
  for (int i = t; i < CIN * COUT; i += 256) ((float*)sW)[i] = W[i];
  for (int i = t; i < ROWS * CIN; i += 256) {
    int r = i / CIN, c = i % CIN;
    sInT[c][r] = in[(size_t)r0 * CIN + i];
  }
  __syncthreads();
  constexpr int NRG = 256 / COUT;
  constexpr int RPT = ROWS / NRG;
  int col = t % COUT, rg = t / COUT;
  int rbase = rg * RPT;
  float acc[RPT];
  float bv = bias ? bias[col] : 0.f;
#pragma unroll
  for (int r = 0; r < RPT; ++r) acc[r] = bv;
  for (int c = 0; c < CIN; ++c) {
    float wv = sW[c][col];
    if constexpr (RPT % 4 == 0) {
#pragma unroll
      for (int rr = 0; rr < RPT; rr += 4) {
        float4 xv = *(const float4*)&sInT[c][rbase + rr];
        acc[rr] += xv.x * wv; acc[rr + 1] += xv.y * wv;
        acc[rr + 2] += xv.z * wv; acc[rr + 3] += xv.w * wv;
      }
    } else {
#pragma unroll
      for (int rr = 0; rr < RPT; ++rr) acc[rr] += sInT[c][rbase + rr] * wv;
    }
  }
#pragma unroll
  for (int rr = 0; rr < RPT; ++rr) {
    float v = acc[rr];
    if (ACT == 1) v = fmaxf(v, 0.f);
    if (ACT == 2) v = 0.5f * v * (1.f + erff(v * 0.70710678118654752440f));
    out[(size_t)(r0 + rbase + rr) * COUT + col] = v;
  }
}

// ---------------- kp2[bl,p,c] = sum_n X[bl,n,c] * P[n,p] ----------------
__global__ __launch_bounds__(256) void k_sproj(const float* __restrict__ X,
                                               const float* __restrict__ P,
                                               float* __restrict__ out) {
  int bl = blockIdx.x;
  const float* src = X + (size_t)bl * KK * CC;
  float* dst = out + (size_t)bl * PR * CC;
  int t = threadIdx.x, c = t & 63, pg = t >> 6;
  __shared__ float sX[64][CC];
  __shared__ float sP[64][PR];
  float acc[16];
#pragma unroll
  for (int i = 0; i < 16; ++i) acc[i] = 0.f;
  for (int n0 = 0; n0 < KK; n0 += 64) {
    for (int i = t; i < 64 * CC; i += 256) ((float*)sX)[i] = src[(size_t)n0 * CC + i];
    for (int i = t; i < 64 * PR; i += 256) ((float*)sP)[i] = P[(size_t)n0 * PR + i];
    __syncthreads();
    for (int n = 0; n < 64; ++n) {
      float xv = sX[n][c];
#pragma unroll
      for (int q = 0; q < 4; ++q) {
        float4 pv = *(const float4*)&sP[n][pg * 16 + q * 4];
        acc[q * 4 + 0] += pv.x * xv; acc[q * 4 + 1] += pv.y * xv;
        acc[q * 4 + 2] += pv.z * xv; acc[q * 4 + 3] += pv.w * xv;
      }
    }
    __syncthreads();
  }
#pragma unroll
  for (int i = 0; i < 16; ++i) dst[(size_t)(pg * 16 + i) * CC + c] = acc[i];
}

// ---------------- spatial attention: one wave per (b,l,h); 4 k-rows per thread ----------------
__global__ __launch_bounds__(64) void k_sattn(const float* __restrict__ Q, const float* __restrict__ KP,
                                              const float* __restrict__ VP, float* __restrict__ O) {
  int blk = blockIdx.x;
  int h = blk & 7, bl = blk >> 3;
  int t = threadIdx.x;
  __shared__ float sK[PR][8], sV[PR][8];
  {
    const float* kr = KP + ((size_t)bl * PR + t) * CC + h * 8;
    const float* vr = VP + ((size_t)bl * PR + t) * CC + h * 8;
    *(float4*)&sK[t][0] = *(const float4*)kr;
    *(float4*)&sK[t][4] = *(const float4*)(kr + 4);
    *(float4*)&sV[t][0] = *(const float4*)vr;
    *(float4*)&sV[t][4] = *(const float4*)(vr + 4);
  }
  __syncthreads();
  float q[4][8], o[4][8], sum[4];
#pragma unroll
  for (int j = 0; j < 4; ++j) {
    const float* qr = Q + ((size_t)bl * KK + j * 64 + t) * CC + h * 8;
    float4 qa = *(const float4*)qr, qb = *(const float4*)(qr + 4);
    q[j][0] = qa.x * SCL; q[j][1] = qa.y * SCL; q[j][2] = qa.z * SCL; q[j][3] = qa.w * SCL;
    q[j][4] = qb.x * SCL; q[j][5] = qb.y * SCL; q[j][6] = qb.z * SCL; q[j][7] = qb.w * SCL;
    sum[j] = 0.f;
#pragma unroll
    for (int d = 0; d < 8; ++d) o[j][d] = 0.f;
  }
  for (int p = 0; p < PR; ++p) {
    float4 ka = *(const float4*)&sK[p][0], kb = *(const float4*)&sK[p][4];
    float4 va = *(const float4*)&sV[p][0], vb = *(const float4*)&sV[p][4];
    float k[8] = {ka.x, ka.y, ka.z, ka.w, kb.x, kb.y, kb.z, kb.w};
    float v[8] = {va.x, va.y, va.z, va.w, vb.x, vb.y, vb.z, vb.w};
#pragma unroll
    for (int j = 0; j < 4; ++j) {
      float s = 0.f;
#pragma unroll
      for (int d = 0; d < 8; ++d) s += q[j][d] * k[d];
      float e = __expf(s);
      sum[j] += e;
#pragma unroll
      for (int d = 0; d < 8; ++d) o[j][d] += e * v[d];
    }
  }
#pragma unroll
  for (int j = 0; j < 4; ++j) {
    float inv = 1.f / sum[j];
    float* orow = O + ((size_t)bl * KK + j * 64 + t) * CC + h * 8;
    float4 ra = {o[j][0] * inv, o[j][1] * inv, o[j][2] * inv, o[j][3] * inv};
    float4 rb = {o[j][4] * inv, o[j][5] * inv, o[j][6] * inv, o[j][7] * inv};
    *(float4*)orow = ra; *(float4*)(orow + 4) = rb;
  }
}

// ---------------- temporal attention: one wave per (b,k,h); 2 l-rows per thread ----------------
__global__ __launch_bounds__(64) void k_tattn(const float* __restrict__ Q, const float* __restrict__ Kt,
                                              const float* __restrict__ Vt, float* __restrict__ O) {
  int blk = blockIdx.x;
  int h = blk & 7, bk = blk >> 3;
  int t = threadIdx.x;
  __shared__ float sK[LL][8], sV[LL][8];
#pragma unroll
  for (int j = 0; j < 2; ++j) {
    int r = j * 64 + t;
    const float* kr = Kt + ((size_t)bk * LL + r) * CC + h * 8;
    const float* vr = Vt + ((size_t)bk * LL + r) * CC + h * 8;
    *(float4*)&sK[r][0] = *(const float4*)kr;
    *(float4*)&sK[r][4] = *(const float4*)(kr + 4);
    *(float4*)&sV[r][0] = *(const float4*)vr;
    *(float4*)&sV[r][4] = *(const float4*)(vr + 4);
  }
  __syncthreads();
  float q[2][8], o[2][8], sum[2];
#pragma unroll
  for (int j = 0; j < 2; ++j) {
    const float* qr = Q + ((size_t)bk * LL + j * 64 + t) * CC + h * 8;
    float4 qa = *(const float4*)qr, qb = *(const float4*)(qr + 4);
    q[j][0] = qa.x * SCL; q[j][1] = qa.y * SCL; q[j][2] = qa.z * SCL; q[j][3] = qa.w * SCL;
    q[j][4] = qb.x * SCL; q[j][5] = qb.y * SCL; q[j][6] = qb.z * SCL; q[j][7] = qb.w * SCL;
    sum[j] = 0.f;
#pragma unroll
    for (int d = 0; d < 8; ++d) o[j][d] = 0.f;
  }
  for (int p = 0; p < LL; ++p) {
    float4 ka = *(const float4*)&sK[p][0], kb = *(const float4*)&sK[p][4];
    float4 va = *(const float4*)&sV[p][0], vb = *(const float4*)&sV[p][4];
    float k[8] = {ka.x, ka.y, ka.z, ka.w, kb.x, kb.y, kb.z, kb.w};
    float v[8] = {va.x, va.y, va.z, va.w, vb.x, vb.y, vb.z, vb.w};
#pragma unroll
    for (int j = 0; j < 2; ++j) {
      float s = 0.f;
#pragma unroll
      for (int d = 0; d < 8; ++d) s += q[j][d] * k[d];
      float e = __expf(s);
      sum[j] += e;
#pragma unroll
      for (int d = 0; d < 8; ++d) o[j][d] += e * v[d];
    }
  }
#pragma unroll
  for (int j = 0; j < 2; ++j) {
    float inv = 1.f / sum[j];
    float* orow = O + ((size_t)bk * LL + j * 64 + t) * CC + h * 8;
    float4 ra = {o[j][0] * inv, o[j][1] * inv, o[j][2] * inv, o[j][3] * inv};
    float4 rb = {o[j][4] * inv, o[j][5] * inv, o[j][6] * inv, o[j][7] * inv};
    *(float4*)orow = ra; *(float4*)(orow + 4) = rb;
  }
}

// ---------------- LayerNorm over C=64 per row, input = A (+ optional Bp) ----------------
__global__ __launch_bounds__(256) void k_ln(const float* __restrict__ A, const float* __restrict__ Bp,
                                            const float* __restrict__ g, const float* __restrict__ be,
                                            float* __restrict__ out) {
  int row = blockIdx.x * 4 + (threadIdx.x >> 6);
  int c = threadIdx.x & 63;
  size_t idx = (size_t)row * CC + c;
  float x = A[idx] + (Bp ? Bp[idx] : 0.f);
  float s = x, ss = x * x;
#pragma unroll
  for (int off = 32; off; off >>= 1) { s += __shfl_xor(s, off); ss += __shfl_xor(ss, off); }
  float mu = s * (1.f / 64.f);
  float var = ss * (1.f / 64.f) - mu * mu;
  out[idx] = (x - mu) * rsqrtf(var + EPSV) * g[c] + be[c];
}

// ---------------- GroupNorm: deterministic two-phase stats (float4, up to 5 summed inputs) ----------------
__global__ __launch_bounds__(256) void k_gn_part(const float* __restrict__ p0, const float* __restrict__ p1,
                                                 const float* __restrict__ p2, const float* __restrict__ p3,
                                                 const float* __restrict__ p4,
                                                 float* __restrict__ part) {
  int bg = blockIdx.y, blk = blockIdx.x, t = threadIdx.x;
  size_t start = (size_t)bg * ((size_t)CPG * NN) + (size_t)blk * 8192;
  const float4* q0 = (const float4*)(p0 + start);
  const float4* q1 = p1 ? (const float4*)(p1 + start) : nullptr;
  const float4* q2 = p2 ? (const float4*)(p2 + start) : nullptr;
  const float4* q3 = p3 ? (const float4*)(p3 + start) : nullptr;
  const float4* q4 = p4 ? (const float4*)(p4 + start) : nullptr;
  float s = 0.f, ss = 0.f;
  for (int i = t; i < 2048; i += 256) {
    float4 x = q0[i];
    if (q1) { float4 y4 = q1[i]; x.x += y4.x; x.y += y4.y; x.z += y4.z; x.w += y4.w; }
    if (q2) { float4 y4 = q2[i]; x.x += y4.x; x.y += y4.y; x.z += y4.z; x.w += y4.w; }
    if (q3) { float4 y4 = q3[i]; x.x += y4.x; x.y += y4.y; x.z += y4.z; x.w += y4.w; }
    if (q4) { float4 y4 = q4[i]; x.x += y4.x; x.y += y4.y; x.z += y4.z; x.w += y4.w; }
    s += x.x + x.y + x.z + x.w;
    ss += x.x * x.x + x.y * x.y + x.z * x.z + x.w * x.w;
  }
  __shared__ float rs[256], rq[256];
  rs[t] = s; rq[t] = ss; __syncthreads();
  for (int off = 128; off; off >>= 1) { if (t < off) { rs[t] += rs[t + off]; rq[t] += rq[t + off]; } __syncthreads(); }
  if (t == 0) { part[(bg * 64 + blk) * 2] = rs[0]; part[(bg * 64 + blk) * 2 + 1] = rq[0]; }
}

__global__ __launch_bounds__(64) void k_gn_final(const float* __restrict__ part, float* __restrict__ stats) {
  int bg = blockIdx.x, t = threadIdx.x;
  float s = part[(bg * 64 + t) * 2], ss = part[(bg * 64 + t) * 2 + 1];
#pragma unroll
  for (int off = 32; off; off >>= 1) { s += __shfl_xor(s, off); ss += __shfl_xor(ss, off); }
  if (t == 0) {
    float inv = 1.f / (float)((size_t)CPG * NN);
    float mu = s * inv;
    float var = ss * inv - mu * mu;
    stats[bg * 2] = mu;
    stats[bg * 2 + 1] = rsqrtf(var + EPSV);
  }
}

// out = GN(p0+p1+p2+p3+p4) (+ q0) (+ q1)   — float4, grid 4096
__global__ __launch_bounds__(256) void k_gn_apply(const float* __restrict__ p0, const float* __restrict__ p1,
                                                  const float* __restrict__ p2, const float* __restrict__ p3,
                                                  const float* __restrict__ p4,
                                                  const float* __restrict__ stats, const float* __restrict__ g,
                                                  const float* __restrict__ be,
                                                  const float* __restrict__ q0, const float* __restrict__ q1,
                                                  float* __restrict__ out) {
  size_t i4 = (size_t)blockIdx.x * 256 + threadIdx.x;
  size_t i = i4 * 4;
  int chan = (int)(i >> 15) & 63;
  int bg = (int)(i >> 19);
  float4 x = ((const float4*)p0)[i4];
  if (p1) { float4 y4 = ((const float4*)p1)[i4]; x.x += y4.x; x.y += y4.y; x.z += y4.z; x.w += y4.w; }
  if (p2) { float4 y4 = ((const float4*)p2)[i4]; x.x += y4.x; x.y += y4.y; x.z += y4.z; x.w += y4.w; }
  if (p3) { float4 y4 = ((const float4*)p3)[i4]; x.x += y4.x; x.y += y4.y; x.z += y4.z; x.w += y4.w; }
  if (p4) { float4 y4 = ((const float4*)p4)[i4]; x.x += y4.x; x.y += y4.y; x.z += y4.z; x.w += y4.w; }
  float mu = stats[bg * 2], rr = stats[bg * 2 + 1];
  float gc = g[chan], bc = be[chan];
  float4 v;
  v.x = (x.x - mu) * rr * gc + bc;
  v.y = (x.y - mu) * rr * gc + bc;
  v.z = (x.z - mu) * rr * gc + bc;
  v.w = (x.w - mu) * rr * gc + bc;
  if (q0) { float4 y4 = ((const float4*)q0)[i4]; v.x += y4.x; v.y += y4.y; v.z += y4.z; v.w += y4.w; }
  if (q1) { float4 y4 = ((const float4*)q1)[i4]; v.x += y4.x; v.y += y4.y; v.z += y4.z; v.w += y4.w; }
  ((float4*)out)[i4] = v;
}

extern "C" void kernel_launch(void* const* d_in, const int* in_sizes, int n_in,
                              void* d_out, int out_size, void* d_ws, size_t ws_size,
                              hipStream_t stream) {
  (void)in_sizes; (void)n_in; (void)out_size; (void)ws_size;
  const float* y     = (const float*)d_in[0];
  const float* a1    = (const float*)d_in[1];
  const float* a2    = (const float*)d_in[2];
  const float* nv1   = (const float*)d_in[3];
  const float* nv2   = (const float*)d_in[4];
  const float* gcn_w = (const float*)d_in[5];
  const float* gcn_b = (const float*)d_in[6];
  const float* s_wq  = (const float*)d_in[7];
  const float* s_wk  = (const float*)d_in[8];
  const float* s_wv  = (const float*)d_in[9];
  const float* s_pk  = (const float*)d_in[10];
  const float* s_pv  = (const float*)d_in[11];
  const float* s_wo  = (const float*)d_in[12];
  const float* s_bo  = (const float*)d_in[13];
  const float* t_wq  = (const float*)d_in[14];
  const float* t_wk  = (const float*)d_in[15];
  const float* t_wv  = (const float*)d_in[16];
  const float* t_bq  = (const float*)d_in[17];
  const float* t_bk  = (const float*)d_in[18];
  const float* t_bv  = (const float*)d_in[19];
  const float* t_wo  = (const float*)d_in[20];
  const float* t_bo  = (const float*)d_in[21];
  const float* t_l1w = (const float*)d_in[22];
  const float* t_l1b = (const float*)d_in[23];
  const float* t_l2w = (const float*)d_in[24];
  const float* t_l2b = (const float*)d_in[25];
  const float* ln1g  = (const float*)d_in[26];
  const float* ln1b  = (const float*)d_in[27];
  const float* ln2g  = (const float*)d_in[28];
  const float* ln2b  = (const float*)d_in[29];
  const float* gnlg  = (const float*)d_in[30];
  const float* gnlb  = (const float*)d_in[31];
  const float* gnsg  = (const float*)d_in[32];
  const float* gnsb  = (const float*)d_in[33];
  const float* gntg  = (const float*)d_in[34];
  const float* gntb  = (const float*)d_in[35];
  const float* ff1w  = (const float*)d_in[36];
  const float* ff1b  = (const float*)d_in[37];
  const float* ff2w  = (const float*)d_in[38];
  const float* ff2b  = (const float*)d_in[39];
  const float* gn2g  = (const float*)d_in[40];
  const float* gn2b  = (const float*)d_in[41];

  float* ws = (float*)d_ws;
  float* adp   = ws;                                       // [0, 65536)
  float* part  = ws + 65536;
  float* stats = ws + 66560;
  unsigned short* a1_bf   = (unsigned short*)(ws + 131072);   // 32768 ushort
  unsigned short* a2_bf   = (unsigned short*)(ws + 163840);
  unsigned short* adp_bf  = (unsigned short*)(ws + 196608);
  unsigned short* gcnw_bf = (unsigned short*)(ws + 229376);   // 28672 ushort
  unsigned short* xs_bf   = (unsigned short*)(ws + 262144);   // 4.19M ushort [262144, 2359296)
  // later-phase scratch (GCN-section small buffers above are dead by then):
  float* kp2 = ws + 131072;
  float* vp2 = ws + 131072 + 1048576;
  float* ffh = ws + 2228224;
  const size_t SLOT = 4194304;
  float* G0 = ws + SLOT * 1;
  float* G1 = ws + SLOT * 2;
  float* G2 = ws + SLOT * 3;
  float* G3 = ws + SLOT * 4;
  float* G4 = ws + SLOT * 5;
  float* G5 = ws + SLOT * 6;
  float* G6 = ws + SLOT * 7;
  unsigned short* U1 = (unsigned short*)G3;
  unsigned short* U2 = (unsigned short*)G3 + 4194304;
  unsigned short* U3 = (unsigned short*)G4;
  unsigned short* U4 = (unsigned short*)G4 + 4194304;
  unsigned short* U5 = (unsigned short*)G5;
  unsigned short* U6 = (unsigned short*)G5 + 4194304;
  unsigned short* PT = (unsigned short*)G6;
  float* out = (float*)d_out;

  const long BS = 2097152;

  // ---- adaptive adjacency + bf16 casts ----
  k_adp<<<256, 256, 0, stream>>>(nv1, nv2, adp);
  k_cast<<<256, 256, 0, stream>>>(a1, a1_bf);
  k_cast<<<256, 256, 0, stream>>>(a2, a2_bf);
  k_cast<<<256, 256, 0, stream>>>(adp, adp_bf);
  k_cast<<<112, 256, 0, stream>>>(gcn_w, gcnw_bf);

  // ---- xs (B,L,K,C) fp32 + bf16 (feeds both GCN channel-mix and spatial attention) ----
  k_tr<<<dim3(512, 8), 256, 0, stream>>>(y, G2, nullptr, xs_bf, BS, 128, 32768, 1, BS, 64, 1, 16384, 64, 128);

  // ---- AdaptiveGCN (reordered): U_s = W_s X; out = s0 + Sum_f A_f(U_odd + A_f U_even) ----
  k_mix<<<1024, 64, 0, stream>>>(xs_bf, gcnw_bf, gcn_b, G1, U1, U2, U3, U4, U5, U6);
  k_adjM<<<512, 256, 0, stream>>>(a1_bf, U2, nullptr, PT, U1);
  k_adjM<<<512, 256, 0, stream>>>(a1_bf, PT, G3, nullptr, nullptr);   // Q1 (overwrites U1/U2, both dead)
  k_adjM<<<512, 256, 0, stream>>>(a2_bf, U4, nullptr, PT, U3);
  k_adjM<<<512, 256, 0, stream>>>(a2_bf, PT, G4, nullptr, nullptr);   // Q2
  k_adjM<<<512, 256, 0, stream>>>(adp_bf, U6, nullptr, PT, U5);
  k_adjM<<<512, 256, 0, stream>>>(adp_bf, PT, G5, nullptr, nullptr);  // Q3
  k_gn_part<<<dim3(64, 8), 256, 0, stream>>>(y, G1, G3, G4, G5, part);
  k_gn_final<<<8, 64, 0, stream>>>(part, stats);
  k_gn_apply<<<4096, 256, 0, stream>>>(y, G1, G3, G4, G5, stats, gnlg, gnlb, nullptr, nullptr, G0);

  // ---- Linformer spatial attention (G2 = xs already computed) ----
  k_qkv<<<1024, 256, 0, stream>>>(G2, s_wq, s_wk, s_wv, nullptr, nullptr, nullptr, G3, G4, G5);
  k_sproj<<<256, 256, 0, stream>>>(G4, s_pk, kp2);
  k_sproj<<<256, 256, 0, stream>>>(G5, s_pv, vp2);
  k_sattn<<<2048, 64, 0, stream>>>(G3, kp2, vp2, G6);
  k_rowmm<64, 64, 0, 64><<<1024, 256, 0, stream>>>(G6, s_wo, s_bo, G4);
  k_tr<<<dim3(512, 8), 256, 0, stream>>>(G4, G1, nullptr, nullptr, BS, 64, 16384, 1, BS, 128, 1, 32768, 128, 64);
  k_gn_part<<<dim3(64, 8), 256, 0, stream>>>(y, G1, nullptr, nullptr, nullptr, part);
  k_gn_final<<<8, 64, 0, stream>>>(part, stats);
  k_gn_apply<<<4096, 256, 0, stream>>>(y, G1, nullptr, nullptr, nullptr, stats, gnsg, gnsb, nullptr, nullptr, G1);

  // ---- temporal transformer layer ----
  k_tr<<<dim3(512, 8), 256, 0, stream>>>(y, G2, nullptr, nullptr, BS, 128, 32768, 1, BS, 8192, 1, 64, 64, 128);
  k_qkv<<<1024, 256, 0, stream>>>(G2, t_wq, t_wk, t_wv, t_bq, t_bk, t_bv, G3, G4, G5);
  k_tattn<<<4096, 64, 0, stream>>>(G3, G4, G5, G6);
  k_rowmm<64, 64, 0, 64><<<1024, 256, 0, stream>>>(G6, t_wo, t_bo, G3);
  k_ln<<<16384, 256, 0, stream>>>(G2, G3, ln1g, ln1b, G4);
  k_rowmm<64, 8, 2, 64><<<1024, 256, 0, stream>>>(G4, t_l1w, t_l1b, ffh);
  k_rowmm<8, 64, 0, 64><<<1024, 256, 0, stream>>>(ffh, t_l2w, t_l2b, G5);
  k_ln<<<16384, 256, 0, stream>>>(G4, G5, ln2g, ln2b, G6);
  k_tr<<<dim3(512, 8), 256, 0, stream>>>(G6, G2, nullptr, nullptr, BS, 8192, 64, 1, BS, 128, 1, 32768, 128, 64);
  k_gn_part<<<dim3(64, 8), 256, 0, stream>>>(y, G2, nullptr, nullptr, nullptr, part);
  k_gn_final<<<8, 64, 0, stream>>>(part, stats);
  // y_in2 = GN(y + y_t_pre) + G0 + G1 -> G3
  k_gn_apply<<<4096, 256, 0, stream>>>(y, G2, nullptr, nullptr, nullptr, stats, gntg, gntb, G0, G1, G3);

  // ---- fuse + channel FFN + final GroupNorm ----
  k_tr<<<dim3(512, 8), 256, 0, stream>>>(G3, G4, nullptr, nullptr, BS, 128, 32768, 1, BS, 8192, 1, 64, 64, 128);
  k_rowmm<64, 128, 1, 64><<<1024, 256, 0, stream>>>(G4, ff1w, ff1b, G5);
  k_rowmm<128, 64, 0, 32><<<2048, 256, 0, stream>>>(G5, ff2w, ff2b, G4);
  k_tr<<<dim3(512, 8), 256, 0, stream>>>(G4, out, G3, nullptr, BS, 8192, 64, 1, BS, 128, 1, 32768, 128, 64);
  k_gn_part<<<dim3(64, 8), 256, 0, stream>>>(out, nullptr, nullptr, nullptr, nullptr, part);
  k_gn_final<<<8, 64, 0, stream>>>(part, stats);
  k_gn_apply<<<4096, 256, 0, stream>>>(out, nullptr, nullptr, nullptr, nullptr, stats, gn2g, gn2b, nullptr, nullptr, out);
}

// Round 8
// 639.283 us; speedup vs baseline: 3.7314x; 1.0364x over previous
//
#include <hip/hip_runtime.h>
#include <math.h>

constexpr int CC = 64, KK = 256, LL = 128;
constexpr int NN = KK * LL;          // 32768
constexpr int PR = 64;               // Linformer projection
constexpr int CPG = 16;              // channels per group (C / 4)
constexpr float EPSV = 1e-5f;
constexpr float SCL = 0.35355339059327373f;  // 1/sqrt(8)

typedef __attribute__((ext_vector_type(8))) short short8;      // 8 bf16 (4 VGPR)
typedef __attribute__((ext_vector_type(4))) float f32x4;       // MFMA 16x16 acc

__device__ __forceinline__ unsigned short f2bf(float x) {
  union { float f; unsigned int u; } v; v.f = x;
  unsigned int r = (v.u + 0x7FFFu + ((v.u >> 16) & 1u)) >> 16;
  return (unsigned short)r;
}
__device__ __forceinline__ float bf2f(unsigned short x) {
  union { unsigned int u; float f; } v; v.u = ((unsigned int)x) << 16;
  return v.f;
}

// ---------------- adaptive adjacency: softmax(relu(nv1@nv2), axis=1) ----------------
__global__ __launch_bounds__(256) void k_adp(const float* __restrict__ nv1,
                                             const float* __restrict__ nv2,
                                             float* __restrict__ adp) {
  int w = blockIdx.x, v = threadIdx.x;
  float s = 0.f;
  for (int d = 0; d < 10; ++d) s += nv1[w * 10 + d] * nv2[d * KK + v];
  s = fmaxf(s, 0.f);
  __shared__ float red[256];
  red[v] = s; __syncthreads();
  for (int off = 128; off; off >>= 1) { if (v < off) red[v] = fmaxf(red[v], red[v + off]); __syncthreads(); }
  float m = red[0]; __syncthreads();
  float e = expf(s - m);
  red[v] = e; __syncthreads();
  for (int off = 128; off; off >>= 1) { if (v < off) red[v] += red[v + off]; __syncthreads(); }
  adp[w * KK + v] = e / red[0];
}

// ---------------- fp32 -> bf16 cast ----------------
__global__ __launch_bounds__(256) void k_cast(const float* __restrict__ src,
                                              unsigned short* __restrict__ dst) {
  int i = blockIdx.x * 256 + threadIdx.x;
  dst[i] = f2bf(src[i]);
}

// ---------------- channel-mix: U_s[(b,l,k), o] = xs[(b,l,k), c] @ W_s[c][o]  (MFMA, K=64) ----------------
__global__ __launch_bounds__(64) void k_mix(const unsigned short* __restrict__ Xbf,
                                            const unsigned short* __restrict__ Wbf,
                                            const float* __restrict__ bias,
                                            float* __restrict__ s0,
                                            unsigned short* __restrict__ U1, unsigned short* __restrict__ U2,
                                            unsigned short* __restrict__ U3, unsigned short* __restrict__ U4,
                                            unsigned short* __restrict__ U5, unsigned short* __restrict__ U6) {
  unsigned short* Us[6] = {U1, U2, U3, U4, U5, U6};
  int pb = blockIdx.x;
  int b = pb >> 9;
  int rem = pb & 511;
  int l = rem >> 2;
  int kq = (rem & 3) * 64;
  size_t posbase = ((size_t)(b * 128 + l)) * 256 + kq;
  int lane = threadIdx.x;
  int lr = lane & 15, g = lane >> 4;

  short8 af[4][2];
#pragma unroll
  for (int rt = 0; rt < 4; ++rt)
#pragma unroll
    for (int kc = 0; kc < 2; ++kc)
      af[rt][kc] = *(const short8*)(Xbf + (posbase + rt * 16 + lr) * 64 + kc * 32 + g * 8);

  for (int s = 0; s < 7; ++s) {
    short8 bf[4][2];
#pragma unroll
    for (int ct = 0; ct < 4; ++ct)
#pragma unroll
      for (int kc = 0; kc < 2; ++kc)
        bf[ct][kc] = *(const short8*)(Wbf + (size_t)(ct * 16 + lr) * 448 + s * 64 + kc * 32 + g * 8);
    f32x4 acc[4][4];
#pragma unroll
    for (int rt = 0; rt < 4; ++rt)
#pragma unroll
      for (int ct = 0; ct < 4; ++ct) acc[rt][ct] = f32x4{0.f, 0.f, 0.f, 0.f};
#pragma unroll
    for (int kc = 0; kc < 2; ++kc)
#pragma unroll
      for (int rt = 0; rt < 4; ++rt)
#pragma unroll
        for (int ct = 0; ct < 4; ++ct)
          acc[rt][ct] = __builtin_amdgcn_mfma_f32_16x16x32_bf16(af[rt][kc], bf[ct][kc], acc[rt][ct], 0, 0, 0);

    if (s == 0) {
#pragma unroll
      for (int rt = 0; rt < 4; ++rt)
#pragma unroll
        for (int ct = 0; ct < 4; ++ct) {
          int o = ct * 16 + lr;
          float bv = bias[o];
          int k = kq + rt * 16 + g * 4;
#pragma unroll
          for (int j = 0; j < 4; ++j)
            s0[(size_t)(b * 64 + o) * NN + (size_t)(k + j) * 128 + l] = acc[rt][ct][j] + bv;
        }
    } else {
      unsigned short* dst = Us[s - 1];
#pragma unroll
      for (int rt = 0; rt < 4; ++rt)
#pragma unroll
        for (int ct = 0; ct < 4; ++ct) {
          int o = ct * 16 + lr;
          int k = kq + rt * 16 + g * 4;
          ushort4 pk;
          pk.x = f2bf(acc[rt][ct][0]); pk.y = f2bf(acc[rt][ct][1]);
          pk.z = f2bf(acc[rt][ct][2]); pk.w = f2bf(acc[rt][ct][3]);
          *(ushort4*)&dst[((size_t)(b * 64 + o) * 128 + l) * 256 + k] = pk;
        }
    }
  }
}

// ---------------- out[bc, w, l] = sum_v A[w,v] * XT[bc, l, v]  (bf16 MFMA 16x16x32) ----------------
__global__ __launch_bounds__(256) void k_adjM(const unsigned short* __restrict__ Abf,
                                              const unsigned short* __restrict__ XT,
                                              float* __restrict__ out,
                                              unsigned short* __restrict__ outT,
                                              const unsigned short* __restrict__ addT) {
  int lq = blockIdx.x & 3, bc = blockIdx.x >> 2;
  int tid = threadIdx.x, wid = tid >> 6, lane = tid & 63;
  int lr = lane & 15, g = lane >> 4;
  int wbase = wid * 64;
  const unsigned short* aP = Abf + (size_t)(wbase + lr) * 256 + g * 8;
  const unsigned short* bP = XT + ((size_t)bc * 128 + lq * 32 + lr) * 256 + g * 8;
  f32x4 acc[4][2];
#pragma unroll
  for (int i = 0; i < 4; ++i)
#pragma unroll
    for (int j = 0; j < 2; ++j) acc[i][j] = f32x4{0.f, 0.f, 0.f, 0.f};
  for (int k0 = 0; k0 < 256; k0 += 32) {
    short8 af[4], bfv[2];
#pragma unroll
    for (int i = 0; i < 4; ++i) af[i] = *(const short8*)(aP + (size_t)i * 16 * 256 + k0);
#pragma unroll
    for (int i = 0; i < 2; ++i) bfv[i] = *(const short8*)(bP + (size_t)i * 16 * 256 + k0);
#pragma unroll
    for (int rm = 0; rm < 4; ++rm)
#pragma unroll
      for (int cn = 0; cn < 2; ++cn)
        acc[rm][cn] = __builtin_amdgcn_mfma_f32_16x16x32_bf16(af[rm], bfv[cn], acc[rm][cn], 0, 0, 0);
  }
  if (out) {
    float* dst = out + (size_t)bc * NN + lq * 32;
#pragma unroll
    for (int rm = 0; rm < 4; ++rm)
#pragma unroll
      for (int cn = 0; cn < 2; ++cn) {
        int col = cn * 16 + lr;
        int row = wbase + rm * 16 + g * 4;
#pragma unroll
        for (int j = 0; j < 4; ++j)
          dst[(size_t)(row + j) * 128 + col] = acc[rm][cn][j];
      }
  }
  if (outT) {
    unsigned short* dT = outT + (size_t)bc * NN + (size_t)(lq * 32) * 256;
    const unsigned short* aT = addT ? addT + (size_t)bc * NN + (size_t)(lq * 32) * 256 : nullptr;
#pragma unroll
    for (int rm = 0; rm < 4; ++rm)
#pragma unroll
      for (int cn = 0; cn < 2; ++cn) {
        int l = cn * 16 + lr;
        int v = wbase + rm * 16 + g * 4;
        float a0 = 0.f, a1 = 0.f, a2 = 0.f, a3 = 0.f;
        if (aT) {
          ushort4 av = *(const ushort4*)&aT[(size_t)l * 256 + v];
          a0 = bf2f(av.x); a1 = bf2f(av.y); a2 = bf2f(av.z); a3 = bf2f(av.w);
        }
        ushort4 pk;
        pk.x = f2bf(acc[rm][cn][0] + a0); pk.y = f2bf(acc[rm][cn][1] + a1);
        pk.z = f2bf(acc[rm][cn][2] + a2); pk.w = f2bf(acc[rm][cn][3] + a3);
        *(ushort4*)&dT[(size_t)l * 256 + v] = pk;
      }
  }
}

// ---------------- generic (c,l)-plane transpose per (b,k), optional add + bf16 side output ----------------
__global__ __launch_bounds__(256) void k_tr(const float* __restrict__ src, float* __restrict__ dst,
                                            const float* __restrict__ add,
                                            unsigned short* __restrict__ dstBf,
                                            long sb, long sk, long sc, long sl,
                                            long db, long dk, long dc, long dl, int nC, int nL) {
  int outer = blockIdx.x;
  int b = outer >> 8, k = outer & 255;
  int tilesL = nL >> 5;
  int tC = blockIdx.y / tilesL, tL = blockIdx.y % tilesL;
  int c0 = tC << 5, l0 = tL << 5;
  __shared__ float s[32][33];
  int tx = threadIdx.x & 31, ty = threadIdx.x >> 5;
  const float* sp = src + (long)b * sb + (long)k * sk;
#pragma unroll
  for (int j = 0; j < 4; ++j) {
    int cc = c0 + ty + j * 8;
    s[ty + j * 8][tx] = sp[(long)cc * sc + (long)(l0 + tx) * sl];
  }
  __syncthreads();
  long dbase = (long)b * db + (long)k * dk;
#pragma unroll
  for (int j = 0; j < 4; ++j) {
    int ll = l0 + ty + j * 8;
    long off = dbase + (long)(c0 + tx) * dc + (long)ll * dl;
    float val = s[tx][ty + j * 8];
    if (add) val += add[off];
    dst[off] = val;
    if (dstBf) dstBf[off] = f2bf(val);
  }
}

// ---------------- fused QKV row-matmul: (R,64) @ 3x(64,64) (+biases) ----------------
__global__ __launch_bounds__(256) void k_qkv(const float* __restrict__ in,
                                             const float* __restrict__ W0, const float* __restrict__ W1,
                                             const float* __restrict__ W2,
                                             const float* __restrict__ b0, const float* __restrict__ b1,
                                             const float* __restrict__ b2,
                                             float* __restrict__ o0, float* __restrict__ o1,
                                             float* __restrict__ o2) {
  int r0 = blockIdx.x * 64;
  __shared__ float sInT[64][68];
  __shared__ float sW[3][64][64];
  int t = threadIdx.x;
  for (int i = t; i < 4096; i += 256) {
    int c = i >> 6, o = i & 63;
    sW[0][c][o] = W0[i];
    sW[1][c][o] = W1[i];
    sW[2][c][o] = W2[i];
  }
  for (int i = t; i < 4096; i += 256) {
    int r = i >> 6, c = i & 63;
    sInT[c][r] = in[(size_t)(r0 + r) * 64 + c];
  }
  __syncthreads();
  int col = t & 63, rg = t >> 6;
  int rbase = rg * 16;
  float a0[16], a1[16], a2[16];
  float bv0 = b0 ? b0[col] : 0.f;
  float bv1 = b1 ? b1[col] : 0.f;
  float bv2 = b2 ? b2[col] : 0.f;
#pragma unroll
  for (int i = 0; i < 16; ++i) { a0[i] = bv0; a1[i] = bv1; a2[i] = bv2; }
  for (int c = 0; c < 64; ++c) {
    float w0 = sW[0][c][col], w1 = sW[1][c][col], w2 = sW[2][c][col];
#pragma unroll
    for (int rr = 0; rr < 16; rr += 4) {
      float4 xv = *(const float4*)&sInT[c][rbase + rr];
      a0[rr + 0] += xv.x * w0; a0[rr + 1] += xv.y * w0; a0[rr + 2] += xv.z * w0; a0[rr + 3] += xv.w * w0;
      a1[rr + 0] += xv.x * w1; a1[rr + 1] += xv.y * w1; a1[rr + 2] += xv.z * w1; a1[rr + 3] += xv.w * w1;
      a2[rr + 0] += xv.x * w2; a2[rr + 1] += xv.y * w2; a2[rr + 2] += xv.z * w2; a2[rr + 3] += xv.w * w2;
    }
  }
#pragma unroll
  for (int rr = 0; rr < 16; ++rr) {
    size_t idx = (size_t)(r0 + rbase + rr) * 64 + col;
    o0[idx] = a0[rr]; o1[idx] = a1[rr]; o2[idx] = a2[rr];
  }
}

// ---------------- row-major (R,CIN) @ (CIN,COUT) + bias, optional activation ----------------
template <int CIN, int COUT, int ACT, int ROWS>
__global__ __launch_bounds__(256) void k_rowmm(const float* __restrict__ in,
                                               const float* __restrict__ W,
                                               const float* __restrict__ bias,
                                               float* __restrict__ out) {
  int r0 = blockIdx.x * ROWS;
  __shared__ float sInT[CIN][ROWS + 4];
  __shared__ float sW[CIN][COUT];
  int t = threadIdx.x;
  for (int i = t; i < CIN * COUT; i += 256) ((float*)sW)[i] = W[i];
  for (int i = t; i < ROWS * CIN; i += 256) {
    int r = i / CIN, c = i % CIN;
    sInT[c][r] = in[(size_t)r0 * CIN + i];
  }
  __syncthreads();
  constexpr int NRG = 256 / COUT;
  constexpr int RPT = ROWS / NRG;
  int col = t % COUT, rg = t / COUT;
  int rbase = rg * RPT;
  float acc[RPT];
  float bv = bias ? bias[col] : 0.f;
#pragma unroll
  for (int r = 0; r < RPT; ++r) acc[r] = bv;
  for (int c = 0; c < CIN; ++c) {
    float wv = sW[c][col];
    if constexpr (RPT % 4 == 0) {
#pragma unroll
      for (int rr = 0; rr < RPT; rr += 4) {
        float4 xv = *(const float4*)&sInT[c][rbase + rr];
        acc[rr] += xv.x * wv; acc[rr + 1] += xv.y * wv;
        acc[rr + 2] += xv.z * wv; acc[rr + 3] += xv.w * wv;
      }
    } else {
#pragma unroll
      for (int rr = 0; rr < RPT; ++rr) acc[rr] += sInT[c][rbase + rr] * wv;
    }
  }
#pragma unroll
  for (int rr = 0; rr < RPT; ++rr) {
    float v = acc[rr];
    if (ACT == 1) v = fmaxf(v, 0.f);
    if (ACT == 2) v = 0.5f * v * (1.f + erff(v * 0.70710678118654752440f));
    out[(size_t)(r0 + rbase + rr) * COUT + col] = v;
  }
}

// ---------------- kp2[bl,p,c] = sum_n X[bl,n,c] * P[n,p] ----------------
__global__ __launch_bounds__(256) void k_sproj(const float* __restrict__ X,
                                               const float* __restrict__ P,
                                               float* __restrict__ out) {
  int bl = blockIdx.x;
  const float* src = X + (size_t)bl * KK * CC;
  float* dst = out + (size_t)bl * PR * CC;
  int t = threadIdx.x, c = t & 63, pg = t >> 6;
  __shared__ float sX[64][CC];
  __shared__ float sP[64][PR];
  float acc[16];
#pragma unroll
  for (int i = 0; i < 16; ++i) acc[i] = 0.f;
  for (int n0 = 0; n0 < KK; n0 += 64) {
    for (int i = t; i < 64 * CC; i += 256) ((float*)sX)[i] = src[(size_t)n0 * CC + i];
    for (int i = t; i < 64 * PR; i += 256) ((float*)sP)[i] = P[(size_t)n0 * PR + i];
    __syncthreads();
    for (int n = 0; n < 64; ++n) {
      float xv = sX[n][c];
#pragma unroll
      for (int q = 0; q < 4; ++q) {
        float4 pv = *(const float4*)&sP[n][pg * 16 + q * 4];
        acc[q * 4 + 0] += pv.x * xv; acc[q * 4 + 1] += pv.y * xv;
        acc[q * 4 + 2] += pv.z * xv; acc[q * 4 + 3] += pv.w * xv;
      }
    }
    __syncthreads();
  }
#pragma unroll
  for (int i = 0; i < 16; ++i) dst[(size_t)(pg * 16 + i) * CC + c] = acc[i];
}

// ---------------- spatial attention v2: block = (b,l,khalf), 8 waves = 8 heads ----------------
// grid 512; K/V staged row-major in LDS (linear copy, conflict-free; compute reads broadcast).
__global__ __launch_bounds__(512) void k_sattn(const float* __restrict__ Q, const float* __restrict__ KP,
                                               const float* __restrict__ VP, float* __restrict__ O) {
  int blk = blockIdx.x;
  int kh = blk & 1, bl = blk >> 1;
  int t = threadIdx.x;
  int h = t >> 6, lane = t & 63;
  __shared__ float sK[PR][64];   // 16 KB
  __shared__ float sV[PR][64];
  {
    const float4* gK = (const float4*)(KP + (size_t)bl * PR * CC);
    const float4* gV = (const float4*)(VP + (size_t)bl * PR * CC);
    float4* lK = (float4*)sK;
    float4* lV = (float4*)sV;
    for (int i = t; i < 1024; i += 512) { lK[i] = gK[i]; lV[i] = gV[i]; }
  }
  __syncthreads();
  float q[2][8], o[2][8], sum[2];
#pragma unroll
  for (int j = 0; j < 2; ++j) {
    int row = kh * 128 + j * 64 + lane;
    const float* qr = Q + ((size_t)bl * KK + row) * CC + h * 8;
    float4 qa = *(const float4*)qr, qb = *(const float4*)(qr + 4);
    q[j][0] = qa.x * SCL; q[j][1] = qa.y * SCL; q[j][2] = qa.z * SCL; q[j][3] = qa.w * SCL;
    q[j][4] = qb.x * SCL; q[j][5] = qb.y * SCL; q[j][6] = qb.z * SCL; q[j][7] = qb.w * SCL;
    sum[j] = 0.f;
#pragma unroll
    for (int d = 0; d < 8; ++d) o[j][d] = 0.f;
  }
  for (int p = 0; p < PR; ++p) {
    float4 ka = *(const float4*)&sK[p][h * 8], kb = *(const float4*)&sK[p][h * 8 + 4];
    float4 va = *(const float4*)&sV[p][h * 8], vb = *(const float4*)&sV[p][h * 8 + 4];
    float k[8] = {ka.x, ka.y, ka.z, ka.w, kb.x, kb.y, kb.z, kb.w};
    float v[8] = {va.x, va.y, va.z, va.w, vb.x, vb.y, vb.z, vb.w};
#pragma unroll
    for (int j = 0; j < 2; ++j) {
      float s = 0.f;
#pragma unroll
      for (int d = 0; d < 8; ++d) s += q[j][d] * k[d];
      float e = __expf(s);
      sum[j] += e;
#pragma unroll
      for (int d = 0; d < 8; ++d) o[j][d] += e * v[d];
    }
  }
#pragma unroll
  for (int j = 0; j < 2; ++j) {
    float inv = 1.f / sum[j];
    int row = kh * 128 + j * 64 + lane;
    float* orow = O + ((size_t)bl * KK + row) * CC + h * 8;
    float4 ra = {o[j][0] * inv, o[j][1] * inv, o[j][2] * inv, o[j][3] * inv};
    float4 rb = {o[j][4] * inv, o[j][5] * inv, o[j][6] * inv, o[j][7] * inv};
    *(float4*)orow = ra; *(float4*)(orow + 4) = rb;
  }
}

// ---------------- temporal attention v2: block = (b,k), 8 waves = 8 heads ----------------
// grid 512; K/V staged row-major in LDS (64 KB), 2 l-rows per thread.
__global__ __launch_bounds__(512) void k_tattn(const float* __restrict__ Q, const float* __restrict__ Kt,
                                               const float* __restrict__ Vt, float* __restrict__ O) {
  int bk = blockIdx.x;
  int t = threadIdx.x;
  int h = t >> 6, lane = t & 63;
  __shared__ float sK[LL][64];   // 32 KB
  __shared__ float sV[LL][64];
  {
    const float4* gK = (const float4*)(Kt + (size_t)bk * LL * CC);
    const float4* gV = (const float4*)(Vt + (size_t)bk * LL * CC);
    float4* lK = (float4*)sK;
    float4* lV = (float4*)sV;
    for (int i = t; i < 2048; i += 512) { lK[i] = gK[i]; lV[i] = gV[i]; }
  }
  __syncthreads();
  float q[2][8], o[2][8], sum[2];
#pragma unroll
  for (int j = 0; j < 2; ++j) {
    int row = j * 64 + lane;
    const float* qr = Q + ((size_t)bk * LL + row) * CC + h * 8;
    float4 qa = *(const float4*)qr, qb = *(const float4*)(qr + 4);
    q[j][0] = qa.x * SCL; q[j][1] = qa.y * SCL; q[j][2] = qa.z * SCL; q[j][3] = qa.w * SCL;
    q[j][4] = qb.x * SCL; q[j][5] = qb.y * SCL; q[j][6] = qb.z * SCL; q[j][7] = qb.w * SCL;
    sum[j] = 0.f;
#pragma unroll
    for (int d = 0; d < 8; ++d) o[j][d] = 0.f;
  }
  for (int p = 0; p < LL; ++p) {
    float4 ka = *(const float4*)&sK[p][h * 8], kb = *(const float4*)&sK[p][h * 8 + 4];
    float4 va = *(const float4*)&sV[p][h * 8], vb = *(const float4*)&sV[p][h * 8 + 4];
    float k[8] = {ka.x, ka.y, ka.z, ka.w, kb.x, kb.y, kb.z, kb.w};
    float v[8] = {va.x, va.y, va.z, va.w, vb.x, vb.y, vb.z, vb.w};
#pragma unroll
    for (int j = 0; j < 2; ++j) {
      float s = 0.f;
#pragma unroll
      for (int d = 0; d < 8; ++d) s += q[j][d] * k[d];
      float e = __expf(s);
      sum[j] += e;
#pragma unroll
      for (int d = 0; d < 8; ++d) o[j][d] += e * v[d];
    }
  }
#pragma unroll
  for (int j = 0; j < 2; ++j) {
    float inv = 1.f / sum[j];
    int row = j * 64 + lane;
    float* orow = O + ((size_t)bk * LL + row) * CC + h * 8;
    float4 ra = {o[j][0] * inv, o[j][1] * inv, o[j][2] * inv, o[j][3] * inv};
    float4 rb = {o[j][4] * inv, o[j][5] * inv, o[j][6] * inv, o[j][7] * inv};
    *(float4*)orow = ra; *(float4*)(orow + 4) = rb;
  }
}

// ---------------- LayerNorm over C=64 per row, input = A (+ optional Bp) ----------------
__global__ __launch_bounds__(256) void k_ln(const float* __restrict__ A, const float* __restrict__ Bp,
                                            const float* __restrict__ g, const float* __restrict__ be,
                                            float* __restrict__ out) {
  int row = blockIdx.x * 4 + (threadIdx.x >> 6);
  int c = threadIdx.x & 63;
  size_t idx = (size_t)row * CC + c;
  float x = A[idx] + (Bp ? Bp[idx] : 0.f);
  float s = x, ss = x * x;
#pragma unroll
  for (int off = 32; off; off >>= 1) { s += __shfl_xor(s, off); ss += __shfl_xor(ss, off); }
  float mu = s * (1.f / 64.f);
  float var = ss * (1.f / 64.f) - mu * mu;
  out[idx] = (x - mu) * rsqrtf(var + EPSV) * g[c] + be[c];
}

// ---------------- GroupNorm: deterministic two-phase stats (float4, up to 5 summed inputs) ----------------
__global__ __launch_bounds__(256) void k_gn_part(const float* __restrict__ p0, const float* __restrict__ p1,
                                                 const float* __restrict__ p2, const float* __restrict__ p3,
                                                 const float* __restrict__ p4,
                                                 float* __restrict__ part) {
  int bg = blockIdx.y, blk = blockIdx.x, t = threadIdx.x;
  size_t start = (size_t)bg * ((size_t)CPG * NN) + (size_t)blk * 8192;
  const float4* q0 = (const float4*)(p0 + start);
  const float4* q1 = p1 ? (const float4*)(p1 + start) : nullptr;
  const float4* q2 = p2 ? (const float4*)(p2 + start) : nullptr;
  const float4* q3 = p3 ? (const float4*)(p3 + start) : nullptr;
  const float4* q4 = p4 ? (const float4*)(p4 + start) : nullptr;
  float s = 0.f, ss = 0.f;
  for (int i = t; i < 2048; i += 256) {
    float4 x = q0[i];
    if (q1) { float4 y4 = q1[i]; x.x += y4.x; x.y += y4.y; x.z += y4.z; x.w += y4.w; }
    if (q2) { float4 y4 = q2[i]; x.x += y4.x; x.y += y4.y; x.z += y4.z; x.w += y4.w; }
    if (q3) { float4 y4 = q3[i]; x.x += y4.x; x.y += y4.y; x.z += y4.z; x.w += y4.w; }
    if (q4) { float4 y4 = q4[i]; x.x += y4.x; x.y += y4.y; x.z += y4.z; x.w += y4.w; }
    s += x.x + x.y + x.z + x.w;
    ss += x.x * x.x + x.y * x.y + x.z * x.z + x.w * x.w;
  }
  __shared__ float rs[256], rq[256];
  rs[t] = s; rq[t] = ss; __syncthreads();
  for (int off = 128; off; off >>= 1) { if (t < off) { rs[t] += rs[t + off]; rq[t] += rq[t + off]; } __syncthreads(); }
  if (t == 0) { part[(bg * 64 + blk) * 2] = rs[0]; part[(bg * 64 + blk) * 2 + 1] = rq[0]; }
}

__global__ __launch_bounds__(64) void k_gn_final(const float* __restrict__ part, float* __restrict__ stats) {
  int bg = blockIdx.x, t = threadIdx.x;
  float s = part[(bg * 64 + t) * 2], ss = part[(bg * 64 + t) * 2 + 1];
#pragma unroll
  for (int off = 32; off; off >>= 1) { s += __shfl_xor(s, off); ss += __shfl_xor(ss, off); }
  if (t == 0) {
    float inv = 1.f / (float)((size_t)CPG * NN);
    float mu = s * inv;
    float var = ss * inv - mu * mu;
    stats[bg * 2] = mu;
    stats[bg * 2 + 1] = rsqrtf(var + EPSV);
  }
}

// out = GN(p0+p1+p2+p3+p4) (+ q0) (+ q1)   — float4, grid 4096
__global__ __launch_bounds__(256) void k_gn_apply(const float* __restrict__ p0, const float* __restrict__ p1,
                                                  const float* __restrict__ p2, const float* __restrict__ p3,
                                                  const float* __restrict__ p4,
                                                  const float* __restrict__ stats, const float* __restrict__ g,
                                                  const float* __restrict__ be,
                                                  const float* __restrict__ q0, const float* __restrict__ q1,
                                                  float* __restrict__ out) {
  size_t i4 = (size_t)blockIdx.x * 256 + threadIdx.x;
  size_t i = i4 * 4;
  int chan = (int)(i >> 15) & 63;
  int bg = (int)(i >> 19);
  float4 x = ((const float4*)p0)[i4];
  if (p1) { float4 y4 = ((const float4*)p1)[i4]; x.x += y4.x; x.y += y4.y; x.z += y4.z; x.w += y4.w; }
  if (p2) { float4 y4 = ((const float4*)p2)[i4]; x.x += y4.x; x.y += y4.y; x.z += y4.z; x.w += y4.w; }
  if (p3) { float4 y4 = ((const float4*)p3)[i4]; x.x += y4.x; x.y += y4.y; x.z += y4.z; x.w += y4.w; }
  if (p4) { float4 y4 = ((const float4*)p4)[i4]; x.x += y4.x; x.y += y4.y; x.z += y4.z; x.w += y4.w; }
  float mu = stats[bg * 2], rr = stats[bg * 2 + 1];
  float gc = g[chan], bc = be[chan];
  float4 v;
  v.x = (x.x - mu) * rr * gc + bc;
  v.y = (x.y - mu) * rr * gc + bc;
  v.z = (x.z - mu) * rr * gc + bc;
  v.w = (x.w - mu) * rr * gc + bc;
  if (q0) { float4 y4 = ((const float4*)q0)[i4]; v.x += y4.x; v.y += y4.y; v.z += y4.z; v.w += y4.w; }
  if (q1) { float4 y4 = ((const float4*)q1)[i4]; v.x += y4.x; v.y += y4.y; v.z += y4.z; v.w += y4.w; }
  ((float4*)out)[i4] = v;
}

extern "C" void kernel_launch(void* const* d_in, const int* in_sizes, int n_in,
                              void* d_out, int out_size, void* d_ws, size_t ws_size,
                              hipStream_t stream) {
  (void)in_sizes; (void)n_in; (void)out_size; (void)ws_size;
  const float* y     = (const float*)d_in[0];
  const float* a1    = (const float*)d_in[1];
  const float* a2    = (const float*)d_in[2];
  const float* nv1   = (const float*)d_in[3];
  const float* nv2   = (const float*)d_in[4];
  const float* gcn_w = (const float*)d_in[5];
  const float* gcn_b = (const float*)d_in[6];
  const float* s_wq  = (const float*)d_in[7];
  const float* s_wk  = (const float*)d_in[8];
  const float* s_wv  = (const float*)d_in[9];
  const float* s_pk  = (const float*)d_in[10];
  const float* s_pv  = (const float*)d_in[11];
  const float* s_wo  = (const float*)d_in[12];
  const float* s_bo  = (const float*)d_in[13];
  const float* t_wq  = (const float*)d_in[14];
  const float* t_wk  = (const float*)d_in[15];
  const float* t_wv  = (const float*)d_in[16];
  const float* t_bq  = (const float*)d_in[17];
  const float* t_bk  = (const float*)d_in[18];
  const float* t_bv  = (const float*)d_in[19];
  const float* t_wo  = (const float*)d_in[20];
  const float* t_bo  = (const float*)d_in[21];
  const float* t_l1w = (const float*)d_in[22];
  const float* t_l1b = (const float*)d_in[23];
  const float* t_l2w = (const float*)d_in[24];
  const float* t_l2b = (const float*)d_in[25];
  const float* ln1g  = (const float*)d_in[26];
  const float* ln1b  = (const float*)d_in[27];
  const float* ln2g  = (const float*)d_in[28];
  const float* ln2b  = (const float*)d_in[29];
  const float* gnlg  = (const float*)d_in[30];
  const float* gnlb  = (const float*)d_in[31];
  const float* gnsg  = (const float*)d_in[32];
  const float* gnsb  = (const float*)d_in[33];
  const float* gntg  = (const float*)d_in[34];
  const float* gntb  = (const float*)d_in[35];
  const float* ff1w  = (const float*)d_in[36];
  const float* ff1b  = (const float*)d_in[37];
  const float* ff2w  = (const float*)d_in[38];
  const float* ff2b  = (const float*)d_in[39];
  const float* gn2g  = (const float*)d_in[40];
  const float* gn2b  = (const float*)d_in[41];

  float* ws = (float*)d_ws;
  float* adp   = ws;
  float* part  = ws + 65536;
  float* stats = ws + 66560;
  unsigned short* a1_bf   = (unsigned short*)(ws + 131072);
  unsigned short* a2_bf   = (unsigned short*)(ws + 163840);
  unsigned short* adp_bf  = (unsigned short*)(ws + 196608);
  unsigned short* gcnw_bf = (unsigned short*)(ws + 229376);
  unsigned short* xs_bf   = (unsigned short*)(ws + 262144);
  float* kp2 = ws + 131072;
  float* vp2 = ws + 131072 + 1048576;
  float* ffh = ws + 2228224;
  const size_t SLOT = 4194304;
  float* G0 = ws + SLOT * 1;
  float* G1 = ws + SLOT * 2;
  float* G2 = ws + SLOT * 3;
  float* G3 = ws + SLOT * 4;
  float* G4 = ws + SLOT * 5;
  float* G5 = ws + SLOT * 6;
  float* G6 = ws + SLOT * 7;
  unsigned short* U1 = (unsigned short*)G3;
  unsigned short* U2 = (unsigned short*)G3 + 4194304;
  unsigned short* U3 = (unsigned short*)G4;
  unsigned short* U4 = (unsigned short*)G4 + 4194304;
  unsigned short* U5 = (unsigned short*)G5;
  unsigned short* U6 = (unsigned short*)G5 + 4194304;
  unsigned short* PT = (unsigned short*)G6;
  float* out = (float*)d_out;

  const long BS = 2097152;

  // ---- adaptive adjacency + bf16 casts ----
  k_adp<<<256, 256, 0, stream>>>(nv1, nv2, adp);
  k_cast<<<256, 256, 0, stream>>>(a1, a1_bf);
  k_cast<<<256, 256, 0, stream>>>(a2, a2_bf);
  k_cast<<<256, 256, 0, stream>>>(adp, adp_bf);
  k_cast<<<112, 256, 0, stream>>>(gcn_w, gcnw_bf);

  // ---- xs (B,L,K,C) fp32 + bf16 ----
  k_tr<<<dim3(512, 8), 256, 0, stream>>>(y, G2, nullptr, xs_bf, BS, 128, 32768, 1, BS, 64, 1, 16384, 64, 128);

  // ---- AdaptiveGCN (reordered): U_s = W_s X; out = s0 + Sum_f A_f(U_odd + A_f U_even) ----
  k_mix<<<1024, 64, 0, stream>>>(xs_bf, gcnw_bf, gcn_b, G1, U1, U2, U3, U4, U5, U6);
  k_adjM<<<512, 256, 0, stream>>>(a1_bf, U2, nullptr, PT, U1);
  k_adjM<<<512, 256, 0, stream>>>(a1_bf, PT, G3, nullptr, nullptr);
  k_adjM<<<512, 256, 0, stream>>>(a2_bf, U4, nullptr, PT, U3);
  k_adjM<<<512, 256, 0, stream>>>(a2_bf, PT, G4, nullptr, nullptr);
  k_adjM<<<512, 256, 0, stream>>>(adp_bf, U6, nullptr, PT, U5);
  k_adjM<<<512, 256, 0, stream>>>(adp_bf, PT, G5, nullptr, nullptr);
  k_gn_part<<<dim3(64, 8), 256, 0, stream>>>(y, G1, G3, G4, G5, part);
  k_gn_final<<<8, 64, 0, stream>>>(part, stats);
  k_gn_apply<<<4096, 256, 0, stream>>>(y, G1, G3, G4, G5, stats, gnlg, gnlb, nullptr, nullptr, G0);

  // ---- Linformer spatial attention ----
  k_qkv<<<1024, 256, 0, stream>>>(G2, s_wq, s_wk, s_wv, nullptr, nullptr, nullptr, G3, G4, G5);
  k_sproj<<<256, 256, 0, stream>>>(G4, s_pk, kp2);
  k_sproj<<<256, 256, 0, stream>>>(G5, s_pv, vp2);
  k_sattn<<<512, 512, 0, stream>>>(G3, kp2, vp2, G6);
  k_rowmm<64, 64, 0, 64><<<1024, 256, 0, stream>>>(G6, s_wo, s_bo, G4);
  k_tr<<<dim3(512, 8), 256, 0, stream>>>(G4, G1, nullptr, nullptr, BS, 64, 16384, 1, BS, 128, 1, 32768, 128, 64);
  k_gn_part<<<dim3(64, 8), 256, 0, stream>>>(y, G1, nullptr, nullptr, nullptr, part);
  k_gn_final<<<8, 64, 0, stream>>>(part, stats);
  k_gn_apply<<<4096, 256, 0, stream>>>(y, G1, nullptr, nullptr, nullptr, stats, gnsg, gnsb, nullptr, nullptr, G1);

  // ---- temporal transformer layer ----
  k_tr<<<dim3(512, 8), 256, 0, stream>>>(y, G2, nullptr, nullptr, BS, 128, 32768, 1, BS, 8192, 1, 64, 64, 128);
  k_qkv<<<1024, 256, 0, stream>>>(G2, t_wq, t_wk, t_wv, t_bq, t_bk, t_bv, G3, G4, G5);
  k_tattn<<<512, 512, 0, stream>>>(G3, G4, G5, G6);
  k_rowmm<64, 64, 0, 64><<<1024, 256, 0, stream>>>(G6, t_wo, t_bo, G3);
  k_ln<<<16384, 256, 0, stream>>>(G2, G3, ln1g, ln1b, G4);
  k_rowmm<64, 8, 2, 64><<<1024, 256, 0, stream>>>(G4, t_l1w, t_l1b, ffh);
  k_rowmm<8, 64, 0, 64><<<1024, 256, 0, stream>>>(ffh, t_l2w, t_l2b, G5);
  k_ln<<<16384, 256, 0, stream>>>(G4, G5, ln2g, ln2b, G6);
  k_tr<<<dim3(512, 8), 256, 0, stream>>>(G6, G2, nullptr, nullptr, BS, 8192, 64, 1, BS, 128, 1, 32768, 128, 64);
  k_gn_part<<<dim3(64, 8), 256, 0, stream>>>(y, G2, nullptr, nullptr, nullptr, part);
  k_gn_final<<<8, 64, 0, stream>>>(part, stats);
  k_gn_apply<<<4096, 256, 0, stream>>>(y, G2, nullptr, nullptr, nullptr, stats, gntg, gntb, G0, G1, G3);

  // ---- fuse + channel FFN + final GroupNorm ----
  k_tr<<<dim3(512, 8), 256, 0, stream>>>(G3, G4, nullptr, nullptr, BS, 128, 32768, 1, BS, 8192, 1, 64, 64, 128);
  k_rowmm<64, 128, 1, 64><<<1024, 256, 0, stream>>>(G4, ff1w, ff1b, G5);
  k_rowmm<128, 64, 0, 32><<<2048, 256, 0, stream>>>(G5, ff2w, ff2b, G4);
  k_tr<<<dim3(512, 8), 256, 0, stream>>>(G4, out, G3, nullptr, BS, 8192, 64, 1, BS, 128, 1, 32768, 128, 64);
  k_gn_part<<<dim3(64, 8), 256, 0, stream>>>(out, nullptr, nullptr, nullptr, nullptr, part);
  k_gn_final<<<8, 64, 0, stream>>>(part, stats);
  k_gn_apply<<<4096, 256, 0, stream>>>(out, nullptr, nullptr, nullptr, nullptr, stats, gn2g, gn2b, nullptr, nullptr, out);
}